// Round 1
// baseline (1369.631 us; speedup 1.0000x reference)
//
#include <hip/hip_runtime.h>
#include <hip/hip_bf16.h>

#define N_NODES 20000
#define E_EDGES 320000
#define FEAT 128
#define CDIM 256
#define NHEAD 8
#define HDIM 32
#define NLAYER 5
#define TDIM 64
#define MSLOT 10
#define MDIM 128
#define NCLS 2

// ---------------------------------------------------------------------------
// fp32 tiled GEMM: C[M,Nf] = op((A [+ A2]) @ B [+ bias]), op = optional relu
// A: [M,K] row-major, B: [K,Nf] row-major. K multiple of 16, Nf multiple of 64.
// ---------------------------------------------------------------------------
__global__ __launch_bounds__(256) void gemm64(
    const float* __restrict__ A, const float* __restrict__ A2,
    const float* __restrict__ B, const float* __restrict__ bias,
    float* __restrict__ C, int M, int K, int Nf, int doRelu)
{
    __shared__ float As[16][64];
    __shared__ float Bs[16][64];
    int tid = threadIdx.x;
    int tx = tid & 15, ty = tid >> 4;
    int row0 = blockIdx.y * 64, col0 = blockIdx.x * 64;
    int ar = tid >> 2;            // 0..63
    int ac = (tid & 3) * 4;       // 0,4,8,12

    float acc[4][4] = {};

    for (int k0 = 0; k0 < K; k0 += 16) {
        // stage A (transposed into As[k][m])
        int arow = row0 + ar;
        float4 av = make_float4(0.f, 0.f, 0.f, 0.f);
        if (arow < M) {
            av = *(const float4*)(A + (size_t)arow * K + k0 + ac);
            if (A2) {
                float4 a2 = *(const float4*)(A2 + (size_t)arow * K + k0 + ac);
                av.x += a2.x; av.y += a2.y; av.z += a2.z; av.w += a2.w;
            }
        }
        As[ac + 0][ar] = av.x;
        As[ac + 1][ar] = av.y;
        As[ac + 2][ar] = av.z;
        As[ac + 3][ar] = av.w;
        // stage B
        float4 bv = *(const float4*)(B + (size_t)(k0 + (tid >> 4)) * Nf + col0 + (tid & 15) * 4);
        *(float4*)&Bs[tid >> 4][(tid & 15) * 4] = bv;
        __syncthreads();
#pragma unroll
        for (int kk = 0; kk < 16; kk++) {
            float4 a = *(const float4*)&As[kk][ty * 4];
            float4 b = *(const float4*)&Bs[kk][tx * 4];
            acc[0][0] += a.x * b.x; acc[0][1] += a.x * b.y; acc[0][2] += a.x * b.z; acc[0][3] += a.x * b.w;
            acc[1][0] += a.y * b.x; acc[1][1] += a.y * b.y; acc[1][2] += a.y * b.z; acc[1][3] += a.y * b.w;
            acc[2][0] += a.z * b.x; acc[2][1] += a.z * b.y; acc[2][2] += a.z * b.z; acc[2][3] += a.z * b.w;
            acc[3][0] += a.w * b.x; acc[3][1] += a.w * b.y; acc[3][2] += a.w * b.z; acc[3][3] += a.w * b.w;
        }
        __syncthreads();
    }

    float4 bv = make_float4(0.f, 0.f, 0.f, 0.f);
    if (bias) bv = *(const float4*)(bias + col0 + tx * 4);
#pragma unroll
    for (int i = 0; i < 4; i++) {
        int r = row0 + ty * 4 + i;
        if (r < M) {
            float4 o;
            o.x = acc[i][0] + bv.x;
            o.y = acc[i][1] + bv.y;
            o.z = acc[i][2] + bv.z;
            o.w = acc[i][3] + bv.w;
            if (doRelu) {
                o.x = fmaxf(o.x, 0.f); o.y = fmaxf(o.y, 0.f);
                o.z = fmaxf(o.z, 0.f); o.w = fmaxf(o.w, 0.f);
            }
            *(float4*)(C + (size_t)r * Nf + col0 + tx * 4) = o;
        }
    }
}

// ---------------------------------------------------------------------------
// CSR construction
// ---------------------------------------------------------------------------
__global__ void count_deg(const int* __restrict__ dst, int* __restrict__ deg, int ne)
{
    int e = blockIdx.x * blockDim.x + threadIdx.x;
    if (e < ne) atomicAdd(&deg[dst[e]], 1);
}

__global__ __launch_bounds__(1024) void scan_kernel(const int* __restrict__ deg,
                                                    int* __restrict__ offs, int n)
{
    __shared__ int swt[16];
    __shared__ int srun;
    int tid = threadIdx.x, lane = tid & 63, wid = tid >> 6;
    if (tid == 0) srun = 0;
    __syncthreads();
    for (int base = 0; base < n; base += 1024) {
        int v = (base + tid < n) ? deg[base + tid] : 0;
        int x = v;
#pragma unroll
        for (int d = 1; d < 64; d <<= 1) {
            int t = __shfl_up(x, d);
            if (lane >= d) x += t;
        }
        if (lane == 63) swt[wid] = x;
        __syncthreads();
        if (wid == 0) {
            int w = (lane < 16) ? swt[lane] : 0;
#pragma unroll
            for (int d = 1; d < 16; d <<= 1) {
                int t = __shfl_up(w, d);
                if (lane >= d) w += t;
            }
            if (lane < 16) swt[lane] = w;
        }
        __syncthreads();
        int wbase = (wid == 0) ? 0 : swt[wid - 1];
        int total = swt[15];
        int run = srun;
        if (base + tid < n) offs[base + tid] = run + wbase + x - v;
        __syncthreads();
        if (tid == 0) srun = run + total;
        __syncthreads();
    }
}

__global__ void fill_csr(const int* __restrict__ src, const int* __restrict__ dst,
                         const int* __restrict__ offs, int* __restrict__ cursor,
                         int* __restrict__ csr_src, int ne)
{
    int e = blockIdx.x * blockDim.x + threadIdx.x;
    if (e < ne) {
        int d = dst[e];
        int p = atomicAdd(&cursor[d], 1);
        csr_src[offs[d] + p] = src[e];
    }
}

// ---------------------------------------------------------------------------
// e_src/e_dst: per-head dot of h with attention vectors (a flat-indexed by c)
// one wave per node; lane owns channels [lane*4, lane*4+4); head = lane>>3
// ---------------------------------------------------------------------------
__global__ __launch_bounds__(256) void head_logits(
    const float* __restrict__ h, const float* __restrict__ a_s, const float* __restrict__ a_d,
    float* __restrict__ esrc, float* __restrict__ edst, int n)
{
    int lane = threadIdx.x & 63;
    int node = (blockIdx.x * blockDim.x + threadIdx.x) >> 6;
    if (node >= n) return;
    float4 hv = *(const float4*)(h + (size_t)node * CDIM + lane * 4);
    float4 as4 = *(const float4*)(a_s + lane * 4);
    float4 ad4 = *(const float4*)(a_d + lane * 4);
    float ps = hv.x * as4.x + hv.y * as4.y + hv.z * as4.z + hv.w * as4.w;
    float pd = hv.x * ad4.x + hv.y * ad4.y + hv.z * ad4.z + hv.w * ad4.w;
    ps += __shfl_xor(ps, 1); ps += __shfl_xor(ps, 2); ps += __shfl_xor(ps, 4);
    pd += __shfl_xor(pd, 1); pd += __shfl_xor(pd, 2); pd += __shfl_xor(pd, 4);
    if ((lane & 7) == 0) {
        esrc[node * NHEAD + (lane >> 3)] = ps;
        edst[node * NHEAD + (lane >> 3)] = pd;
    }
}

// ---------------------------------------------------------------------------
// Fused GAT softmax + aggregation, per-destination (CSR). One wave per node.
// lanes each own 4 contiguous channels (float4); softmax per head computed
// redundantly on 8-lane groups (hh = lane&7), routed by shfl.
// ---------------------------------------------------------------------------
__global__ __launch_bounds__(256) void gat_agg(
    const float* __restrict__ h, const float* __restrict__ esrc, const float* __restrict__ edst,
    const int* __restrict__ offs, const int* __restrict__ deg, const int* __restrict__ csr_src,
    float* __restrict__ out, int n)
{
    int lane = threadIdx.x & 63;
    int node = (blockIdx.x * blockDim.x + threadIdx.x) >> 6;
    if (node >= n) return;
    int start = offs[node], cnt = deg[node];
    int hh = lane & 7;
    float edl = edst[node * NHEAD + hh];

    // pass 1: per-head max of leaky_relu(e_src[s] + e_dst[n])
    float m = -3.0e38f;
    int i8 = lane >> 3;
    for (int i = 0; i < cnt; i += 8) {
        int ii = i + i8;
        if (ii < cnt) {
            int s = csr_src[start + ii];
            float lg = esrc[s * NHEAD + hh] + edl;
            lg = lg > 0.f ? lg : 0.2f * lg;
            m = fmaxf(m, lg);
        }
    }
    m = fmaxf(m, __shfl_xor(m, 8));
    m = fmaxf(m, __shfl_xor(m, 16));
    m = fmaxf(m, __shfl_xor(m, 32));
    // every lane now holds max for head hh = lane&7

    // pass 2: accumulate exp-weighted h[src]
    float4 acc = make_float4(0.f, 0.f, 0.f, 0.f);
    float den = 0.f;
    int chead = lane >> 3;   // head owning this lane's channels
    for (int i = 0; i < cnt; i++) {
        int s = csr_src[start + i];
        float lg = esrc[s * NHEAD + hh] + edl;
        lg = lg > 0.f ? lg : 0.2f * lg;
        float w = __expf(lg - m);
        den += w;
        float wc = __shfl(w, chead);
        float4 hv = *(const float4*)(h + (size_t)s * CDIM + lane * 4);
        acc.x += wc * hv.x; acc.y += wc * hv.y; acc.z += wc * hv.z; acc.w += wc * hv.w;
    }
    float dc = __shfl(den, chead) + 1e-16f;
    float inv = 1.f / dc;
    float4 o;
    o.x = fmaxf(acc.x * inv, 0.f);
    o.y = fmaxf(acc.y * inv, 0.f);
    o.z = fmaxf(acc.z * inv, 0.f);
    o.w = fmaxf(acc.w * inv, 0.f);
    *(float4*)(out + (size_t)node * CDIM + lane * 4) = o;
}

// ---------------------------------------------------------------------------
// Cross-attention to 10-slot memory + residual + relu. One wave per node.
// out = relu(gat + softmax(q k^T / 16) v + xin)
// ---------------------------------------------------------------------------
__global__ __launch_bounds__(256) void cross_attn(
    const float* __restrict__ gat, const float* __restrict__ q,
    const float* __restrict__ kbuf, const float* __restrict__ vbuf,
    const float* __restrict__ xin, float* __restrict__ out, int n)
{
    __shared__ float sk[MSLOT * CDIM];
    __shared__ float sv[MSLOT * CDIM];
    for (int i = threadIdx.x; i < MSLOT * CDIM; i += 256) {
        sk[i] = kbuf[i];
        sv[i] = vbuf[i];
    }
    __syncthreads();
    int lane = threadIdx.x & 63;
    int node = (blockIdx.x * blockDim.x + threadIdx.x) >> 6;
    if (node >= n) return;
    float4 q4 = *(const float4*)(q + (size_t)node * CDIM + lane * 4);
    float s[MSLOT];
#pragma unroll
    for (int j = 0; j < MSLOT; j++) {
        float4 k4 = *(const float4*)(sk + j * CDIM + lane * 4);
        float p = q4.x * k4.x + q4.y * k4.y + q4.z * k4.z + q4.w * k4.w;
        p += __shfl_xor(p, 1); p += __shfl_xor(p, 2); p += __shfl_xor(p, 4);
        p += __shfl_xor(p, 8); p += __shfl_xor(p, 16); p += __shfl_xor(p, 32);
        s[j] = p * 0.0625f;   // / sqrt(256)
    }
    float m = s[0];
#pragma unroll
    for (int j = 1; j < MSLOT; j++) m = fmaxf(m, s[j]);
    float e[MSLOT], sum = 0.f;
#pragma unroll
    for (int j = 0; j < MSLOT; j++) { e[j] = __expf(s[j] - m); sum += e[j]; }
    float inv = 1.f / sum;
    float4 g4 = *(const float4*)(gat + (size_t)node * CDIM + lane * 4);
    float4 x4 = *(const float4*)(xin + (size_t)node * CDIM + lane * 4);
    float4 o;
    o.x = g4.x + x4.x; o.y = g4.y + x4.y; o.z = g4.z + x4.z; o.w = g4.w + x4.w;
#pragma unroll
    for (int j = 0; j < MSLOT; j++) {
        float p = e[j] * inv;
        float4 v4 = *(const float4*)(sv + j * CDIM + lane * 4);
        o.x += p * v4.x; o.y += p * v4.y; o.z += p * v4.z; o.w += p * v4.w;
    }
    o.x = fmaxf(o.x, 0.f); o.y = fmaxf(o.y, 0.f); o.z = fmaxf(o.z, 0.f); o.w = fmaxf(o.w, 0.f);
    *(float4*)(out + (size_t)node * CDIM + lane * 4) = o;
}

// ---------------------------------------------------------------------------
// Column mean (partial sums + atomics) and final projection
// ---------------------------------------------------------------------------
__global__ void col_sum(const float* __restrict__ node, float* __restrict__ pooled, int n)
{
    float acc = 0.f;
    int c = threadIdx.x;
    for (int r = blockIdx.x; r < n; r += gridDim.x) acc += node[(size_t)r * CDIM + c];
    atomicAdd(&pooled[c], acc);
}

__global__ void finalize(const float* __restrict__ pooled, const float* __restrict__ mem,
                         const float* __restrict__ Wc, const float* __restrict__ bc,
                         float* __restrict__ out)
{
    int lane = threadIdx.x;   // 64 threads
    float a0 = 0.f, a1 = 0.f;
    for (int i = lane; i < CDIM + MDIM; i += 64) {
        float f;
        if (i < CDIM) {
            f = pooled[i] * (1.0f / (float)N_NODES);
        } else {
            float s = 0.f;
            for (int r = 0; r < MSLOT; r++) s += mem[r * MDIM + (i - CDIM)];
            f = s * (1.0f / (float)MSLOT);
        }
        a0 += f * Wc[i * NCLS + 0];
        a1 += f * Wc[i * NCLS + 1];
    }
#pragma unroll
    for (int d = 1; d < 64; d <<= 1) { a0 += __shfl_xor(a0, d); a1 += __shfl_xor(a1, d); }
    if (lane == 0) { out[0] = a0 + bc[0]; out[1] = a1 + bc[1]; }
}

// ---------------------------------------------------------------------------
extern "C" void kernel_launch(void* const* d_in, const int* in_sizes, int n_in,
                              void* d_out, int out_size, void* d_ws, size_t ws_size,
                              hipStream_t stream)
{
    const float* x    = (const float*)d_in[0];
    const int*   ei   = (const int*)d_in[1];
    const float* temb = (const float*)d_in[2];
    const float* Wi   = (const float*)d_in[3];
    const float* bi   = (const float*)d_in[4];
    const float* Wg   = (const float*)d_in[5];
    const float* a_s  = (const float*)d_in[6];
    const float* a_d  = (const float*)d_in[7];
    const float* Wt   = (const float*)d_in[8];
    const float* Wq   = (const float*)d_in[9];
    const float* Wk   = (const float*)d_in[10];
    const float* Wv   = (const float*)d_in[11];
    const float* mem  = (const float*)d_in[12];
    const float* Wc   = (const float*)d_in[13];
    const float* bc   = (const float*)d_in[14];
    float* out = (float*)d_out;
    char* ws = (char*)d_ws;

    const size_t NC_BYTES = (size_t)N_NODES * CDIM * 4;   // 20,480,000
    float* nodeA  = (float*)(ws + 0 * NC_BYTES);
    float* nodeB  = (float*)(ws + 1 * NC_BYTES);
    float* gat    = (float*)(ws + 2 * NC_BYTES);
    float* scr    = (float*)(ws + 3 * NC_BYTES);
    size_t off = 4 * NC_BYTES;                      // 81,920,000
    float* esrc   = (float*)(ws + off); off += (size_t)N_NODES * NHEAD * 4;   // 640,000
    float* edst   = (float*)(ws + off); off += (size_t)N_NODES * NHEAD * 4;
    float* kbuf   = (float*)(ws + off); off += MSLOT * CDIM * 4;              // 10,240
    float* vbuf   = (float*)(ws + off); off += MSLOT * CDIM * 4;
    size_t zero_base = off;
    float* pooled = (float*)(ws + off); off += CDIM * 4;                      // 1,024
    int* deg      = (int*)(ws + off);   off += N_NODES * 4;
    int* offs     = (int*)(ws + off);   off += (N_NODES + 4) * 4;
    int* cursor   = (int*)(ws + off);   off += N_NODES * 4;
    size_t zero_len = off - zero_base;
    int* csr_src  = (int*)(ws + off);   off += (size_t)E_EDGES * 4;

    const int* srcIdx = ei;
    const int* dstIdx = ei + E_EDGES;

    hipMemsetAsync(ws + zero_base, 0, zero_len, stream);

    dim3 gBig(CDIM / 64, (N_NODES + 63) / 64);   // 4 x 313
    dim3 gMem(CDIM / 64, 1);
    int nodeBlocks = (N_NODES + 3) / 4;          // 4 waves (nodes) per 256-thr block

    // node = relu(x @ Wi + bi)
    gemm64<<<gBig, 256, 0, stream>>>(x, nullptr, Wi, bi, nodeA, N_NODES, FEAT, CDIM, 1);

    // CSR by destination (same for all layers)
    count_deg<<<(E_EDGES + 255) / 256, 256, 0, stream>>>(dstIdx, deg, E_EDGES);
    scan_kernel<<<1, 1024, 0, stream>>>(deg, offs, N_NODES);
    fill_csr<<<(E_EDGES + 255) / 256, 256, 0, stream>>>(srcIdx, dstIdx, offs, cursor, csr_src, E_EDGES);

    float* cur  = nodeA;
    float* hbuf = nodeB;
    for (int l = 0; l < NLAYER; l++) {
        // t_proj = temb @ Wt[l]
        gemm64<<<gBig, 256, 0, stream>>>(temb, nullptr, Wt + (size_t)l * TDIM * CDIM, nullptr,
                                         scr, N_NODES, TDIM, CDIM, 0);
        // h = (cur + t_proj) @ Wg[l]
        gemm64<<<gBig, 256, 0, stream>>>(cur, scr, Wg + (size_t)l * CDIM * CDIM, nullptr,
                                         hbuf, N_NODES, CDIM, CDIM, 0);
        head_logits<<<nodeBlocks, 256, 0, stream>>>(hbuf, a_s + (size_t)l * CDIM,
                                                    a_d + (size_t)l * CDIM, esrc, edst, N_NODES);
        gat_agg<<<nodeBlocks, 256, 0, stream>>>(hbuf, esrc, edst, offs, deg, csr_src, gat, N_NODES);
        // q = gat @ Wq[l]
        gemm64<<<gBig, 256, 0, stream>>>(gat, nullptr, Wq + (size_t)l * CDIM * CDIM, nullptr,
                                         scr, N_NODES, CDIM, CDIM, 0);
        // k,v = mem @ Wk[l], mem @ Wv[l]
        gemm64<<<gMem, 256, 0, stream>>>(mem, nullptr, Wk + (size_t)l * MDIM * CDIM, nullptr,
                                         kbuf, MSLOT, MDIM, CDIM, 0);
        gemm64<<<gMem, 256, 0, stream>>>(mem, nullptr, Wv + (size_t)l * MDIM * CDIM, nullptr,
                                         vbuf, MSLOT, MDIM, CDIM, 0);
        // node_next = relu(gat + attn @ v + cur)  -> hbuf
        cross_attn<<<nodeBlocks, 256, 0, stream>>>(gat, scr, kbuf, vbuf, cur, hbuf, N_NODES);
        // rotate: new node lives in hbuf; reuse old cur as next h buffer
        float* t = cur; cur = hbuf; hbuf = t;
    }

    col_sum<<<128, 256, 0, stream>>>(cur, pooled, N_NODES);
    finalize<<<1, 64, 0, stream>>>(pooled, mem, Wc, bc, out);
}

// Round 2
// 793.247 us; speedup vs baseline: 1.7266x; 1.7266x over previous
//
#include <hip/hip_runtime.h>
#include <hip/hip_bf16.h>

#define N_NODES 20000
#define E_EDGES 320000
#define FEAT 128
#define CDIM 256
#define NHEAD 8
#define HDIM 32
#define NLAYER 5
#define TDIM 64
#define MSLOT 10
#define MDIM 128
#define NCLS 2

typedef unsigned short ushort_t;
typedef short short8 __attribute__((ext_vector_type(8)));
typedef float floatx4 __attribute__((ext_vector_type(4)));

__device__ __forceinline__ ushort_t f2bf(float f) {
    union { float f; unsigned int u; } t; t.f = f;
    unsigned int r = (t.u + 0x7FFF + ((t.u >> 16) & 1)) >> 16;
    return (ushort_t)r;
}
__device__ __forceinline__ float bf2f(ushort_t u) {
    union { float f; unsigned int u; } t; t.u = ((unsigned int)u) << 16;
    return t.f;
}

// ---------------------------------------------------------------------------
// bf16 MFMA GEMM: C[M,256] = op((A1|A2) @ B + bias). A1:[M,K1] bf16 row-major,
// A2:[M,Ktot-K1] bf16 (fused concat along K; null if K1==Ktot).
// Bt: [256][Ktot] bf16 (B transposed, k contiguous). BM=32, BN=256, BK=32.
// Grid = M/32 blocks of 256 threads (4 waves; wave w owns cols [w*64,w*64+64)).
// A staged via global_load_lds (16B) with chunk-rotate swizzle; B same.
// ---------------------------------------------------------------------------
__global__ __launch_bounds__(256) void gemm_mfma(
    const ushort_t* __restrict__ A1, int lda1, int K1,
    const ushort_t* __restrict__ A2, int lda2, int Ktot,
    const ushort_t* __restrict__ Bt,
    const float* __restrict__ bias,
    float* Cf, ushort_t* Cbf, int doRelu)
{
    __shared__ __align__(16) ushort_t smemA[32 * 32];
    __shared__ __align__(16) ushort_t smemB[256 * 32];
    int tid = threadIdx.x;
    int lane = tid & 63, wid = tid >> 6;
    int li = lane & 15, lq = lane >> 4;
    int row0 = blockIdx.x * 32;

    floatx4 acc[2][4];
#pragma unroll
    for (int a = 0; a < 2; a++)
#pragma unroll
        for (int b = 0; b < 4; b++) acc[a][b] = {0.f, 0.f, 0.f, 0.f};

    for (int k0 = 0; k0 < Ktot; k0 += 32) {
        __syncthreads();
        const ushort_t* Ab;
        int lda;
        if (k0 < K1) { Ab = A1 + k0; lda = lda1; }
        else         { Ab = A2 + (k0 - K1); lda = lda2; }
        if (wid < 2) {
            int slot = wid * 64 + lane;
            int r = slot >> 2, c = slot & 3;
            int gc = (c - (r >> 1)) & 3;
            const void* g = (const void*)(Ab + (size_t)(row0 + r) * lda + gc * 8);
            __builtin_amdgcn_global_load_lds(
                (const __attribute__((address_space(1))) void*)g,
                (__attribute__((address_space(3))) void*)&smemA[wid * 512], 16, 0, 0);
        }
#pragma unroll
        for (int j = 0; j < 4; j++) {
            int slot = wid * 256 + j * 64 + lane;
            int n = slot >> 2, c = slot & 3;
            int gc = (c - (n >> 1)) & 3;
            const void* g = (const void*)(Bt + (size_t)n * Ktot + k0 + gc * 8);
            __builtin_amdgcn_global_load_lds(
                (const __attribute__((address_space(1))) void*)g,
                (__attribute__((address_space(3))) void*)&smemB[(wid * 256 + j * 64) * 8], 16, 0, 0);
        }
        __syncthreads();

        short8 af[2], bfr[4];
#pragma unroll
        for (int mt = 0; mt < 2; mt++) {
            int m = mt * 16 + li;
            int sw = (lq + (m >> 1)) & 3;
            af[mt] = *(const short8*)&smemA[m * 32 + sw * 8];
        }
#pragma unroll
        for (int nt = 0; nt < 4; nt++) {
            int n = wid * 64 + nt * 16 + li;
            int sw = (lq + (n >> 1)) & 3;
            bfr[nt] = *(const short8*)&smemB[n * 32 + sw * 8];
        }
#pragma unroll
        for (int mt = 0; mt < 2; mt++)
#pragma unroll
            for (int nt = 0; nt < 4; nt++)
                acc[mt][nt] = __builtin_amdgcn_mfma_f32_16x16x32_bf16(af[mt], bfr[nt], acc[mt][nt], 0, 0, 0);
    }

#pragma unroll
    for (int mt = 0; mt < 2; mt++) {
        int row = row0 + mt * 16 + lq * 4;
#pragma unroll
        for (int nt = 0; nt < 4; nt++) {
            int col = wid * 64 + nt * 16 + li;
            float bv = bias ? bias[col] : 0.f;
#pragma unroll
            for (int r = 0; r < 4; r++) {
                float v = acc[mt][nt][r] + bv;
                if (doRelu) v = fmaxf(v, 0.f);
                if (Cf)  Cf[(size_t)(row + r) * CDIM + col] = v;
                if (Cbf) Cbf[(size_t)(row + r) * CDIM + col] = f2bf(v);
            }
        }
    }
}

// ---------------------------------------------------------------------------
// fp32 tiled GEMM (kept for tiny matmuls: Wt@Wg prep and mem@Wk/Wv), batched.
// ---------------------------------------------------------------------------
__global__ __launch_bounds__(256) void gemm64(
    const float* __restrict__ A, const float* __restrict__ A2,
    const float* __restrict__ B, const float* __restrict__ bias,
    float* __restrict__ C, int M, int K, int Nf, int doRelu,
    int sA, int sB, int sC)
{
    __shared__ float As[16][64];
    __shared__ float Bs[16][64];
    A += (size_t)blockIdx.z * sA;
    B += (size_t)blockIdx.z * sB;
    C += (size_t)blockIdx.z * sC;
    int tid = threadIdx.x;
    int tx = tid & 15, ty = tid >> 4;
    int row0 = blockIdx.y * 64, col0 = blockIdx.x * 64;
    int ar = tid >> 2;
    int ac = (tid & 3) * 4;

    float acc[4][4] = {};

    for (int k0 = 0; k0 < K; k0 += 16) {
        int arow = row0 + ar;
        float4 av = make_float4(0.f, 0.f, 0.f, 0.f);
        if (arow < M) {
            av = *(const float4*)(A + (size_t)arow * K + k0 + ac);
            if (A2) {
                float4 a2 = *(const float4*)(A2 + (size_t)arow * K + k0 + ac);
                av.x += a2.x; av.y += a2.y; av.z += a2.z; av.w += a2.w;
            }
        }
        As[ac + 0][ar] = av.x;
        As[ac + 1][ar] = av.y;
        As[ac + 2][ar] = av.z;
        As[ac + 3][ar] = av.w;
        float4 bv = *(const float4*)(B + (size_t)(k0 + (tid >> 4)) * Nf + col0 + (tid & 15) * 4);
        *(float4*)&Bs[tid >> 4][(tid & 15) * 4] = bv;
        __syncthreads();
#pragma unroll
        for (int kk = 0; kk < 16; kk++) {
            float4 a = *(const float4*)&As[kk][ty * 4];
            float4 b = *(const float4*)&Bs[kk][tx * 4];
            acc[0][0] += a.x * b.x; acc[0][1] += a.x * b.y; acc[0][2] += a.x * b.z; acc[0][3] += a.x * b.w;
            acc[1][0] += a.y * b.x; acc[1][1] += a.y * b.y; acc[1][2] += a.y * b.z; acc[1][3] += a.y * b.w;
            acc[2][0] += a.z * b.x; acc[2][1] += a.z * b.y; acc[2][2] += a.z * b.z; acc[2][3] += a.z * b.w;
            acc[3][0] += a.w * b.x; acc[3][1] += a.w * b.y; acc[3][2] += a.w * b.z; acc[3][3] += a.w * b.w;
        }
        __syncthreads();
    }

    float4 bv = make_float4(0.f, 0.f, 0.f, 0.f);
    if (bias) bv = *(const float4*)(bias + col0 + tx * 4);
#pragma unroll
    for (int i = 0; i < 4; i++) {
        int r = row0 + ty * 4 + i;
        if (r < M) {
            float4 o;
            o.x = acc[i][0] + bv.x;
            o.y = acc[i][1] + bv.y;
            o.z = acc[i][2] + bv.z;
            o.w = acc[i][3] + bv.w;
            if (doRelu) {
                o.x = fmaxf(o.x, 0.f); o.y = fmaxf(o.y, 0.f);
                o.z = fmaxf(o.z, 0.f); o.w = fmaxf(o.w, 0.f);
            }
            *(float4*)(C + (size_t)r * Nf + col0 + tx * 4) = o;
        }
    }
}

// ---------------------------------------------------------------------------
// Prep: fp32 -> bf16 convert; fp32 -> bf16 transpose (batched)
// ---------------------------------------------------------------------------
__global__ void cvt_bf16(const float* __restrict__ in, ushort_t* __restrict__ out, int n)
{
    int i = blockIdx.x * blockDim.x + threadIdx.x;
    if (i < n) out[i] = f2bf(in[i]);
}

__global__ __launch_bounds__(256) void transpose_cast(
    const float* __restrict__ in, int K, int Nn,
    ushort_t* __restrict__ out, int ostride, int koff,
    int inBatchStride, int outBatchStride)
{
    __shared__ float tile[32][33];
    in  += (size_t)blockIdx.z * inBatchStride;
    out += (size_t)blockIdx.z * outBatchStride;
    int k0 = blockIdx.y * 32, n0 = blockIdx.x * 32;
    int tx = threadIdx.x & 31, ty = threadIdx.x >> 5;   // ty 0..7
#pragma unroll
    for (int j = 0; j < 4; j++)
        tile[ty + j * 8][tx] = in[(size_t)(k0 + ty + j * 8) * Nn + n0 + tx];
    __syncthreads();
#pragma unroll
    for (int j = 0; j < 4; j++) {
        int n = n0 + ty + j * 8;
        out[(size_t)n * ostride + koff + k0 + tx] = f2bf(tile[tx][ty + j * 8]);
    }
}

// ---------------------------------------------------------------------------
// CSR construction
// ---------------------------------------------------------------------------
__global__ void count_deg(const int* __restrict__ dst, int* __restrict__ deg, int ne)
{
    int e = blockIdx.x * blockDim.x + threadIdx.x;
    if (e < ne) atomicAdd(&deg[dst[e]], 1);
}

__global__ __launch_bounds__(1024) void scan_kernel(const int* __restrict__ deg,
                                                    int* __restrict__ offs, int n)
{
    __shared__ int swt[16];
    __shared__ int srun;
    int tid = threadIdx.x, lane = tid & 63, wid = tid >> 6;
    if (tid == 0) srun = 0;
    __syncthreads();
    for (int base = 0; base < n; base += 1024) {
        int v = (base + tid < n) ? deg[base + tid] : 0;
        int x = v;
#pragma unroll
        for (int d = 1; d < 64; d <<= 1) {
            int t = __shfl_up(x, d);
            if (lane >= d) x += t;
        }
        if (lane == 63) swt[wid] = x;
        __syncthreads();
        if (wid == 0) {
            int w = (lane < 16) ? swt[lane] : 0;
#pragma unroll
            for (int d = 1; d < 16; d <<= 1) {
                int t = __shfl_up(w, d);
                if (lane >= d) w += t;
            }
            if (lane < 16) swt[lane] = w;
        }
        __syncthreads();
        int wbase = (wid == 0) ? 0 : swt[wid - 1];
        int total = swt[15];
        int run = srun;
        if (base + tid < n) offs[base + tid] = run + wbase + x - v;
        __syncthreads();
        if (tid == 0) srun = run + total;
        __syncthreads();
    }
}

__global__ void fill_csr(const int* __restrict__ src, const int* __restrict__ dst,
                         const int* __restrict__ offs, int* __restrict__ cursor,
                         int* __restrict__ csr_src, int ne)
{
    int e = blockIdx.x * blockDim.x + threadIdx.x;
    if (e < ne) {
        int d = dst[e];
        int p = atomicAdd(&cursor[d], 1);
        csr_src[offs[d] + p] = src[e];
    }
}

// ---------------------------------------------------------------------------
// head logits from bf16 h
// ---------------------------------------------------------------------------
__global__ __launch_bounds__(256) void head_logits(
    const ushort_t* __restrict__ h, const float* __restrict__ a_s, const float* __restrict__ a_d,
    float* __restrict__ esrc, float* __restrict__ edst, int n)
{
    int lane = threadIdx.x & 63;
    int node = (blockIdx.x * blockDim.x + threadIdx.x) >> 6;
    if (node >= n) return;
    ushort4 hu = *(const ushort4*)(h + (size_t)node * CDIM + lane * 4);
    float h0 = bf2f(hu.x), h1 = bf2f(hu.y), h2 = bf2f(hu.z), h3 = bf2f(hu.w);
    float4 as4 = *(const float4*)(a_s + lane * 4);
    float4 ad4 = *(const float4*)(a_d + lane * 4);
    float ps = h0 * as4.x + h1 * as4.y + h2 * as4.z + h3 * as4.w;
    float pd = h0 * ad4.x + h1 * ad4.y + h2 * ad4.z + h3 * ad4.w;
    ps += __shfl_xor(ps, 1); ps += __shfl_xor(ps, 2); ps += __shfl_xor(ps, 4);
    pd += __shfl_xor(pd, 1); pd += __shfl_xor(pd, 2); pd += __shfl_xor(pd, 4);
    if ((lane & 7) == 0) {
        esrc[node * NHEAD + (lane >> 3)] = ps;
        edst[node * NHEAD + (lane >> 3)] = pd;
    }
}

// ---------------------------------------------------------------------------
// Fused GAT softmax + aggregation over CSR; h in bf16. One wave per node.
// Writes gat fp32 + gat bf16.
// ---------------------------------------------------------------------------
__global__ __launch_bounds__(256) void gat_agg(
    const ushort_t* __restrict__ h, const float* __restrict__ esrc, const float* __restrict__ edst,
    const int* __restrict__ offs, const int* __restrict__ deg, const int* __restrict__ csr_src,
    float* __restrict__ out, ushort_t* __restrict__ outbf, int n)
{
    int lane = threadIdx.x & 63;
    int node = (blockIdx.x * blockDim.x + threadIdx.x) >> 6;
    if (node >= n) return;
    int start = offs[node], cnt = deg[node];
    int hh = lane & 7;
    float edl = edst[node * NHEAD + hh];

    float m = -3.0e38f;
    int i8 = lane >> 3;
    for (int i = 0; i < cnt; i += 8) {
        int ii = i + i8;
        if (ii < cnt) {
            int s = csr_src[start + ii];
            float lg = esrc[s * NHEAD + hh] + edl;
            lg = lg > 0.f ? lg : 0.2f * lg;
            m = fmaxf(m, lg);
        }
    }
    m = fmaxf(m, __shfl_xor(m, 8));
    m = fmaxf(m, __shfl_xor(m, 16));
    m = fmaxf(m, __shfl_xor(m, 32));

    float4 acc = make_float4(0.f, 0.f, 0.f, 0.f);
    float den = 0.f;
    int chead = lane >> 3;
    for (int i = 0; i < cnt; i++) {
        int s = csr_src[start + i];
        float lg = esrc[s * NHEAD + hh] + edl;
        lg = lg > 0.f ? lg : 0.2f * lg;
        float w = __expf(lg - m);
        den += w;
        float wc = __shfl(w, chead);
        ushort4 hu = *(const ushort4*)(h + (size_t)s * CDIM + lane * 4);
        acc.x += wc * bf2f(hu.x); acc.y += wc * bf2f(hu.y);
        acc.z += wc * bf2f(hu.z); acc.w += wc * bf2f(hu.w);
    }
    float dc = __shfl(den, chead) + 1e-16f;
    float inv = 1.f / dc;
    float4 o;
    o.x = fmaxf(acc.x * inv, 0.f);
    o.y = fmaxf(acc.y * inv, 0.f);
    o.z = fmaxf(acc.z * inv, 0.f);
    o.w = fmaxf(acc.w * inv, 0.f);
    *(float4*)(out + (size_t)node * CDIM + lane * 4) = o;
    ushort4 ob;
    ob.x = f2bf(o.x); ob.y = f2bf(o.y); ob.z = f2bf(o.z); ob.w = f2bf(o.w);
    *(ushort4*)(outbf + (size_t)node * CDIM + lane * 4) = ob;
}

// ---------------------------------------------------------------------------
// Cross-attention to 10-slot memory + residual + relu. Writes fp32 + bf16.
// NOTE: q and outf may alias (same buffer) — read-before-write per node.
// ---------------------------------------------------------------------------
__global__ __launch_bounds__(256) void cross_attn(
    const float* __restrict__ gat, const float* q,
    const float* __restrict__ kbuf, const float* __restrict__ vbuf,
    const float* __restrict__ xin, float* outf, ushort_t* __restrict__ outbf, int n)
{
    __shared__ float sk[MSLOT * CDIM];
    __shared__ float sv[MSLOT * CDIM];
    for (int i = threadIdx.x; i < MSLOT * CDIM; i += 256) {
        sk[i] = kbuf[i];
        sv[i] = vbuf[i];
    }
    __syncthreads();
    int lane = threadIdx.x & 63;
    int node = (blockIdx.x * blockDim.x + threadIdx.x) >> 6;
    if (node >= n) return;
    float4 q4 = *(const float4*)(q + (size_t)node * CDIM + lane * 4);
    float s[MSLOT];
#pragma unroll
    for (int j = 0; j < MSLOT; j++) {
        float4 k4 = *(const float4*)(sk + j * CDIM + lane * 4);
        float p = q4.x * k4.x + q4.y * k4.y + q4.z * k4.z + q4.w * k4.w;
        p += __shfl_xor(p, 1); p += __shfl_xor(p, 2); p += __shfl_xor(p, 4);
        p += __shfl_xor(p, 8); p += __shfl_xor(p, 16); p += __shfl_xor(p, 32);
        s[j] = p * 0.0625f;
    }
    float m = s[0];
#pragma unroll
    for (int j = 1; j < MSLOT; j++) m = fmaxf(m, s[j]);
    float e[MSLOT], sum = 0.f;
#pragma unroll
    for (int j = 0; j < MSLOT; j++) { e[j] = __expf(s[j] - m); sum += e[j]; }
    float inv = 1.f / sum;
    float4 g4 = *(const float4*)(gat + (size_t)node * CDIM + lane * 4);
    float4 x4 = *(const float4*)(xin + (size_t)node * CDIM + lane * 4);
    float4 o;
    o.x = g4.x + x4.x; o.y = g4.y + x4.y; o.z = g4.z + x4.z; o.w = g4.w + x4.w;
#pragma unroll
    for (int j = 0; j < MSLOT; j++) {
        float p = e[j] * inv;
        float4 v4 = *(const float4*)(sv + j * CDIM + lane * 4);
        o.x += p * v4.x; o.y += p * v4.y; o.z += p * v4.z; o.w += p * v4.w;
    }
    o.x = fmaxf(o.x, 0.f); o.y = fmaxf(o.y, 0.f); o.z = fmaxf(o.z, 0.f); o.w = fmaxf(o.w, 0.f);
    *(float4*)(outf + (size_t)node * CDIM + lane * 4) = o;
    ushort4 ob;
    ob.x = f2bf(o.x); ob.y = f2bf(o.y); ob.z = f2bf(o.z); ob.w = f2bf(o.w);
    *(ushort4*)(outbf + (size_t)node * CDIM + lane * 4) = ob;
}

// ---------------------------------------------------------------------------
__global__ void col_sum(const float* __restrict__ node, float* __restrict__ pooled, int n)
{
    float acc = 0.f;
    int c = threadIdx.x;
    for (int r = blockIdx.x; r < n; r += gridDim.x) acc += node[(size_t)r * CDIM + c];
    atomicAdd(&pooled[c], acc);
}

__global__ void finalize(const float* __restrict__ pooled, const float* __restrict__ mem,
                         const float* __restrict__ Wc, const float* __restrict__ bc,
                         float* __restrict__ out)
{
    int lane = threadIdx.x;
    float a0 = 0.f, a1 = 0.f;
    for (int i = lane; i < CDIM + MDIM; i += 64) {
        float f;
        if (i < CDIM) {
            f = pooled[i] * (1.0f / (float)N_NODES);
        } else {
            float s = 0.f;
            for (int r = 0; r < MSLOT; r++) s += mem[r * MDIM + (i - CDIM)];
            f = s * (1.0f / (float)MSLOT);
        }
        a0 += f * Wc[i * NCLS + 0];
        a1 += f * Wc[i * NCLS + 1];
    }
#pragma unroll
    for (int d = 1; d < 64; d <<= 1) { a0 += __shfl_xor(a0, d); a1 += __shfl_xor(a1, d); }
    if (lane == 0) { out[0] = a0 + bc[0]; out[1] = a1 + bc[1]; }
}

// ---------------------------------------------------------------------------
extern "C" void kernel_launch(void* const* d_in, const int* in_sizes, int n_in,
                              void* d_out, int out_size, void* d_ws, size_t ws_size,
                              hipStream_t stream)
{
    const float* x    = (const float*)d_in[0];
    const int*   ei   = (const int*)d_in[1];
    const float* temb = (const float*)d_in[2];
    const float* Wi   = (const float*)d_in[3];
    const float* bi   = (const float*)d_in[4];
    const float* Wg   = (const float*)d_in[5];
    const float* a_s  = (const float*)d_in[6];
    const float* a_d  = (const float*)d_in[7];
    const float* Wt   = (const float*)d_in[8];
    const float* Wq   = (const float*)d_in[9];
    const float* Wk   = (const float*)d_in[10];
    const float* Wv   = (const float*)d_in[11];
    const float* mem  = (const float*)d_in[12];
    const float* Wc   = (const float*)d_in[13];
    const float* bc   = (const float*)d_in[14];
    float* out = (float*)d_out;
    char* ws = (char*)d_ws;

    const size_t NC_BYTES  = (size_t)N_NODES * CDIM * 4;      // 20.48 MB
    const size_t NCB_BYTES = (size_t)N_NODES * CDIM * 2;      // 10.24 MB
    size_t off = 0;
    float* bufA   = (float*)(ws + off); off += NC_BYTES;      // node (fp32)
    float* bufB   = (float*)(ws + off); off += NC_BYTES;      // q / next node
    float* gat    = (float*)(ws + off); off += NC_BYTES;
    ushort_t* hbf    = (ushort_t*)(ws + off); off += NCB_BYTES;
    ushort_t* nodebf = (ushort_t*)(ws + off); off += NCB_BYTES;
    ushort_t* gatbf  = (ushort_t*)(ws + off); off += NCB_BYTES;
    ushort_t* xbf    = (ushort_t*)(ws + off); off += (size_t)N_NODES * FEAT * 2;
    ushort_t* tembbf = (ushort_t*)(ws + off); off += (size_t)N_NODES * TDIM * 2;
    float* esrc   = (float*)(ws + off); off += (size_t)N_NODES * NHEAD * 4;
    float* edst   = (float*)(ws + off); off += (size_t)N_NODES * NHEAD * 4;
    float* kbufs  = (float*)(ws + off); off += (size_t)NLAYER * MSLOT * CDIM * 4;
    float* vbufs  = (float*)(ws + off); off += (size_t)NLAYER * MSLOT * CDIM * 4;
    float* Wtp    = (float*)(ws + off); off += (size_t)NLAYER * TDIM * CDIM * 4;
    ushort_t* Bt_i = (ushort_t*)(ws + off); off += (size_t)CDIM * FEAT * 2;
    ushort_t* Bt_h = (ushort_t*)(ws + off); off += (size_t)NLAYER * CDIM * (CDIM + TDIM) * 2;
    ushort_t* Bt_q = (ushort_t*)(ws + off); off += (size_t)NLAYER * CDIM * CDIM * 2;
    size_t zero_base = off;
    float* pooled = (float*)(ws + off); off += CDIM * 4;
    int* deg      = (int*)(ws + off);   off += N_NODES * 4;
    int* cursor   = (int*)(ws + off);   off += N_NODES * 4;
    size_t zero_len = off - zero_base;
    int* offs     = (int*)(ws + off);   off += (N_NODES + 4) * 4;
    int* csr_src  = (int*)(ws + off);   off += (size_t)E_EDGES * 4;

    const int* srcIdx = ei;
    const int* dstIdx = ei + E_EDGES;

    hipMemsetAsync(ws + zero_base, 0, zero_len, stream);

    // ---- prep: converts, Wt' = Wt@Wg, transposed bf16 weights ----
    cvt_bf16<<<(N_NODES * FEAT + 255) / 256, 256, 0, stream>>>(x, xbf, N_NODES * FEAT);
    cvt_bf16<<<(N_NODES * TDIM + 255) / 256, 256, 0, stream>>>(temb, tembbf, N_NODES * TDIM);
    // Wt' (batched over layers): [64,256] = Wt[l] @ Wg[l]
    gemm64<<<dim3(4, 1, NLAYER), 256, 0, stream>>>(Wt, nullptr, Wg, nullptr, Wtp,
        TDIM, CDIM, CDIM, 0, TDIM * CDIM, CDIM * CDIM, TDIM * CDIM);
    // transposes -> bf16
    transpose_cast<<<dim3(CDIM / 32, FEAT / 32, 1), 256, 0, stream>>>(
        Wi, FEAT, CDIM, Bt_i, FEAT, 0, 0, 0);
    transpose_cast<<<dim3(CDIM / 32, CDIM / 32, NLAYER), 256, 0, stream>>>(
        Wg, CDIM, CDIM, Bt_h, CDIM + TDIM, 0, CDIM * CDIM, CDIM * (CDIM + TDIM));
    transpose_cast<<<dim3(CDIM / 32, TDIM / 32, NLAYER), 256, 0, stream>>>(
        Wtp, TDIM, CDIM, Bt_h, CDIM + TDIM, CDIM, TDIM * CDIM, CDIM * (CDIM + TDIM));
    transpose_cast<<<dim3(CDIM / 32, CDIM / 32, NLAYER), 256, 0, stream>>>(
        Wq, CDIM, CDIM, Bt_q, CDIM, 0, CDIM * CDIM, CDIM * CDIM);
    // k,v for all layers (batched; A=mem has stride 0)
    gemm64<<<dim3(4, 1, NLAYER), 256, 0, stream>>>(mem, nullptr, Wk, nullptr, kbufs,
        MSLOT, MDIM, CDIM, 0, 0, MDIM * CDIM, MSLOT * CDIM);
    gemm64<<<dim3(4, 1, NLAYER), 256, 0, stream>>>(mem, nullptr, Wv, nullptr, vbufs,
        MSLOT, MDIM, CDIM, 0, 0, MDIM * CDIM, MSLOT * CDIM);

    // ---- CSR by destination ----
    count_deg<<<(E_EDGES + 255) / 256, 256, 0, stream>>>(dstIdx, deg, E_EDGES);
    scan_kernel<<<1, 1024, 0, stream>>>(deg, offs, N_NODES);
    fill_csr<<<(E_EDGES + 255) / 256, 256, 0, stream>>>(srcIdx, dstIdx, offs, cursor, csr_src, E_EDGES);

    int mfmaBlocks = N_NODES / 32;                // 625
    int nodeBlocks = (N_NODES + 3) / 4;

    // node = relu(x @ Wi + bi)  -> bufA fp32 + nodebf
    gemm_mfma<<<mfmaBlocks, 256, 0, stream>>>(xbf, FEAT, FEAT, nullptr, 0, FEAT,
                                              Bt_i, bi, bufA, nodebf, 1);

    float* cur = bufA;
    float* alt = bufB;
    for (int l = 0; l < NLAYER; l++) {
        // h = node@Wg + temb@Wt'  (K=320 fused) -> hbf (bf16 only)
        gemm_mfma<<<mfmaBlocks, 256, 0, stream>>>(nodebf, CDIM, CDIM, tembbf, TDIM, CDIM + TDIM,
                                                  Bt_h + (size_t)l * CDIM * (CDIM + TDIM),
                                                  nullptr, nullptr, hbf, 0);
        head_logits<<<nodeBlocks, 256, 0, stream>>>(hbf, a_s + (size_t)l * CDIM,
                                                    a_d + (size_t)l * CDIM, esrc, edst, N_NODES);
        gat_agg<<<nodeBlocks, 256, 0, stream>>>(hbf, esrc, edst, offs, deg, csr_src,
                                                gat, gatbf, N_NODES);
        // q = gat @ Wq -> alt fp32
        gemm_mfma<<<mfmaBlocks, 256, 0, stream>>>(gatbf, CDIM, CDIM, nullptr, 0, CDIM,
                                                  Bt_q + (size_t)l * CDIM * CDIM,
                                                  nullptr, alt, nullptr, 0);
        // node_next = relu(gat + attn@v + cur) -> alt fp32 (aliases q) + nodebf
        cross_attn<<<nodeBlocks, 256, 0, stream>>>(gat, alt, kbufs + (size_t)l * MSLOT * CDIM,
                                                   vbufs + (size_t)l * MSLOT * CDIM,
                                                   cur, alt, nodebf, N_NODES);
        float* t = cur; cur = alt; alt = t;
    }

    col_sum<<<128, 256, 0, stream>>>(cur, pooled, N_NODES);
    finalize<<<1, 64, 0, stream>>>(pooled, mem, Wc, bc, out);
}

// Round 3
// 779.281 us; speedup vs baseline: 1.7576x; 1.0179x over previous
//
#include <hip/hip_runtime.h>
#include <hip/hip_bf16.h>

#define N_NODES 20000
#define E_EDGES 320000
#define FEAT 128
#define CDIM 256
#define NHEAD 8
#define HDIM 32
#define NLAYER 5
#define TDIM 64
#define MSLOT 10
#define MDIM 128
#define NCLS 2

typedef unsigned short ushort_t;
typedef short short8 __attribute__((ext_vector_type(8)));
typedef float floatx4 __attribute__((ext_vector_type(4)));

__device__ __forceinline__ ushort_t f2bf(float f) {
    union { float f; unsigned int u; } t; t.f = f;
    unsigned int r = (t.u + 0x7FFF + ((t.u >> 16) & 1)) >> 16;
    return (ushort_t)r;
}
__device__ __forceinline__ float bf2f(ushort_t u) {
    union { float f; unsigned int u; } t; t.u = ((unsigned int)u) << 16;
    return t.f;
}

// ---------------------------------------------------------------------------
// Shared MFMA K-loop macro pieces are inlined in each GEMM variant.
// Tiling: BM=32, BN=256, BK=32; 256 threads = 4 waves, wave w owns cols
// [w*64, w*64+64). C/D mapping (verified r1): row = row0+mt*16+lq*4+r,
// col = wid*64+nt*16+li.
// ---------------------------------------------------------------------------

// Plain variant (initial projection): Cf fp32 + Cbf bf16 + bias + relu
__global__ __launch_bounds__(256) void gemm_mfma(
    const ushort_t* __restrict__ A1, int lda1, int K1,
    const ushort_t* __restrict__ A2, int lda2, int Ktot,
    const ushort_t* __restrict__ Bt,
    const float* __restrict__ bias,
    float* Cf, ushort_t* Cbf, int doRelu)
{
    __shared__ __align__(16) ushort_t smemA[32 * 32];
    __shared__ __align__(16) ushort_t smemB[256 * 32];
    int tid = threadIdx.x;
    int lane = tid & 63, wid = tid >> 6;
    int li = lane & 15, lq = lane >> 4;
    int row0 = blockIdx.x * 32;

    floatx4 acc[2][4];
#pragma unroll
    for (int a = 0; a < 2; a++)
#pragma unroll
        for (int b = 0; b < 4; b++) acc[a][b] = {0.f, 0.f, 0.f, 0.f};

    for (int k0 = 0; k0 < Ktot; k0 += 32) {
        __syncthreads();
        const ushort_t* Ab; int lda;
        if (k0 < K1) { Ab = A1 + k0; lda = lda1; }
        else         { Ab = A2 + (k0 - K1); lda = lda2; }
        if (wid < 2) {
            int slot = wid * 64 + lane;
            int r = slot >> 2, c = slot & 3;
            int gc = (c - (r >> 1)) & 3;
            const void* g = (const void*)(Ab + (size_t)(row0 + r) * lda + gc * 8);
            __builtin_amdgcn_global_load_lds(
                (const __attribute__((address_space(1))) void*)g,
                (__attribute__((address_space(3))) void*)&smemA[wid * 512], 16, 0, 0);
        }
#pragma unroll
        for (int j = 0; j < 4; j++) {
            int slot = wid * 256 + j * 64 + lane;
            int n = slot >> 2, c = slot & 3;
            int gc = (c - (n >> 1)) & 3;
            const void* g = (const void*)(Bt + (size_t)n * Ktot + k0 + gc * 8);
            __builtin_amdgcn_global_load_lds(
                (const __attribute__((address_space(1))) void*)g,
                (__attribute__((address_space(3))) void*)&smemB[(wid * 256 + j * 64) * 8], 16, 0, 0);
        }
        __syncthreads();

        short8 af[2], bfr[4];
#pragma unroll
        for (int mt = 0; mt < 2; mt++) {
            int m = mt * 16 + li;
            int sw = (lq + (m >> 1)) & 3;
            af[mt] = *(const short8*)&smemA[m * 32 + sw * 8];
        }
#pragma unroll
        for (int nt = 0; nt < 4; nt++) {
            int n = wid * 64 + nt * 16 + li;
            int sw = (lq + (n >> 1)) & 3;
            bfr[nt] = *(const short8*)&smemB[n * 32 + sw * 8];
        }
#pragma unroll
        for (int mt = 0; mt < 2; mt++)
#pragma unroll
            for (int nt = 0; nt < 4; nt++)
                acc[mt][nt] = __builtin_amdgcn_mfma_f32_16x16x32_bf16(af[mt], bfr[nt], acc[mt][nt], 0, 0, 0);
    }

#pragma unroll
    for (int mt = 0; mt < 2; mt++) {
        int row = row0 + mt * 16 + lq * 4;
#pragma unroll
        for (int nt = 0; nt < 4; nt++) {
            int col = wid * 64 + nt * 16 + li;
            float bv = bias ? bias[col] : 0.f;
#pragma unroll
            for (int r = 0; r < 4; r++) {
                float v = acc[mt][nt][r] + bv;
                if (doRelu) v = fmaxf(v, 0.f);
                if (Cf)  Cf[(size_t)(row + r) * CDIM + col] = v;
                if (Cbf) Cbf[(size_t)(row + r) * CDIM + col] = f2bf(v);
            }
        }
    }
}

// h-GEMM with fused head-logits epilogue: writes hbf + esrc/edst
__global__ __launch_bounds__(256) void gemm_h(
    const ushort_t* __restrict__ A1, int lda1, int K1,
    const ushort_t* __restrict__ A2, int lda2, int Ktot,
    const ushort_t* __restrict__ Bt,
    const float* __restrict__ a_s, const float* __restrict__ a_d,
    ushort_t* __restrict__ Cbf,
    float* __restrict__ esrc, float* __restrict__ edst)
{
    __shared__ __align__(16) ushort_t smemA[32 * 32];
    __shared__ __align__(16) ushort_t smemB[256 * 32];
    __shared__ float eldsS[32][8];
    __shared__ float eldsD[32][8];
    int tid = threadIdx.x;
    int lane = tid & 63, wid = tid >> 6;
    int li = lane & 15, lq = lane >> 4;
    int row0 = blockIdx.x * 32;

    floatx4 acc[2][4];
#pragma unroll
    for (int a = 0; a < 2; a++)
#pragma unroll
        for (int b = 0; b < 4; b++) acc[a][b] = {0.f, 0.f, 0.f, 0.f};

    for (int k0 = 0; k0 < Ktot; k0 += 32) {
        __syncthreads();
        const ushort_t* Ab; int lda;
        if (k0 < K1) { Ab = A1 + k0; lda = lda1; }
        else         { Ab = A2 + (k0 - K1); lda = lda2; }
        if (wid < 2) {
            int slot = wid * 64 + lane;
            int r = slot >> 2, c = slot & 3;
            int gc = (c - (r >> 1)) & 3;
            const void* g = (const void*)(Ab + (size_t)(row0 + r) * lda + gc * 8);
            __builtin_amdgcn_global_load_lds(
                (const __attribute__((address_space(1))) void*)g,
                (__attribute__((address_space(3))) void*)&smemA[wid * 512], 16, 0, 0);
        }
#pragma unroll
        for (int j = 0; j < 4; j++) {
            int slot = wid * 256 + j * 64 + lane;
            int n = slot >> 2, c = slot & 3;
            int gc = (c - (n >> 1)) & 3;
            const void* g = (const void*)(Bt + (size_t)n * Ktot + k0 + gc * 8);
            __builtin_amdgcn_global_load_lds(
                (const __attribute__((address_space(1))) void*)g,
                (__attribute__((address_space(3))) void*)&smemB[(wid * 256 + j * 64) * 8], 16, 0, 0);
        }
        __syncthreads();

        short8 af[2], bfr[4];
#pragma unroll
        for (int mt = 0; mt < 2; mt++) {
            int m = mt * 16 + li;
            int sw = (lq + (m >> 1)) & 3;
            af[mt] = *(const short8*)&smemA[m * 32 + sw * 8];
        }
#pragma unroll
        for (int nt = 0; nt < 4; nt++) {
            int n = wid * 64 + nt * 16 + li;
            int sw = (lq + (n >> 1)) & 3;
            bfr[nt] = *(const short8*)&smemB[n * 32 + sw * 8];
        }
#pragma unroll
        for (int mt = 0; mt < 2; mt++)
#pragma unroll
            for (int nt = 0; nt < 4; nt++)
                acc[mt][nt] = __builtin_amdgcn_mfma_f32_16x16x32_bf16(af[mt], bfr[nt], acc[mt][nt], 0, 0, 0);
    }

    // epilogue: write hbf + per-head logits
    float as4[4], ad4[4];
#pragma unroll
    for (int nt = 0; nt < 4; nt++) {
        int col = wid * 64 + nt * 16 + li;
        as4[nt] = a_s[col];
        ad4[nt] = a_d[col];
    }
#pragma unroll
    for (int mt = 0; mt < 2; mt++) {
        int row = row0 + mt * 16 + lq * 4;
#pragma unroll
        for (int nt = 0; nt < 4; nt++) {
            int col = wid * 64 + nt * 16 + li;
#pragma unroll
            for (int r = 0; r < 4; r++)
                Cbf[(size_t)(row + r) * CDIM + col] = f2bf(acc[mt][nt][r]);
        }
#pragma unroll
        for (int r = 0; r < 4; r++) {
            int row_local = mt * 16 + lq * 4 + r;
            float psA = acc[mt][0][r] * as4[0] + acc[mt][1][r] * as4[1];
            float psB = acc[mt][2][r] * as4[2] + acc[mt][3][r] * as4[3];
            float pdA = acc[mt][0][r] * ad4[0] + acc[mt][1][r] * ad4[1];
            float pdB = acc[mt][2][r] * ad4[2] + acc[mt][3][r] * ad4[3];
#pragma unroll
            for (int d = 1; d < 16; d <<= 1) {
                psA += __shfl_xor(psA, d); psB += __shfl_xor(psB, d);
                pdA += __shfl_xor(pdA, d); pdB += __shfl_xor(pdB, d);
            }
            if (li == 0) {
                eldsS[row_local][2 * wid + 0] = psA;
                eldsS[row_local][2 * wid + 1] = psB;
                eldsD[row_local][2 * wid + 0] = pdA;
                eldsD[row_local][2 * wid + 1] = pdB;
            }
        }
    }
    __syncthreads();
    {
        int row = tid >> 3, hh = tid & 7;
        esrc[(size_t)(row0 + row) * NHEAD + hh] = eldsS[row][hh];
        edst[(size_t)(row0 + row) * NHEAD + hh] = eldsD[row][hh];
    }
}

// q-GEMM with fused cross-attention epilogue:
// out = relu(gat + softmax(q kT/16) v + cur), written fp32 + bf16
__global__ __launch_bounds__(256) void gemm_q_attn(
    const ushort_t* __restrict__ A1, int Ktot,
    const ushort_t* __restrict__ Bt,
    const float* __restrict__ kbuf, const float* __restrict__ vbuf,
    const float* __restrict__ gat, const float* __restrict__ cur,
    float* __restrict__ outf, ushort_t* __restrict__ outbf)
{
    __shared__ __align__(16) ushort_t smemA[32 * 32];
    __shared__ __align__(16) ushort_t smemB[256 * 32];
    __shared__ float skL[MSLOT * CDIM];
    __shared__ float svL[MSLOT * CDIM];
    __shared__ float scL[4][32][MSLOT];
    __shared__ float pL[32][MSLOT];
    int tid = threadIdx.x;
    int lane = tid & 63, wid = tid >> 6;
    int li = lane & 15, lq = lane >> 4;
    int row0 = blockIdx.x * 32;

    for (int i = tid; i < MSLOT * CDIM; i += 256) {
        skL[i] = kbuf[i];
        svL[i] = vbuf[i];
    }

    floatx4 acc[2][4];
#pragma unroll
    for (int a = 0; a < 2; a++)
#pragma unroll
        for (int b = 0; b < 4; b++) acc[a][b] = {0.f, 0.f, 0.f, 0.f};

    for (int k0 = 0; k0 < Ktot; k0 += 32) {
        __syncthreads();
        {
            if (wid < 2) {
                int slot = wid * 64 + lane;
                int r = slot >> 2, c = slot & 3;
                int gc = (c - (r >> 1)) & 3;
                const void* g = (const void*)(A1 + (size_t)(row0 + r) * Ktot + k0 + gc * 8);
                __builtin_amdgcn_global_load_lds(
                    (const __attribute__((address_space(1))) void*)g,
                    (__attribute__((address_space(3))) void*)&smemA[wid * 512], 16, 0, 0);
            }
#pragma unroll
            for (int j = 0; j < 4; j++) {
                int slot = wid * 256 + j * 64 + lane;
                int n = slot >> 2, c = slot & 3;
                int gc = (c - (n >> 1)) & 3;
                const void* g = (const void*)(Bt + (size_t)n * Ktot + k0 + gc * 8);
                __builtin_amdgcn_global_load_lds(
                    (const __attribute__((address_space(1))) void*)g,
                    (__attribute__((address_space(3))) void*)&smemB[(wid * 256 + j * 64) * 8], 16, 0, 0);
            }
        }
        __syncthreads();

        short8 af[2], bfr[4];
#pragma unroll
        for (int mt = 0; mt < 2; mt++) {
            int m = mt * 16 + li;
            int sw = (lq + (m >> 1)) & 3;
            af[mt] = *(const short8*)&smemA[m * 32 + sw * 8];
        }
#pragma unroll
        for (int nt = 0; nt < 4; nt++) {
            int n = wid * 64 + nt * 16 + li;
            int sw = (lq + (n >> 1)) & 3;
            bfr[nt] = *(const short8*)&smemB[n * 32 + sw * 8];
        }
#pragma unroll
        for (int mt = 0; mt < 2; mt++)
#pragma unroll
            for (int nt = 0; nt < 4; nt++)
                acc[mt][nt] = __builtin_amdgcn_mfma_f32_16x16x32_bf16(af[mt], bfr[nt], acc[mt][nt], 0, 0, 0);
    }

    // ---- scores: s[row][j] = q[row] . k[j] ----
    int colv[4];
#pragma unroll
    for (int nt = 0; nt < 4; nt++) colv[nt] = wid * 64 + nt * 16 + li;

#pragma unroll
    for (int j = 0; j < MSLOT; j++) {
        float k0v = skL[j * CDIM + colv[0]];
        float k1v = skL[j * CDIM + colv[1]];
        float k2v = skL[j * CDIM + colv[2]];
        float k3v = skL[j * CDIM + colv[3]];
#pragma unroll
        for (int mt = 0; mt < 2; mt++) {
#pragma unroll
            for (int r = 0; r < 4; r++) {
                float p = acc[mt][0][r] * k0v + acc[mt][1][r] * k1v
                        + acc[mt][2][r] * k2v + acc[mt][3][r] * k3v;
#pragma unroll
                for (int d = 1; d < 16; d <<= 1) p += __shfl_xor(p, d);
                if (li == 0) scL[wid][mt * 16 + lq * 4 + r][j] = p;
            }
        }
    }
    __syncthreads();
    // combine waves + softmax (threads 0..31, one row each)
    if (tid < 32) {
        float s[MSLOT];
        float m = -3.0e38f;
#pragma unroll
        for (int j = 0; j < MSLOT; j++) {
            s[j] = (scL[0][tid][j] + scL[1][tid][j] + scL[2][tid][j] + scL[3][tid][j]) * 0.0625f;
            m = fmaxf(m, s[j]);
        }
        float sum = 0.f;
#pragma unroll
        for (int j = 0; j < MSLOT; j++) { s[j] = __expf(s[j] - m); sum += s[j]; }
        float inv = 1.f / sum;
#pragma unroll
        for (int j = 0; j < MSLOT; j++) pL[tid][j] = s[j] * inv;
    }
    __syncthreads();

    // ---- output: o = relu(gat + cur + sum_j p_j v_j) ----
    float o[2][4][4];
#pragma unroll
    for (int mt = 0; mt < 2; mt++) {
        int row = row0 + mt * 16 + lq * 4;
#pragma unroll
        for (int nt = 0; nt < 4; nt++) {
            int col = colv[nt];
#pragma unroll
            for (int r = 0; r < 4; r++)
                o[mt][nt][r] = gat[(size_t)(row + r) * CDIM + col] + cur[(size_t)(row + r) * CDIM + col];
        }
    }
#pragma unroll
    for (int j = 0; j < MSLOT; j++) {
        float v0 = svL[j * CDIM + colv[0]];
        float v1 = svL[j * CDIM + colv[1]];
        float v2 = svL[j * CDIM + colv[2]];
        float v3 = svL[j * CDIM + colv[3]];
#pragma unroll
        for (int mt = 0; mt < 2; mt++) {
#pragma unroll
            for (int r = 0; r < 4; r++) {
                float pv = pL[mt * 16 + lq * 4 + r][j];
                o[mt][0][r] += pv * v0;
                o[mt][1][r] += pv * v1;
                o[mt][2][r] += pv * v2;
                o[mt][3][r] += pv * v3;
            }
        }
    }
#pragma unroll
    for (int mt = 0; mt < 2; mt++) {
        int row = row0 + mt * 16 + lq * 4;
#pragma unroll
        for (int nt = 0; nt < 4; nt++) {
            int col = colv[nt];
#pragma unroll
            for (int r = 0; r < 4; r++) {
                float v = fmaxf(o[mt][nt][r], 0.f);
                outf[(size_t)(row + r) * CDIM + col] = v;
                outbf[(size_t)(row + r) * CDIM + col] = f2bf(v);
            }
        }
    }
}

// ---------------------------------------------------------------------------
// fp32 tiled GEMM (tiny matmuls: Wt@Wg prep and mem@Wk/Wv), batched.
// ---------------------------------------------------------------------------
__global__ __launch_bounds__(256) void gemm64(
    const float* __restrict__ A, const float* __restrict__ A2,
    const float* __restrict__ B, const float* __restrict__ bias,
    float* __restrict__ C, int M, int K, int Nf, int doRelu,
    int sA, int sB, int sC)
{
    __shared__ float As[16][64];
    __shared__ float Bs[16][64];
    A += (size_t)blockIdx.z * sA;
    B += (size_t)blockIdx.z * sB;
    C += (size_t)blockIdx.z * sC;
    int tid = threadIdx.x;
    int tx = tid & 15, ty = tid >> 4;
    int row0 = blockIdx.y * 64, col0 = blockIdx.x * 64;
    int ar = tid >> 2;
    int ac = (tid & 3) * 4;

    float acc[4][4] = {};

    for (int k0 = 0; k0 < K; k0 += 16) {
        int arow = row0 + ar;
        float4 av = make_float4(0.f, 0.f, 0.f, 0.f);
        if (arow < M) {
            av = *(const float4*)(A + (size_t)arow * K + k0 + ac);
            if (A2) {
                float4 a2 = *(const float4*)(A2 + (size_t)arow * K + k0 + ac);
                av.x += a2.x; av.y += a2.y; av.z += a2.z; av.w += a2.w;
            }
        }
        As[ac + 0][ar] = av.x;
        As[ac + 1][ar] = av.y;
        As[ac + 2][ar] = av.z;
        As[ac + 3][ar] = av.w;
        float4 bv = *(const float4*)(B + (size_t)(k0 + (tid >> 4)) * Nf + col0 + (tid & 15) * 4);
        *(float4*)&Bs[tid >> 4][(tid & 15) * 4] = bv;
        __syncthreads();
#pragma unroll
        for (int kk = 0; kk < 16; kk++) {
            float4 a = *(const float4*)&As[kk][ty * 4];
            float4 b = *(const float4*)&Bs[kk][tx * 4];
            acc[0][0] += a.x * b.x; acc[0][1] += a.x * b.y; acc[0][2] += a.x * b.z; acc[0][3] += a.x * b.w;
            acc[1][0] += a.y * b.x; acc[1][1] += a.y * b.y; acc[1][2] += a.y * b.z; acc[1][3] += a.y * b.w;
            acc[2][0] += a.z * b.x; acc[2][1] += a.z * b.y; acc[2][2] += a.z * b.z; acc[2][3] += a.z * b.w;
            acc[3][0] += a.w * b.x; acc[3][1] += a.w * b.y; acc[3][2] += a.w * b.z; acc[3][3] += a.w * b.w;
        }
        __syncthreads();
    }

    float4 bv = make_float4(0.f, 0.f, 0.f, 0.f);
    if (bias) bv = *(const float4*)(bias + col0 + tx * 4);
#pragma unroll
    for (int i = 0; i < 4; i++) {
        int r = row0 + ty * 4 + i;
        if (r < M) {
            float4 o;
            o.x = acc[i][0] + bv.x;
            o.y = acc[i][1] + bv.y;
            o.z = acc[i][2] + bv.z;
            o.w = acc[i][3] + bv.w;
            if (doRelu) {
                o.x = fmaxf(o.x, 0.f); o.y = fmaxf(o.y, 0.f);
                o.z = fmaxf(o.z, 0.f); o.w = fmaxf(o.w, 0.f);
            }
            *(float4*)(C + (size_t)r * Nf + col0 + tx * 4) = o;
        }
    }
}

// ---------------------------------------------------------------------------
// Prep kernels
// ---------------------------------------------------------------------------
__global__ void cvt_bf16(const float* __restrict__ in, ushort_t* __restrict__ out, int n)
{
    int i = blockIdx.x * blockDim.x + threadIdx.x;
    if (i < n) out[i] = f2bf(in[i]);
}

__global__ __launch_bounds__(256) void transpose_cast(
    const float* __restrict__ in, int K, int Nn,
    ushort_t* __restrict__ out, int ostride, int koff,
    int inBatchStride, int outBatchStride)
{
    __shared__ float tile[32][33];
    in  += (size_t)blockIdx.z * inBatchStride;
    out += (size_t)blockIdx.z * outBatchStride;
    int k0 = blockIdx.y * 32, n0 = blockIdx.x * 32;
    int tx = threadIdx.x & 31, ty = threadIdx.x >> 5;
#pragma unroll
    for (int j = 0; j < 4; j++)
        tile[ty + j * 8][tx] = in[(size_t)(k0 + ty + j * 8) * Nn + n0 + tx];
    __syncthreads();
#pragma unroll
    for (int j = 0; j < 4; j++) {
        int n = n0 + ty + j * 8;
        out[(size_t)n * ostride + koff + k0 + tx] = f2bf(tile[tx][ty + j * 8]);
    }
}

// ---------------------------------------------------------------------------
// CSR construction
// ---------------------------------------------------------------------------
__global__ void count_deg(const int* __restrict__ dst, int* __restrict__ deg, int ne)
{
    int e = blockIdx.x * blockDim.x + threadIdx.x;
    if (e < ne) atomicAdd(&deg[dst[e]], 1);
}

__global__ __launch_bounds__(1024) void scan_kernel(const int* __restrict__ deg,
                                                    int* __restrict__ offs, int n)
{
    __shared__ int swt[16];
    __shared__ int srun;
    int tid = threadIdx.x, lane = tid & 63, wid = tid >> 6;
    if (tid == 0) srun = 0;
    __syncthreads();
    for (int base = 0; base < n; base += 1024) {
        int v = (base + tid < n) ? deg[base + tid] : 0;
        int x = v;
#pragma unroll
        for (int d = 1; d < 64; d <<= 1) {
            int t = __shfl_up(x, d);
            if (lane >= d) x += t;
        }
        if (lane == 63) swt[wid] = x;
        __syncthreads();
        if (wid == 0) {
            int w = (lane < 16) ? swt[lane] : 0;
#pragma unroll
            for (int d = 1; d < 16; d <<= 1) {
                int t = __shfl_up(w, d);
                if (lane >= d) w += t;
            }
            if (lane < 16) swt[lane] = w;
        }
        __syncthreads();
        int wbase = (wid == 0) ? 0 : swt[wid - 1];
        int total = swt[15];
        int run = srun;
        if (base + tid < n) offs[base + tid] = run + wbase + x - v;
        __syncthreads();
        if (tid == 0) srun = run + total;
        __syncthreads();
    }
}

__global__ void fill_csr(const int* __restrict__ src, const int* __restrict__ dst,
                         const int* __restrict__ offs, int* __restrict__ cursor,
                         int* __restrict__ csr_src, int ne)
{
    int e = blockIdx.x * blockDim.x + threadIdx.x;
    if (e < ne) {
        int d = dst[e];
        int p = atomicAdd(&cursor[d], 1);
        csr_src[offs[d] + p] = src[e];
    }
}

// ---------------------------------------------------------------------------
// Fused GAT softmax + aggregation, restructured:
// fast path (deg<=64): edge-per-lane parallel softmax, alpha in LDS,
// 4x-unrolled gather with precomputed addresses. Slow path: serial (rare).
// ---------------------------------------------------------------------------
__global__ __launch_bounds__(256) void gat_agg(
    const ushort_t* __restrict__ h, const float* __restrict__ esrc, const float* __restrict__ edst,
    const int* __restrict__ offs, const int* __restrict__ deg, const int* __restrict__ csr_src,
    float* __restrict__ out, ushort_t* __restrict__ outbf, int n)
{
    __shared__ float alphaL[4][NHEAD * 65];   // padded: bank = (h + i) % 32
    __shared__ int   sIdx[4][64];
    int lane = threadIdx.x & 63;
    int wslot = threadIdx.x >> 6;
    int node = (blockIdx.x * blockDim.x + threadIdx.x) >> 6;
    if (node >= n) return;
    int start = offs[node], cnt = deg[node];
    int chead = lane >> 3;

    if (cnt <= 64) {
        // --- phase 1: edge-per-lane logits + softmax ---
        int s = 0;
        if (lane < cnt) s = csr_src[start + lane];
        sIdx[wslot][lane] = s;
        float4 ed0 = *(const float4*)(edst + (size_t)node * NHEAD);
        float4 ed1 = *(const float4*)(edst + (size_t)node * NHEAD + 4);
        float4 es0 = *(const float4*)(esrc + (size_t)s * NHEAD);
        float4 es1 = *(const float4*)(esrc + (size_t)s * NHEAD + 4);
        float lg[8];
        lg[0] = es0.x + ed0.x; lg[1] = es0.y + ed0.y; lg[2] = es0.z + ed0.z; lg[3] = es0.w + ed0.w;
        lg[4] = es1.x + ed1.x; lg[5] = es1.y + ed1.y; lg[6] = es1.z + ed1.z; lg[7] = es1.w + ed1.w;
#pragma unroll
        for (int k = 0; k < 8; k++) {
            float v = lg[k];
            v = v > 0.f ? v : 0.2f * v;
            lg[k] = (lane < cnt) ? v : -3.0e38f;
        }
        float mx[8];
#pragma unroll
        for (int k = 0; k < 8; k++) {
            float v = lg[k];
#pragma unroll
            for (int d = 1; d < 64; d <<= 1) v = fmaxf(v, __shfl_xor(v, d));
            mx[k] = v;
        }
        float w8[8], den[8];
#pragma unroll
        for (int k = 0; k < 8; k++) {
            float w = __expf(lg[k] - mx[k]);
            w8[k] = w;
#pragma unroll
            for (int d = 1; d < 64; d <<= 1) w += __shfl_xor(w, d);
            den[k] = w;
        }
#pragma unroll
        for (int k = 0; k < 8; k++)
            alphaL[wslot][k * 65 + lane] = w8[k] / (den[k] + 1e-16f);

        // --- phase 2: gather, 4x unrolled (alpha=0 for padded edges) ---
        __builtin_amdgcn_s_waitcnt(0);   // drain LDS writes (wave-local)
        float4 acc = make_float4(0.f, 0.f, 0.f, 0.f);
        const float* aBase = &alphaL[wslot][chead * 65];
        const int* sBase = sIdx[wslot];
        int rounds = (cnt + 3) >> 2;
        for (int rr = 0; rr < rounds; rr++) {
            int i0 = rr * 4;
            int s0 = sBase[i0 + 0], s1 = sBase[i0 + 1], s2 = sBase[i0 + 2], s3 = sBase[i0 + 3];
            float a0 = aBase[i0 + 0], a1 = aBase[i0 + 1], a2 = aBase[i0 + 2], a3 = aBase[i0 + 3];
            ushort4 h0 = *(const ushort4*)(h + (size_t)s0 * CDIM + lane * 4);
            ushort4 h1 = *(const ushort4*)(h + (size_t)s1 * CDIM + lane * 4);
            ushort4 h2 = *(const ushort4*)(h + (size_t)s2 * CDIM + lane * 4);
            ushort4 h3 = *(const ushort4*)(h + (size_t)s3 * CDIM + lane * 4);
            acc.x += a0 * bf2f(h0.x) + a1 * bf2f(h1.x) + a2 * bf2f(h2.x) + a3 * bf2f(h3.x);
            acc.y += a0 * bf2f(h0.y) + a1 * bf2f(h1.y) + a2 * bf2f(h2.y) + a3 * bf2f(h3.y);
            acc.z += a0 * bf2f(h0.z) + a1 * bf2f(h1.z) + a2 * bf2f(h2.z) + a3 * bf2f(h3.z);
            acc.w += a0 * bf2f(h0.w) + a1 * bf2f(h1.w) + a2 * bf2f(h2.w) + a3 * bf2f(h3.w);
        }
        float4 o;
        o.x = fmaxf(acc.x, 0.f); o.y = fmaxf(acc.y, 0.f);
        o.z = fmaxf(acc.z, 0.f); o.w = fmaxf(acc.w, 0.f);
        *(float4*)(out + (size_t)node * CDIM + lane * 4) = o;
        ushort4 ob;
        ob.x = f2bf(o.x); ob.y = f2bf(o.y); ob.z = f2bf(o.z); ob.w = f2bf(o.w);
        *(ushort4*)(outbf + (size_t)node * CDIM + lane * 4) = ob;
    } else {
        // --- slow path (deg > 64): original two-pass serial ---
        int hh = lane & 7;
        float edl = edst[node * NHEAD + hh];
        float m = -3.0e38f;
        int i8 = lane >> 3;
        for (int i = 0; i < cnt; i += 8) {
            int ii = i + i8;
            if (ii < cnt) {
                int s = csr_src[start + ii];
                float lgv = esrc[s * NHEAD + hh] + edl;
                lgv = lgv > 0.f ? lgv : 0.2f * lgv;
                m = fmaxf(m, lgv);
            }
        }
        m = fmaxf(m, __shfl_xor(m, 8));
        m = fmaxf(m, __shfl_xor(m, 16));
        m = fmaxf(m, __shfl_xor(m, 32));
        float4 acc = make_float4(0.f, 0.f, 0.f, 0.f);
        float den = 0.f;
        for (int i = 0; i < cnt; i++) {
            int s = csr_src[start + i];
            float lgv = esrc[s * NHEAD + hh] + edl;
            lgv = lgv > 0.f ? lgv : 0.2f * lgv;
            float w = __expf(lgv - m);
            den += w;
            float wc = __shfl(w, chead);
            ushort4 hu = *(const ushort4*)(h + (size_t)s * CDIM + lane * 4);
            acc.x += wc * bf2f(hu.x); acc.y += wc * bf2f(hu.y);
            acc.z += wc * bf2f(hu.z); acc.w += wc * bf2f(hu.w);
        }
        float dc = __shfl(den, chead) + 1e-16f;
        float inv = 1.f / dc;
        float4 o;
        o.x = fmaxf(acc.x * inv, 0.f);
        o.y = fmaxf(acc.y * inv, 0.f);
        o.z = fmaxf(acc.z * inv, 0.f);
        o.w = fmaxf(acc.w * inv, 0.f);
        *(float4*)(out + (size_t)node * CDIM + lane * 4) = o;
        ushort4 ob;
        ob.x = f2bf(o.x); ob.y = f2bf(o.y); ob.z = f2bf(o.z); ob.w = f2bf(o.w);
        *(ushort4*)(outbf + (size_t)node * CDIM + lane * 4) = ob;
    }
}

// ---------------------------------------------------------------------------
__global__ void col_sum(const float* __restrict__ node, float* __restrict__ pooled, int n)
{
    float acc = 0.f;
    int c = threadIdx.x;
    for (int r = blockIdx.x; r < n; r += gridDim.x) acc += node[(size_t)r * CDIM + c];
    atomicAdd(&pooled[c], acc);
}

__global__ void finalize(const float* __restrict__ pooled, const float* __restrict__ mem,
                         const float* __restrict__ Wc, const float* __restrict__ bc,
                         float* __restrict__ out)
{
    int lane = threadIdx.x;
    float a0 = 0.f, a1 = 0.f;
    for (int i = lane; i < CDIM + MDIM; i += 64) {
        float f;
        if (i < CDIM) {
            f = pooled[i] * (1.0f / (float)N_NODES);
        } else {
            float s = 0.f;
            for (int r = 0; r < MSLOT; r++) s += mem[r * MDIM + (i - CDIM)];
            f = s * (1.0f / (float)MSLOT);
        }
        a0 += f * Wc[i * NCLS + 0];
        a1 += f * Wc[i * NCLS + 1];
    }
#pragma unroll
    for (int d = 1; d < 64; d <<= 1) { a0 += __shfl_xor(a0, d); a1 += __shfl_xor(a1, d); }
    if (lane == 0) { out[0] = a0 + bc[0]; out[1] = a1 + bc[1]; }
}

// ---------------------------------------------------------------------------
extern "C" void kernel_launch(void* const* d_in, const int* in_sizes, int n_in,
                              void* d_out, int out_size, void* d_ws, size_t ws_size,
                              hipStream_t stream)
{
    const float* x    = (const float*)d_in[0];
    const int*   ei   = (const int*)d_in[1];
    const float* temb = (const float*)d_in[2];
    const float* Wi   = (const float*)d_in[3];
    const float* bi   = (const float*)d_in[4];
    const float* Wg   = (const float*)d_in[5];
    const float* a_s  = (const float*)d_in[6];
    const float* a_d  = (const float*)d_in[7];
    const float* Wt   = (const float*)d_in[8];
    const float* Wq   = (const float*)d_in[9];
    const float* Wk   = (const float*)d_in[10];
    const float* Wv   = (const float*)d_in[11];
    const float* mem  = (const float*)d_in[12];
    const float* Wc   = (const float*)d_in[13];
    const float* bc   = (const float*)d_in[14];
    float* out = (float*)d_out;
    char* ws = (char*)d_ws;

    const size_t NC_BYTES  = (size_t)N_NODES * CDIM * 4;
    const size_t NCB_BYTES = (size_t)N_NODES * CDIM * 2;
    size_t off = 0;
    float* bufA   = (float*)(ws + off); off += NC_BYTES;      // node (fp32)
    float* bufB   = (float*)(ws + off); off += NC_BYTES;      // next node
    float* gat    = (float*)(ws + off); off += NC_BYTES;
    ushort_t* hbf    = (ushort_t*)(ws + off); off += NCB_BYTES;
    ushort_t* nodebf = (ushort_t*)(ws + off); off += NCB_BYTES;
    ushort_t* gatbf  = (ushort_t*)(ws + off); off += NCB_BYTES;
    ushort_t* xbf    = (ushort_t*)(ws + off); off += (size_t)N_NODES * FEAT * 2;
    ushort_t* tembbf = (ushort_t*)(ws + off); off += (size_t)N_NODES * TDIM * 2;
    float* esrc   = (float*)(ws + off); off += (size_t)N_NODES * NHEAD * 4;
    float* edst   = (float*)(ws + off); off += (size_t)N_NODES * NHEAD * 4;
    float* kbufs  = (float*)(ws + off); off += (size_t)NLAYER * MSLOT * CDIM * 4;
    float* vbufs  = (float*)(ws + off); off += (size_t)NLAYER * MSLOT * CDIM * 4;
    float* Wtp    = (float*)(ws + off); off += (size_t)NLAYER * TDIM * CDIM * 4;
    ushort_t* Bt_i = (ushort_t*)(ws + off); off += (size_t)CDIM * FEAT * 2;
    ushort_t* Bt_h = (ushort_t*)(ws + off); off += (size_t)NLAYER * CDIM * (CDIM + TDIM) * 2;
    ushort_t* Bt_q = (ushort_t*)(ws + off); off += (size_t)NLAYER * CDIM * CDIM * 2;
    size_t zero_base = off;
    float* pooled = (float*)(ws + off); off += CDIM * 4;
    int* deg      = (int*)(ws + off);   off += N_NODES * 4;
    int* cursor   = (int*)(ws + off);   off += N_NODES * 4;
    size_t zero_len = off - zero_base;
    int* offs     = (int*)(ws + off);   off += (N_NODES + 4) * 4;
    int* csr_src  = (int*)(ws + off);   off += (size_t)E_EDGES * 4;

    const int* srcIdx = ei;
    const int* dstIdx = ei + E_EDGES;

    hipMemsetAsync(ws + zero_base, 0, zero_len, stream);

    // ---- prep ----
    cvt_bf16<<<(N_NODES * FEAT + 255) / 256, 256, 0, stream>>>(x, xbf, N_NODES * FEAT);
    cvt_bf16<<<(N_NODES * TDIM + 255) / 256, 256, 0, stream>>>(temb, tembbf, N_NODES * TDIM);
    gemm64<<<dim3(4, 1, NLAYER), 256, 0, stream>>>(Wt, nullptr, Wg, nullptr, Wtp,
        TDIM, CDIM, CDIM, 0, TDIM * CDIM, CDIM * CDIM, TDIM * CDIM);
    transpose_cast<<<dim3(CDIM / 32, FEAT / 32, 1), 256, 0, stream>>>(
        Wi, FEAT, CDIM, Bt_i, FEAT, 0, 0, 0);
    transpose_cast<<<dim3(CDIM / 32, CDIM / 32, NLAYER), 256, 0, stream>>>(
        Wg, CDIM, CDIM, Bt_h, CDIM + TDIM, 0, CDIM * CDIM, CDIM * (CDIM + TDIM));
    transpose_cast<<<dim3(CDIM / 32, TDIM / 32, NLAYER), 256, 0, stream>>>(
        Wtp, TDIM, CDIM, Bt_h, CDIM + TDIM, CDIM, TDIM * CDIM, CDIM * (CDIM + TDIM));
    transpose_cast<<<dim3(CDIM / 32, CDIM / 32, NLAYER), 256, 0, stream>>>(
        Wq, CDIM, CDIM, Bt_q, CDIM, 0, CDIM * CDIM, CDIM * CDIM);
    gemm64<<<dim3(4, 1, NLAYER), 256, 0, stream>>>(mem, nullptr, Wk, nullptr, kbufs,
        MSLOT, MDIM, CDIM, 0, 0, MDIM * CDIM, MSLOT * CDIM);
    gemm64<<<dim3(4, 1, NLAYER), 256, 0, stream>>>(mem, nullptr, Wv, nullptr, vbufs,
        MSLOT, MDIM, CDIM, 0, 0, MDIM * CDIM, MSLOT * CDIM);

    // ---- CSR ----
    count_deg<<<(E_EDGES + 255) / 256, 256, 0, stream>>>(dstIdx, deg, E_EDGES);
    scan_kernel<<<1, 1024, 0, stream>>>(deg, offs, N_NODES);
    fill_csr<<<(E_EDGES + 255) / 256, 256, 0, stream>>>(srcIdx, dstIdx, offs, cursor, csr_src, E_EDGES);

    int mfmaBlocks = N_NODES / 32;
    int nodeBlocks = (N_NODES + 3) / 4;

    // node = relu(x @ Wi + bi)
    gemm_mfma<<<mfmaBlocks, 256, 0, stream>>>(xbf, FEAT, FEAT, nullptr, 0, FEAT,
                                              Bt_i, bi, bufA, nodebf, 1);

    float* cur = bufA;
    float* alt = bufB;
    for (int l = 0; l < NLAYER; l++) {
        // h = node@Wg + temb@Wt'  (K=320) + fused head logits
        gemm_h<<<mfmaBlocks, 256, 0, stream>>>(nodebf, CDIM, CDIM, tembbf, TDIM, CDIM + TDIM,
                                               Bt_h + (size_t)l * CDIM * (CDIM + TDIM),
                                               a_s + (size_t)l * CDIM, a_d + (size_t)l * CDIM,
                                               hbf, esrc, edst);
        gat_agg<<<nodeBlocks, 256, 0, stream>>>(hbf, esrc, edst, offs, deg, csr_src,
                                                gat, gatbf, N_NODES);
        // q GEMM + fused cross-attention + residual -> alt (fp32) + nodebf
        gemm_q_attn<<<mfmaBlocks, 256, 0, stream>>>(gatbf, CDIM,
                                                    Bt_q + (size_t)l * CDIM * CDIM,
                                                    kbufs + (size_t)l * MSLOT * CDIM,
                                                    vbufs + (size_t)l * MSLOT * CDIM,
                                                    gat, cur, alt, nodebf);
        float* t = cur; cur = alt; alt = t;
    }

    col_sum<<<128, 256, 0, stream>>>(cur, pooled, N_NODES);
    finalize<<<1, 64, 0, stream>>>(pooled, mem, Wc, bc, out);
}

// Round 4
// 613.594 us; speedup vs baseline: 2.2321x; 1.2700x over previous
//
#include <hip/hip_runtime.h>
#include <hip/hip_bf16.h>

#define N_NODES 20000
#define E_EDGES 320000
#define FEAT 128
#define CDIM 256
#define NHEAD 8
#define HDIM 32
#define NLAYER 5
#define TDIM 64
#define MSLOT 10
#define MDIM 128
#define NCLS 2

typedef unsigned short ushort_t;
typedef short short8 __attribute__((ext_vector_type(8)));
typedef float floatx4 __attribute__((ext_vector_type(4)));

__device__ __forceinline__ ushort_t f2bf(float f) {
    union { float f; unsigned int u; } t; t.f = f;
    unsigned int r = (t.u + 0x7FFF + ((t.u >> 16) & 1)) >> 16;
    return (ushort_t)r;
}
__device__ __forceinline__ float bf2f(ushort_t u) {
    union { float f; unsigned int u; } t; t.u = ((unsigned int)u) << 16;
    return t.f;
}

// ---------------------------------------------------------------------------
// bf16 MFMA GEMM, BM=32, BN=256, BK=32. 4 waves; wave w owns cols [w*64,+64).
// C/D map: row = row0+mt*16+lq*4+r, col = wid*64+nt*16+li.
// ---------------------------------------------------------------------------
__global__ __launch_bounds__(256) void gemm_mfma(
    const ushort_t* __restrict__ A1, int lda1, int K1,
    const ushort_t* __restrict__ A2, int lda2, int Ktot,
    const ushort_t* __restrict__ Bt,
    const float* __restrict__ bias,
    float* Cf, ushort_t* Cbf, int doRelu)
{
    __shared__ __align__(16) ushort_t smemA[32 * 32];
    __shared__ __align__(16) ushort_t smemB[256 * 32];
    int tid = threadIdx.x;
    int lane = tid & 63, wid = tid >> 6;
    int li = lane & 15, lq = lane >> 4;
    int row0 = blockIdx.x * 32;

    floatx4 acc[2][4];
#pragma unroll
    for (int a = 0; a < 2; a++)
#pragma unroll
        for (int b = 0; b < 4; b++) acc[a][b] = {0.f, 0.f, 0.f, 0.f};

    for (int k0 = 0; k0 < Ktot; k0 += 32) {
        __syncthreads();
        const ushort_t* Ab; int lda;
        if (k0 < K1) { Ab = A1 + k0; lda = lda1; }
        else         { Ab = A2 + (k0 - K1); lda = lda2; }
        if (wid < 2) {
            int slot = wid * 64 + lane;
            int r = slot >> 2, c = slot & 3;
            int gc = (c - (r >> 1)) & 3;
            const void* g = (const void*)(Ab + (size_t)(row0 + r) * lda + gc * 8);
            __builtin_amdgcn_global_load_lds(
                (const __attribute__((address_space(1))) void*)g,
                (__attribute__((address_space(3))) void*)&smemA[wid * 512], 16, 0, 0);
        }
#pragma unroll
        for (int j = 0; j < 4; j++) {
            int slot = wid * 256 + j * 64 + lane;
            int n = slot >> 2, c = slot & 3;
            int gc = (c - (n >> 1)) & 3;
            const void* g = (const void*)(Bt + (size_t)n * Ktot + k0 + gc * 8);
            __builtin_amdgcn_global_load_lds(
                (const __attribute__((address_space(1))) void*)g,
                (__attribute__((address_space(3))) void*)&smemB[(wid * 256 + j * 64) * 8], 16, 0, 0);
        }
        __syncthreads();

        short8 af[2], bfr[4];
#pragma unroll
        for (int mt = 0; mt < 2; mt++) {
            int m = mt * 16 + li;
            int sw = (lq + (m >> 1)) & 3;
            af[mt] = *(const short8*)&smemA[m * 32 + sw * 8];
        }
#pragma unroll
        for (int nt = 0; nt < 4; nt++) {
            int n = wid * 64 + nt * 16 + li;
            int sw = (lq + (n >> 1)) & 3;
            bfr[nt] = *(const short8*)&smemB[n * 32 + sw * 8];
        }
#pragma unroll
        for (int mt = 0; mt < 2; mt++)
#pragma unroll
            for (int nt = 0; nt < 4; nt++)
                acc[mt][nt] = __builtin_amdgcn_mfma_f32_16x16x32_bf16(af[mt], bfr[nt], acc[mt][nt], 0, 0, 0);
    }

#pragma unroll
    for (int mt = 0; mt < 2; mt++) {
        int row = row0 + mt * 16 + lq * 4;
#pragma unroll
        for (int nt = 0; nt < 4; nt++) {
            int col = wid * 64 + nt * 16 + li;
            float bv = bias ? bias[col] : 0.f;
#pragma unroll
            for (int r = 0; r < 4; r++) {
                float v = acc[mt][nt][r] + bv;
                if (doRelu) v = fmaxf(v, 0.f);
                if (Cf)  Cf[(size_t)(row + r) * CDIM + col] = v;
                if (Cbf) Cbf[(size_t)(row + r) * CDIM + col] = f2bf(v);
            }
        }
    }
}

// h-GEMM with fused head-logits epilogue: writes hbf + esrc/edst
__global__ __launch_bounds__(256) void gemm_h(
    const ushort_t* __restrict__ A1, int lda1, int K1,
    const ushort_t* __restrict__ A2, int lda2, int Ktot,
    const ushort_t* __restrict__ Bt,
    const float* __restrict__ a_s, const float* __restrict__ a_d,
    ushort_t* __restrict__ Cbf,
    float* __restrict__ esrc, float* __restrict__ edst)
{
    __shared__ __align__(16) ushort_t smemA[32 * 32];
    __shared__ __align__(16) ushort_t smemB[256 * 32];
    __shared__ float eldsS[32][8];
    __shared__ float eldsD[32][8];
    int tid = threadIdx.x;
    int lane = tid & 63, wid = tid >> 6;
    int li = lane & 15, lq = lane >> 4;
    int row0 = blockIdx.x * 32;

    floatx4 acc[2][4];
#pragma unroll
    for (int a = 0; a < 2; a++)
#pragma unroll
        for (int b = 0; b < 4; b++) acc[a][b] = {0.f, 0.f, 0.f, 0.f};

    for (int k0 = 0; k0 < Ktot; k0 += 32) {
        __syncthreads();
        const ushort_t* Ab; int lda;
        if (k0 < K1) { Ab = A1 + k0; lda = lda1; }
        else         { Ab = A2 + (k0 - K1); lda = lda2; }
        if (wid < 2) {
            int slot = wid * 64 + lane;
            int r = slot >> 2, c = slot & 3;
            int gc = (c - (r >> 1)) & 3;
            const void* g = (const void*)(Ab + (size_t)(row0 + r) * lda + gc * 8);
            __builtin_amdgcn_global_load_lds(
                (const __attribute__((address_space(1))) void*)g,
                (__attribute__((address_space(3))) void*)&smemA[wid * 512], 16, 0, 0);
        }
#pragma unroll
        for (int j = 0; j < 4; j++) {
            int slot = wid * 256 + j * 64 + lane;
            int n = slot >> 2, c = slot & 3;
            int gc = (c - (n >> 1)) & 3;
            const void* g = (const void*)(Bt + (size_t)n * Ktot + k0 + gc * 8);
            __builtin_amdgcn_global_load_lds(
                (const __attribute__((address_space(1))) void*)g,
                (__attribute__((address_space(3))) void*)&smemB[(wid * 256 + j * 64) * 8], 16, 0, 0);
        }
        __syncthreads();

        short8 af[2], bfr[4];
#pragma unroll
        for (int mt = 0; mt < 2; mt++) {
            int m = mt * 16 + li;
            int sw = (lq + (m >> 1)) & 3;
            af[mt] = *(const short8*)&smemA[m * 32 + sw * 8];
        }
#pragma unroll
        for (int nt = 0; nt < 4; nt++) {
            int n = wid * 64 + nt * 16 + li;
            int sw = (lq + (n >> 1)) & 3;
            bfr[nt] = *(const short8*)&smemB[n * 32 + sw * 8];
        }
#pragma unroll
        for (int mt = 0; mt < 2; mt++)
#pragma unroll
            for (int nt = 0; nt < 4; nt++)
                acc[mt][nt] = __builtin_amdgcn_mfma_f32_16x16x32_bf16(af[mt], bfr[nt], acc[mt][nt], 0, 0, 0);
    }

    float as4[4], ad4[4];
#pragma unroll
    for (int nt = 0; nt < 4; nt++) {
        int col = wid * 64 + nt * 16 + li;
        as4[nt] = a_s[col];
        ad4[nt] = a_d[col];
    }
#pragma unroll
    for (int mt = 0; mt < 2; mt++) {
        int row = row0 + mt * 16 + lq * 4;
#pragma unroll
        for (int nt = 0; nt < 4; nt++) {
            int col = wid * 64 + nt * 16 + li;
#pragma unroll
            for (int r = 0; r < 4; r++)
                Cbf[(size_t)(row + r) * CDIM + col] = f2bf(acc[mt][nt][r]);
        }
#pragma unroll
        for (int r = 0; r < 4; r++) {
            int row_local = mt * 16 + lq * 4 + r;
            float psA = acc[mt][0][r] * as4[0] + acc[mt][1][r] * as4[1];
            float psB = acc[mt][2][r] * as4[2] + acc[mt][3][r] * as4[3];
            float pdA = acc[mt][0][r] * ad4[0] + acc[mt][1][r] * ad4[1];
            float pdB = acc[mt][2][r] * ad4[2] + acc[mt][3][r] * ad4[3];
#pragma unroll
            for (int d = 1; d < 16; d <<= 1) {
                psA += __shfl_xor(psA, d); psB += __shfl_xor(psB, d);
                pdA += __shfl_xor(pdA, d); pdB += __shfl_xor(pdB, d);
            }
            if (li == 0) {
                eldsS[row_local][2 * wid + 0] = psA;
                eldsS[row_local][2 * wid + 1] = psB;
                eldsD[row_local][2 * wid + 0] = pdA;
                eldsD[row_local][2 * wid + 1] = pdB;
            }
        }
    }
    __syncthreads();
    {
        int row = tid >> 3, hh = tid & 7;
        esrc[(size_t)(row0 + row) * NHEAD + hh] = eldsS[row][hh];
        edst[(size_t)(row0 + row) * NHEAD + hh] = eldsD[row][hh];
    }
}

// ---------------------------------------------------------------------------
// fp32 tiled GEMM (tiny matmuls), batched.
// ---------------------------------------------------------------------------
__global__ __launch_bounds__(256) void gemm64(
    const float* __restrict__ A, const float* __restrict__ A2,
    const float* __restrict__ B, const float* __restrict__ bias,
    float* __restrict__ C, int M, int K, int Nf, int doRelu,
    int sA, int sB, int sC)
{
    __shared__ float As[16][64];
    __shared__ float Bs[16][64];
    A += (size_t)blockIdx.z * sA;
    B += (size_t)blockIdx.z * sB;
    C += (size_t)blockIdx.z * sC;
    int tid = threadIdx.x;
    int tx = tid & 15, ty = tid >> 4;
    int row0 = blockIdx.y * 64, col0 = blockIdx.x * 64;
    int ar = tid >> 2;
    int ac = (tid & 3) * 4;

    float acc[4][4] = {};

    for (int k0 = 0; k0 < K; k0 += 16) {
        int arow = row0 + ar;
        float4 av = make_float4(0.f, 0.f, 0.f, 0.f);
        if (arow < M) {
            av = *(const float4*)(A + (size_t)arow * K + k0 + ac);
            if (A2) {
                float4 a2 = *(const float4*)(A2 + (size_t)arow * K + k0 + ac);
                av.x += a2.x; av.y += a2.y; av.z += a2.z; av.w += a2.w;
            }
        }
        As[ac + 0][ar] = av.x;
        As[ac + 1][ar] = av.y;
        As[ac + 2][ar] = av.z;
        As[ac + 3][ar] = av.w;
        float4 bv = *(const float4*)(B + (size_t)(k0 + (tid >> 4)) * Nf + col0 + (tid & 15) * 4);
        *(float4*)&Bs[tid >> 4][(tid & 15) * 4] = bv;
        __syncthreads();
#pragma unroll
        for (int kk = 0; kk < 16; kk++) {
            float4 a = *(const float4*)&As[kk][ty * 4];
            float4 b = *(const float4*)&Bs[kk][tx * 4];
            acc[0][0] += a.x * b.x; acc[0][1] += a.x * b.y; acc[0][2] += a.x * b.z; acc[0][3] += a.x * b.w;
            acc[1][0] += a.y * b.x; acc[1][1] += a.y * b.y; acc[1][2] += a.y * b.z; acc[1][3] += a.y * b.w;
            acc[2][0] += a.z * b.x; acc[2][1] += a.z * b.y; acc[2][2] += a.z * b.z; acc[2][3] += a.z * b.w;
            acc[3][0] += a.w * b.x; acc[3][1] += a.w * b.y; acc[3][2] += a.w * b.z; acc[3][3] += a.w * b.w;
        }
        __syncthreads();
    }

    float4 bv = make_float4(0.f, 0.f, 0.f, 0.f);
    if (bias) bv = *(const float4*)(bias + col0 + tx * 4);
#pragma unroll
    for (int i = 0; i < 4; i++) {
        int r = row0 + ty * 4 + i;
        if (r < M) {
            float4 o;
            o.x = acc[i][0] + bv.x;
            o.y = acc[i][1] + bv.y;
            o.z = acc[i][2] + bv.z;
            o.w = acc[i][3] + bv.w;
            if (doRelu) {
                o.x = fmaxf(o.x, 0.f); o.y = fmaxf(o.y, 0.f);
                o.z = fmaxf(o.z, 0.f); o.w = fmaxf(o.w, 0.f);
            }
            *(float4*)(C + (size_t)r * Nf + col0 + tx * 4) = o;
        }
    }
}

// ---------------------------------------------------------------------------
// Prep kernels
// ---------------------------------------------------------------------------
__global__ void cvt_bf16(const float* __restrict__ in, ushort_t* __restrict__ out, int n)
{
    int i = blockIdx.x * blockDim.x + threadIdx.x;
    if (i < n) out[i] = f2bf(in[i]);
}

__global__ __launch_bounds__(256) void transpose_cast(
    const float* __restrict__ in, int K, int Nn,
    ushort_t* __restrict__ out, int ostride, int koff,
    int inBatchStride, int outBatchStride)
{
    __shared__ float tile[32][33];
    in  += (size_t)blockIdx.z * inBatchStride;
    out += (size_t)blockIdx.z * outBatchStride;
    int k0 = blockIdx.y * 32, n0 = blockIdx.x * 32;
    int tx = threadIdx.x & 31, ty = threadIdx.x >> 5;
#pragma unroll
    for (int j = 0; j < 4; j++)
        tile[ty + j * 8][tx] = in[(size_t)(k0 + ty + j * 8) * Nn + n0 + tx];
    __syncthreads();
#pragma unroll
    for (int j = 0; j < 4; j++) {
        int n = n0 + ty + j * 8;
        out[(size_t)n * ostride + koff + k0 + tx] = f2bf(tile[tx][ty + j * 8]);
    }
}

// Wqk[l][j][d] = (1/16) * sum_c Wq[l][d][c] * kbuf[l][j][c]
__global__ __launch_bounds__(256) void wqk_build(
    const float* __restrict__ Wq, const float* __restrict__ kbufs,
    float* __restrict__ wqk)
{
    int j = blockIdx.x, l = blockIdx.y;
    int d = threadIdx.x;
    __shared__ float kk[CDIM];
    kk[d] = kbufs[((size_t)l * MSLOT + j) * CDIM + d];
    __syncthreads();
    const float* wrow = Wq + ((size_t)l * CDIM + d) * CDIM;
    float acc = 0.f;
#pragma unroll 4
    for (int c = 0; c < CDIM; c++) acc += wrow[c] * kk[c];
    wqk[((size_t)l * MSLOT + j) * CDIM + d] = acc * 0.0625f;
}

// ---------------------------------------------------------------------------
// CSR construction
// ---------------------------------------------------------------------------
__global__ void count_deg(const int* __restrict__ dst, int* __restrict__ deg, int ne)
{
    int e = blockIdx.x * blockDim.x + threadIdx.x;
    if (e < ne) atomicAdd(&deg[dst[e]], 1);
}

__global__ __launch_bounds__(1024) void scan_kernel(const int* __restrict__ deg,
                                                    int* __restrict__ offs, int n)
{
    __shared__ int swt[16];
    __shared__ int srun;
    int tid = threadIdx.x, lane = tid & 63, wid = tid >> 6;
    if (tid == 0) srun = 0;
    __syncthreads();
    for (int base = 0; base < n; base += 1024) {
        int v = (base + tid < n) ? deg[base + tid] : 0;
        int x = v;
#pragma unroll
        for (int d = 1; d < 64; d <<= 1) {
            int t = __shfl_up(x, d);
            if (lane >= d) x += t;
        }
        if (lane == 63) swt[wid] = x;
        __syncthreads();
        if (wid == 0) {
            int w = (lane < 16) ? swt[lane] : 0;
#pragma unroll
            for (int d = 1; d < 16; d <<= 1) {
                int t = __shfl_up(w, d);
                if (lane >= d) w += t;
            }
            if (lane < 16) swt[lane] = w;
        }
        __syncthreads();
        int wbase = (wid == 0) ? 0 : swt[wid - 1];
        int total = swt[15];
        int run = srun;
        if (base + tid < n) offs[base + tid] = run + wbase + x - v;
        __syncthreads();
        if (tid == 0) srun = run + total;
        __syncthreads();
    }
}

__global__ void fill_csr(const int* __restrict__ src, const int* __restrict__ dst,
                         const int* __restrict__ offs, int* __restrict__ cursor,
                         int* __restrict__ csr_src, int ne)
{
    int e = blockIdx.x * blockDim.x + threadIdx.x;
    if (e < ne) {
        int d = dst[e];
        int p = atomicAdd(&cursor[d], 1);
        csr_src[offs[d] + p] = src[e];
    }
}

// ---------------------------------------------------------------------------
// Fully fused: GAT softmax + aggregation + cross-attn (via Wqk) + residual.
// One wave per node; n must be divisible by 4 (no early returns; block-level
// staging of Wqk and v in LDS).
// out = relu(gat + softmax(gat.Wqk).v + cur)
// ---------------------------------------------------------------------------
__global__ __launch_bounds__(256) void gat_agg_fused(
    const ushort_t* __restrict__ h, const float* __restrict__ esrc, const float* __restrict__ edst,
    const int* __restrict__ offs, const int* __restrict__ deg, const int* __restrict__ csr_src,
    const float* __restrict__ wqk, const float* __restrict__ vbuf,
    const float* __restrict__ cur,
    float* __restrict__ outf, ushort_t* __restrict__ outbf, int n)
{
    __shared__ float sW[MSLOT * CDIM];
    __shared__ float sV[MSLOT * CDIM];
    __shared__ float alphaL[4][NHEAD * 65];
    __shared__ int   sIdx[4][64];
    int tid = threadIdx.x;
    for (int i = tid; i < MSLOT * CDIM; i += 256) {
        sW[i] = wqk[i];
        sV[i] = vbuf[i];
    }
    __syncthreads();

    int lane = tid & 63;
    int wslot = tid >> 6;
    int node = blockIdx.x * 4 + wslot;
    int start = offs[node], cnt = deg[node];
    int chead = lane >> 3;

    float4 gat4;
    if (cnt <= 64) {
        // --- edge-per-lane parallel softmax ---
        int s = 0;
        if (lane < cnt) s = csr_src[start + lane];
        sIdx[wslot][lane] = s;
        float4 ed0 = *(const float4*)(edst + (size_t)node * NHEAD);
        float4 ed1 = *(const float4*)(edst + (size_t)node * NHEAD + 4);
        float4 es0 = *(const float4*)(esrc + (size_t)s * NHEAD);
        float4 es1 = *(const float4*)(esrc + (size_t)s * NHEAD + 4);
        float lg[8];
        lg[0] = es0.x + ed0.x; lg[1] = es0.y + ed0.y; lg[2] = es0.z + ed0.z; lg[3] = es0.w + ed0.w;
        lg[4] = es1.x + ed1.x; lg[5] = es1.y + ed1.y; lg[6] = es1.z + ed1.z; lg[7] = es1.w + ed1.w;
#pragma unroll
        for (int k = 0; k < 8; k++) {
            float v = lg[k];
            v = v > 0.f ? v : 0.2f * v;
            lg[k] = (lane < cnt) ? v : -3.0e38f;
        }
        float mx[8];
#pragma unroll
        for (int k = 0; k < 8; k++) {
            float v = lg[k];
#pragma unroll
            for (int d = 1; d < 64; d <<= 1) v = fmaxf(v, __shfl_xor(v, d));
            mx[k] = v;
        }
        float w8[8], den[8];
#pragma unroll
        for (int k = 0; k < 8; k++) {
            float w = __expf(lg[k] - mx[k]);
            w8[k] = w;
#pragma unroll
            for (int d = 1; d < 64; d <<= 1) w += __shfl_xor(w, d);
            den[k] = w;
        }
#pragma unroll
        for (int k = 0; k < 8; k++)
            alphaL[wslot][k * 65 + lane] = w8[k] / (den[k] + 1e-16f);

        __builtin_amdgcn_s_waitcnt(0);   // drain wave-local LDS writes
        float4 acc = make_float4(0.f, 0.f, 0.f, 0.f);
        const float* aBase = &alphaL[wslot][chead * 65];
        const int* sBase = sIdx[wslot];
        int rounds = (cnt + 3) >> 2;
        for (int rr = 0; rr < rounds; rr++) {
            int i0 = rr * 4;
            int s0 = sBase[i0 + 0], s1 = sBase[i0 + 1], s2 = sBase[i0 + 2], s3 = sBase[i0 + 3];
            float a0 = aBase[i0 + 0], a1 = aBase[i0 + 1], a2 = aBase[i0 + 2], a3 = aBase[i0 + 3];
            ushort4 h0 = *(const ushort4*)(h + (size_t)s0 * CDIM + lane * 4);
            ushort4 h1 = *(const ushort4*)(h + (size_t)s1 * CDIM + lane * 4);
            ushort4 h2 = *(const ushort4*)(h + (size_t)s2 * CDIM + lane * 4);
            ushort4 h3 = *(const ushort4*)(h + (size_t)s3 * CDIM + lane * 4);
            acc.x += a0 * bf2f(h0.x) + a1 * bf2f(h1.x) + a2 * bf2f(h2.x) + a3 * bf2f(h3.x);
            acc.y += a0 * bf2f(h0.y) + a1 * bf2f(h1.y) + a2 * bf2f(h2.y) + a3 * bf2f(h3.y);
            acc.z += a0 * bf2f(h0.z) + a1 * bf2f(h1.z) + a2 * bf2f(h2.z) + a3 * bf2f(h3.z);
            acc.w += a0 * bf2f(h0.w) + a1 * bf2f(h1.w) + a2 * bf2f(h2.w) + a3 * bf2f(h3.w);
        }
        gat4.x = fmaxf(acc.x, 0.f); gat4.y = fmaxf(acc.y, 0.f);
        gat4.z = fmaxf(acc.z, 0.f); gat4.w = fmaxf(acc.w, 0.f);
    } else {
        // --- slow path (deg > 64): two-pass serial ---
        int hh = lane & 7;
        float edl = edst[node * NHEAD + hh];
        float m = -3.0e38f;
        int i8 = lane >> 3;
        for (int i = 0; i < cnt; i += 8) {
            int ii = i + i8;
            if (ii < cnt) {
                int s = csr_src[start + ii];
                float lgv = esrc[s * NHEAD + hh] + edl;
                lgv = lgv > 0.f ? lgv : 0.2f * lgv;
                m = fmaxf(m, lgv);
            }
        }
        m = fmaxf(m, __shfl_xor(m, 8));
        m = fmaxf(m, __shfl_xor(m, 16));
        m = fmaxf(m, __shfl_xor(m, 32));
        float4 acc = make_float4(0.f, 0.f, 0.f, 0.f);
        float den = 0.f;
        for (int i = 0; i < cnt; i++) {
            int s = csr_src[start + i];
            float lgv = esrc[s * NHEAD + hh] + edl;
            lgv = lgv > 0.f ? lgv : 0.2f * lgv;
            float w = __expf(lgv - m);
            den += w;
            float wc = __shfl(w, chead);
            ushort4 hu = *(const ushort4*)(h + (size_t)s * CDIM + lane * 4);
            acc.x += wc * bf2f(hu.x); acc.y += wc * bf2f(hu.y);
            acc.z += wc * bf2f(hu.z); acc.w += wc * bf2f(hu.w);
        }
        float dc = __shfl(den, chead) + 1e-16f;
        float inv = 1.f / dc;
        gat4.x = fmaxf(acc.x * inv, 0.f);
        gat4.y = fmaxf(acc.y * inv, 0.f);
        gat4.z = fmaxf(acc.z * inv, 0.f);
        gat4.w = fmaxf(acc.w * inv, 0.f);
    }

    // --- cross-attention epilogue: s[j] = gat . Wqk[j] (pre-scaled) ---
    float s[MSLOT];
#pragma unroll
    for (int j = 0; j < MSLOT; j++) {
        float4 w4 = *(const float4*)(sW + j * CDIM + lane * 4);
        s[j] = gat4.x * w4.x + gat4.y * w4.y + gat4.z * w4.z + gat4.w * w4.w;
    }
#pragma unroll
    for (int d = 1; d < 64; d <<= 1) {
#pragma unroll
        for (int j = 0; j < MSLOT; j++) s[j] += __shfl_xor(s[j], d);
    }
    float m = s[0];
#pragma unroll
    for (int j = 1; j < MSLOT; j++) m = fmaxf(m, s[j]);
    float sum = 0.f;
#pragma unroll
    for (int j = 0; j < MSLOT; j++) { s[j] = __expf(s[j] - m); sum += s[j]; }
    float inv = 1.f / sum;

    float4 c4 = *(const float4*)(cur + (size_t)node * CDIM + lane * 4);
    float4 o;
    o.x = gat4.x + c4.x; o.y = gat4.y + c4.y; o.z = gat4.z + c4.z; o.w = gat4.w + c4.w;
#pragma unroll
    for (int j = 0; j < MSLOT; j++) {
        float p = s[j] * inv;
        float4 v4 = *(const float4*)(sV + j * CDIM + lane * 4);
        o.x += p * v4.x; o.y += p * v4.y; o.z += p * v4.z; o.w += p * v4.w;
    }
    o.x = fmaxf(o.x, 0.f); o.y = fmaxf(o.y, 0.f); o.z = fmaxf(o.z, 0.f); o.w = fmaxf(o.w, 0.f);
    *(float4*)(outf + (size_t)node * CDIM + lane * 4) = o;
    ushort4 ob;
    ob.x = f2bf(o.x); ob.y = f2bf(o.y); ob.z = f2bf(o.z); ob.w = f2bf(o.w);
    *(ushort4*)(outbf + (size_t)node * CDIM + lane * 4) = ob;
}

// ---------------------------------------------------------------------------
__global__ void col_sum(const float* __restrict__ node, float* __restrict__ pooled, int n)
{
    float acc = 0.f;
    int c = threadIdx.x;
    for (int r = blockIdx.x; r < n; r += gridDim.x) acc += node[(size_t)r * CDIM + c];
    atomicAdd(&pooled[c], acc);
}

__global__ void finalize(const float* __restrict__ pooled, const float* __restrict__ mem,
                         const float* __restrict__ Wc, const float* __restrict__ bc,
                         float* __restrict__ out)
{
    int lane = threadIdx.x;
    float a0 = 0.f, a1 = 0.f;
    for (int i = lane; i < CDIM + MDIM; i += 64) {
        float f;
        if (i < CDIM) {
            f = pooled[i] * (1.0f / (float)N_NODES);
        } else {
            float s = 0.f;
            for (int r = 0; r < MSLOT; r++) s += mem[r * MDIM + (i - CDIM)];
            f = s * (1.0f / (float)MSLOT);
        }
        a0 += f * Wc[i * NCLS + 0];
        a1 += f * Wc[i * NCLS + 1];
    }
#pragma unroll
    for (int d = 1; d < 64; d <<= 1) { a0 += __shfl_xor(a0, d); a1 += __shfl_xor(a1, d); }
    if (lane == 0) { out[0] = a0 + bc[0]; out[1] = a1 + bc[1]; }
}

// ---------------------------------------------------------------------------
extern "C" void kernel_launch(void* const* d_in, const int* in_sizes, int n_in,
                              void* d_out, int out_size, void* d_ws, size_t ws_size,
                              hipStream_t stream)
{
    const float* x    = (const float*)d_in[0];
    const int*   ei   = (const int*)d_in[1];
    const float* temb = (const float*)d_in[2];
    const float* Wi   = (const float*)d_in[3];
    const float* bi   = (const float*)d_in[4];
    const float* Wg   = (const float*)d_in[5];
    const float* a_s  = (const float*)d_in[6];
    const float* a_d  = (const float*)d_in[7];
    const float* Wt   = (const float*)d_in[8];
    const float* Wq   = (const float*)d_in[9];
    const float* Wk   = (const float*)d_in[10];
    const float* Wv   = (const float*)d_in[11];
    const float* mem  = (const float*)d_in[12];
    const float* Wc   = (const float*)d_in[13];
    const float* bc   = (const float*)d_in[14];
    float* out = (float*)d_out;
    char* ws = (char*)d_ws;

    const size_t NC_BYTES  = (size_t)N_NODES * CDIM * 4;
    const size_t NCB_BYTES = (size_t)N_NODES * CDIM * 2;
    size_t off = 0;
    float* bufA   = (float*)(ws + off); off += NC_BYTES;      // node fp32
    float* bufB   = (float*)(ws + off); off += NC_BYTES;      // next node fp32
    ushort_t* hbf    = (ushort_t*)(ws + off); off += NCB_BYTES;
    ushort_t* nodebf = (ushort_t*)(ws + off); off += NCB_BYTES;
    ushort_t* xbf    = (ushort_t*)(ws + off); off += (size_t)N_NODES * FEAT * 2;
    ushort_t* tembbf = (ushort_t*)(ws + off); off += (size_t)N_NODES * TDIM * 2;
    float* esrc   = (float*)(ws + off); off += (size_t)N_NODES * NHEAD * 4;
    float* edst   = (float*)(ws + off); off += (size_t)N_NODES * NHEAD * 4;
    float* kbufs  = (float*)(ws + off); off += (size_t)NLAYER * MSLOT * CDIM * 4;
    float* vbufs  = (float*)(ws + off); off += (size_t)NLAYER * MSLOT * CDIM * 4;
    float* wqkL   = (float*)(ws + off); off += (size_t)NLAYER * MSLOT * CDIM * 4;
    float* Wtp    = (float*)(ws + off); off += (size_t)NLAYER * TDIM * CDIM * 4;
    ushort_t* Bt_i = (ushort_t*)(ws + off); off += (size_t)CDIM * FEAT * 2;
    ushort_t* Bt_h = (ushort_t*)(ws + off); off += (size_t)NLAYER * CDIM * (CDIM + TDIM) * 2;
    size_t zero_base = off;
    float* pooled = (float*)(ws + off); off += CDIM * 4;
    int* deg      = (int*)(ws + off);   off += N_NODES * 4;
    int* cursor   = (int*)(ws + off);   off += N_NODES * 4;
    size_t zero_len = off - zero_base;
    int* offs     = (int*)(ws + off);   off += (N_NODES + 4) * 4;
    int* csr_src  = (int*)(ws + off);   off += (size_t)E_EDGES * 4;

    const int* srcIdx = ei;
    const int* dstIdx = ei + E_EDGES;

    hipMemsetAsync(ws + zero_base, 0, zero_len, stream);

    // ---- prep ----
    cvt_bf16<<<(N_NODES * FEAT + 255) / 256, 256, 0, stream>>>(x, xbf, N_NODES * FEAT);
    cvt_bf16<<<(N_NODES * TDIM + 255) / 256, 256, 0, stream>>>(temb, tembbf, N_NODES * TDIM);
    gemm64<<<dim3(4, 1, NLAYER), 256, 0, stream>>>(Wt, nullptr, Wg, nullptr, Wtp,
        TDIM, CDIM, CDIM, 0, TDIM * CDIM, CDIM * CDIM, TDIM * CDIM);
    transpose_cast<<<dim3(CDIM / 32, FEAT / 32, 1), 256, 0, stream>>>(
        Wi, FEAT, CDIM, Bt_i, FEAT, 0, 0, 0);
    transpose_cast<<<dim3(CDIM / 32, CDIM / 32, NLAYER), 256, 0, stream>>>(
        Wg, CDIM, CDIM, Bt_h, CDIM + TDIM, 0, CDIM * CDIM, CDIM * (CDIM + TDIM));
    transpose_cast<<<dim3(CDIM / 32, TDIM / 32, NLAYER), 256, 0, stream>>>(
        Wtp, TDIM, CDIM, Bt_h, CDIM + TDIM, CDIM, TDIM * CDIM, CDIM * (CDIM + TDIM));
    gemm64<<<dim3(4, 1, NLAYER), 256, 0, stream>>>(mem, nullptr, Wk, nullptr, kbufs,
        MSLOT, MDIM, CDIM, 0, 0, MDIM * CDIM, MSLOT * CDIM);
    gemm64<<<dim3(4, 1, NLAYER), 256, 0, stream>>>(mem, nullptr, Wv, nullptr, vbufs,
        MSLOT, MDIM, CDIM, 0, 0, MDIM * CDIM, MSLOT * CDIM);
    wqk_build<<<dim3(MSLOT, NLAYER), 256, 0, stream>>>(Wq, kbufs, wqkL);

    // ---- CSR ----
    count_deg<<<(E_EDGES + 255) / 256, 256, 0, stream>>>(dstIdx, deg, E_EDGES);
    scan_kernel<<<1, 1024, 0, stream>>>(deg, offs, N_NODES);
    fill_csr<<<(E_EDGES + 255) / 256, 256, 0, stream>>>(srcIdx, dstIdx, offs, cursor, csr_src, E_EDGES);

    int mfmaBlocks = N_NODES / 32;
    int nodeBlocks = N_NODES / 4;

    // node = relu(x @ Wi + bi)
    gemm_mfma<<<mfmaBlocks, 256, 0, stream>>>(xbf, FEAT, FEAT, nullptr, 0, FEAT,
                                              Bt_i, bi, bufA, nodebf, 1);

    float* cur = bufA;
    float* alt = bufB;
    for (int l = 0; l < NLAYER; l++) {
        gemm_h<<<mfmaBlocks, 256, 0, stream>>>(nodebf, CDIM, CDIM, tembbf, TDIM, CDIM + TDIM,
                                               Bt_h + (size_t)l * CDIM * (CDIM + TDIM),
                                               a_s + (size_t)l * CDIM, a_d + (size_t)l * CDIM,
                                               hbf, esrc, edst);
        gat_agg_fused<<<nodeBlocks, 256, 0, stream>>>(hbf, esrc, edst, offs, deg, csr_src,
                                                      wqkL + (size_t)l * MSLOT * CDIM,
                                                      vbufs + (size_t)l * MSLOT * CDIM,
                                                      cur, alt, nodebf, N_NODES);
        float* t = cur; cur = alt; alt = t;
    }

    col_sum<<<128, 256, 0, stream>>>(cur, pooled, N_NODES);
    finalize<<<1, 64, 0, stream>>>(pooled, mem, Wc, bc, out);
}

// Round 5
// 566.306 us; speedup vs baseline: 2.4185x; 1.0835x over previous
//
#include <hip/hip_runtime.h>
#include <hip/hip_bf16.h>

#define N_NODES 20000
#define E_EDGES 320000
#define FEAT 128
#define CDIM 256
#define NHEAD 8
#define HDIM 32
#define NLAYER 5
#define TDIM 64
#define MSLOT 10
#define MDIM 128
#define NCLS 2

typedef unsigned short ushort_t;
typedef short short8 __attribute__((ext_vector_type(8)));
typedef float floatx4 __attribute__((ext_vector_type(4)));

__device__ __forceinline__ ushort_t f2bf(float f) {
    union { float f; unsigned int u; } t; t.f = f;
    unsigned int r = (t.u + 0x7FFF + ((t.u >> 16) & 1)) >> 16;
    return (ushort_t)r;
}
__device__ __forceinline__ float bf2f(ushort_t u) {
    union { float f; unsigned int u; } t; t.u = ((unsigned int)u) << 16;
    return t.f;
}

// ---------------------------------------------------------------------------
// bf16 MFMA GEMM, BM=64, BN=256, BK=32. 4 waves; wave w owns cols [w*64,+64).
// C/D map: row = row0+mt*16+lq*4+r, col = wid*64+nt*16+li. Rows clamped on
// staging, guarded on store (M % 64 != 0).
// ---------------------------------------------------------------------------
__global__ __launch_bounds__(256) void gemm_mfma(
    const ushort_t* __restrict__ A1, int lda1, int K1,
    const ushort_t* __restrict__ A2, int lda2, int Ktot,
    const ushort_t* __restrict__ Bt,
    const float* __restrict__ bias,
    float* Cf, ushort_t* Cbf, int doRelu, int M)
{
    __shared__ __align__(16) ushort_t smemA[64 * 32];
    __shared__ __align__(16) ushort_t smemB[256 * 32];
    int tid = threadIdx.x;
    int lane = tid & 63, wid = tid >> 6;
    int li = lane & 15, lq = lane >> 4;
    int row0 = blockIdx.x * 64;

    floatx4 acc[4][4];
#pragma unroll
    for (int a = 0; a < 4; a++)
#pragma unroll
        for (int b = 0; b < 4; b++) acc[a][b] = {0.f, 0.f, 0.f, 0.f};

    int ar = tid >> 2, ac = tid & 3;
    int agc = (ac - (ar >> 1)) & 3;
    int arow = row0 + ar; if (arow >= M) arow = M - 1;

    for (int k0 = 0; k0 < Ktot; k0 += 32) {
        __syncthreads();
        const ushort_t* Ab; int lda;
        if (k0 < K1) { Ab = A1 + k0; lda = lda1; }
        else         { Ab = A2 + (k0 - K1); lda = lda2; }
        {
            const void* g = (const void*)(Ab + (size_t)arow * lda + agc * 8);
            __builtin_amdgcn_global_load_lds(
                (const __attribute__((address_space(1))) void*)g,
                (__attribute__((address_space(3))) void*)&smemA[wid * 512], 16, 0, 0);
        }
#pragma unroll
        for (int j = 0; j < 4; j++) {
            int slot = wid * 256 + j * 64 + lane;
            int n = slot >> 2, c = slot & 3;
            int gc = (c - (n >> 1)) & 3;
            const void* g = (const void*)(Bt + (size_t)n * Ktot + k0 + gc * 8);
            __builtin_amdgcn_global_load_lds(
                (const __attribute__((address_space(1))) void*)g,
                (__attribute__((address_space(3))) void*)&smemB[(wid * 256 + j * 64) * 8], 16, 0, 0);
        }
        __syncthreads();

        short8 af[4], bfr[4];
#pragma unroll
        for (int mt = 0; mt < 4; mt++) {
            int m = mt * 16 + li;
            int sw = (lq + (m >> 1)) & 3;
            af[mt] = *(const short8*)&smemA[m * 32 + sw * 8];
        }
#pragma unroll
        for (int nt = 0; nt < 4; nt++) {
            int n = wid * 64 + nt * 16 + li;
            int sw = (lq + (n >> 1)) & 3;
            bfr[nt] = *(const short8*)&smemB[n * 32 + sw * 8];
        }
#pragma unroll
        for (int mt = 0; mt < 4; mt++)
#pragma unroll
            for (int nt = 0; nt < 4; nt++)
                acc[mt][nt] = __builtin_amdgcn_mfma_f32_16x16x32_bf16(af[mt], bfr[nt], acc[mt][nt], 0, 0, 0);
    }

#pragma unroll
    for (int mt = 0; mt < 4; mt++) {
        int row = row0 + mt * 16 + lq * 4;
#pragma unroll
        for (int nt = 0; nt < 4; nt++) {
            int col = wid * 64 + nt * 16 + li;
            float bv = bias ? bias[col] : 0.f;
#pragma unroll
            for (int r = 0; r < 4; r++) {
                if (row + r < M) {
                    float v = acc[mt][nt][r] + bv;
                    if (doRelu) v = fmaxf(v, 0.f);
                    if (Cf)  Cf[(size_t)(row + r) * CDIM + col] = v;
                    if (Cbf) Cbf[(size_t)(row + r) * CDIM + col] = f2bf(v);
                }
            }
        }
    }
}

// h-GEMM (BM=64) with fused head-logits epilogue: writes hbf + esrc/edst
__global__ __launch_bounds__(256) void gemm_h(
    const ushort_t* __restrict__ A1, int lda1, int K1,
    const ushort_t* __restrict__ A2, int lda2, int Ktot,
    const ushort_t* __restrict__ Bt,
    const float* __restrict__ a_s, const float* __restrict__ a_d,
    ushort_t* __restrict__ Cbf,
    float* __restrict__ esrc, float* __restrict__ edst, int M)
{
    __shared__ __align__(16) ushort_t smemA[64 * 32];
    __shared__ __align__(16) ushort_t smemB[256 * 32];
    __shared__ float eldsS[64][8];
    __shared__ float eldsD[64][8];
    int tid = threadIdx.x;
    int lane = tid & 63, wid = tid >> 6;
    int li = lane & 15, lq = lane >> 4;
    int row0 = blockIdx.x * 64;

    floatx4 acc[4][4];
#pragma unroll
    for (int a = 0; a < 4; a++)
#pragma unroll
        for (int b = 0; b < 4; b++) acc[a][b] = {0.f, 0.f, 0.f, 0.f};

    int ar = tid >> 2, ac = tid & 3;
    int agc = (ac - (ar >> 1)) & 3;
    int arow = row0 + ar; if (arow >= M) arow = M - 1;

    for (int k0 = 0; k0 < Ktot; k0 += 32) {
        __syncthreads();
        const ushort_t* Ab; int lda;
        if (k0 < K1) { Ab = A1 + k0; lda = lda1; }
        else         { Ab = A2 + (k0 - K1); lda = lda2; }
        {
            const void* g = (const void*)(Ab + (size_t)arow * lda + agc * 8);
            __builtin_amdgcn_global_load_lds(
                (const __attribute__((address_space(1))) void*)g,
                (__attribute__((address_space(3))) void*)&smemA[wid * 512], 16, 0, 0);
        }
#pragma unroll
        for (int j = 0; j < 4; j++) {
            int slot = wid * 256 + j * 64 + lane;
            int n = slot >> 2, c = slot & 3;
            int gc = (c - (n >> 1)) & 3;
            const void* g = (const void*)(Bt + (size_t)n * Ktot + k0 + gc * 8);
            __builtin_amdgcn_global_load_lds(
                (const __attribute__((address_space(1))) void*)g,
                (__attribute__((address_space(3))) void*)&smemB[(wid * 256 + j * 64) * 8], 16, 0, 0);
        }
        __syncthreads();

        short8 af[4], bfr[4];
#pragma unroll
        for (int mt = 0; mt < 4; mt++) {
            int m = mt * 16 + li;
            int sw = (lq + (m >> 1)) & 3;
            af[mt] = *(const short8*)&smemA[m * 32 + sw * 8];
        }
#pragma unroll
        for (int nt = 0; nt < 4; nt++) {
            int n = wid * 64 + nt * 16 + li;
            int sw = (lq + (n >> 1)) & 3;
            bfr[nt] = *(const short8*)&smemB[n * 32 + sw * 8];
        }
#pragma unroll
        for (int mt = 0; mt < 4; mt++)
#pragma unroll
            for (int nt = 0; nt < 4; nt++)
                acc[mt][nt] = __builtin_amdgcn_mfma_f32_16x16x32_bf16(af[mt], bfr[nt], acc[mt][nt], 0, 0, 0);
    }

    float as4[4], ad4[4];
#pragma unroll
    for (int nt = 0; nt < 4; nt++) {
        int col = wid * 64 + nt * 16 + li;
        as4[nt] = a_s[col];
        ad4[nt] = a_d[col];
    }
#pragma unroll
    for (int mt = 0; mt < 4; mt++) {
        int row = row0 + mt * 16 + lq * 4;
#pragma unroll
        for (int nt = 0; nt < 4; nt++) {
            int col = wid * 64 + nt * 16 + li;
#pragma unroll
            for (int r = 0; r < 4; r++)
                if (row + r < M)
                    Cbf[(size_t)(row + r) * CDIM + col] = f2bf(acc[mt][nt][r]);
        }
#pragma unroll
        for (int r = 0; r < 4; r++) {
            int row_local = mt * 16 + lq * 4 + r;
            float psA = acc[mt][0][r] * as4[0] + acc[mt][1][r] * as4[1];
            float psB = acc[mt][2][r] * as4[2] + acc[mt][3][r] * as4[3];
            float pdA = acc[mt][0][r] * ad4[0] + acc[mt][1][r] * ad4[1];
            float pdB = acc[mt][2][r] * ad4[2] + acc[mt][3][r] * ad4[3];
#pragma unroll
            for (int d = 1; d < 16; d <<= 1) {
                psA += __shfl_xor(psA, d); psB += __shfl_xor(psB, d);
                pdA += __shfl_xor(pdA, d); pdB += __shfl_xor(pdB, d);
            }
            if (li == 0) {
                eldsS[row_local][2 * wid + 0] = psA;
                eldsS[row_local][2 * wid + 1] = psB;
                eldsD[row_local][2 * wid + 0] = pdA;
                eldsD[row_local][2 * wid + 1] = pdB;
            }
        }
    }
    __syncthreads();
#pragma unroll
    for (int rr = 0; rr < 2; rr++) {
        int row = rr * 32 + (tid >> 3), hh = tid & 7;
        if (row0 + row < M) {
            esrc[(size_t)(row0 + row) * NHEAD + hh] = eldsS[row][hh];
            edst[(size_t)(row0 + row) * NHEAD + hh] = eldsD[row][hh];
        }
    }
}

// ---------------------------------------------------------------------------
// fp32 tiled GEMM (tiny matmuls), batched.
// ---------------------------------------------------------------------------
__global__ __launch_bounds__(256) void gemm64(
    const float* __restrict__ A, const float* __restrict__ A2,
    const float* __restrict__ B, const float* __restrict__ bias,
    float* __restrict__ C, int M, int K, int Nf, int doRelu,
    int sA, int sB, int sC)
{
    __shared__ float As[16][64];
    __shared__ float Bs[16][64];
    A += (size_t)blockIdx.z * sA;
    B += (size_t)blockIdx.z * sB;
    C += (size_t)blockIdx.z * sC;
    int tid = threadIdx.x;
    int tx = tid & 15, ty = tid >> 4;
    int row0 = blockIdx.y * 64, col0 = blockIdx.x * 64;
    int ar = tid >> 2;
    int ac = (tid & 3) * 4;

    float acc[4][4] = {};

    for (int k0 = 0; k0 < K; k0 += 16) {
        int arow = row0 + ar;
        float4 av = make_float4(0.f, 0.f, 0.f, 0.f);
        if (arow < M) {
            av = *(const float4*)(A + (size_t)arow * K + k0 + ac);
            if (A2) {
                float4 a2 = *(const float4*)(A2 + (size_t)arow * K + k0 + ac);
                av.x += a2.x; av.y += a2.y; av.z += a2.z; av.w += a2.w;
            }
        }
        As[ac + 0][ar] = av.x;
        As[ac + 1][ar] = av.y;
        As[ac + 2][ar] = av.z;
        As[ac + 3][ar] = av.w;
        float4 bv = *(const float4*)(B + (size_t)(k0 + (tid >> 4)) * Nf + col0 + (tid & 15) * 4);
        *(float4*)&Bs[tid >> 4][(tid & 15) * 4] = bv;
        __syncthreads();
#pragma unroll
        for (int kk = 0; kk < 16; kk++) {
            float4 a = *(const float4*)&As[kk][ty * 4];
            float4 b = *(const float4*)&Bs[kk][tx * 4];
            acc[0][0] += a.x * b.x; acc[0][1] += a.x * b.y; acc[0][2] += a.x * b.z; acc[0][3] += a.x * b.w;
            acc[1][0] += a.y * b.x; acc[1][1] += a.y * b.y; acc[1][2] += a.y * b.z; acc[1][3] += a.y * b.w;
            acc[2][0] += a.z * b.x; acc[2][1] += a.z * b.y; acc[2][2] += a.z * b.z; acc[2][3] += a.z * b.w;
            acc[3][0] += a.w * b.x; acc[3][1] += a.w * b.y; acc[3][2] += a.w * b.z; acc[3][3] += a.w * b.w;
        }
        __syncthreads();
    }

    float4 bv = make_float4(0.f, 0.f, 0.f, 0.f);
    if (bias) bv = *(const float4*)(bias + col0 + tx * 4);
#pragma unroll
    for (int i = 0; i < 4; i++) {
        int r = row0 + ty * 4 + i;
        if (r < M) {
            float4 o;
            o.x = acc[i][0] + bv.x;
            o.y = acc[i][1] + bv.y;
            o.z = acc[i][2] + bv.z;
            o.w = acc[i][3] + bv.w;
            if (doRelu) {
                o.x = fmaxf(o.x, 0.f); o.y = fmaxf(o.y, 0.f);
                o.z = fmaxf(o.z, 0.f); o.w = fmaxf(o.w, 0.f);
            }
            *(float4*)(C + (size_t)r * Nf + col0 + tx * 4) = o;
        }
    }
}

// ---------------------------------------------------------------------------
// Prep kernels
// ---------------------------------------------------------------------------
__global__ void cvt_bf16(const float* __restrict__ in, ushort_t* __restrict__ out, int n)
{
    int i = blockIdx.x * blockDim.x + threadIdx.x;
    if (i < n) out[i] = f2bf(in[i]);
}

__global__ __launch_bounds__(256) void transpose_cast(
    const float* __restrict__ in, int K, int Nn,
    ushort_t* __restrict__ out, int ostride, int koff,
    int inBatchStride, int outBatchStride)
{
    __shared__ float tile[32][33];
    in  += (size_t)blockIdx.z * inBatchStride;
    out += (size_t)blockIdx.z * outBatchStride;
    int k0 = blockIdx.y * 32, n0 = blockIdx.x * 32;
    int tx = threadIdx.x & 31, ty = threadIdx.x >> 5;
#pragma unroll
    for (int j = 0; j < 4; j++)
        tile[ty + j * 8][tx] = in[(size_t)(k0 + ty + j * 8) * Nn + n0 + tx];
    __syncthreads();
#pragma unroll
    for (int j = 0; j < 4; j++) {
        int n = n0 + ty + j * 8;
        out[(size_t)n * ostride + koff + k0 + tx] = f2bf(tile[tx][ty + j * 8]);
    }
}

// Wqk[l][j][d] = (1/16) * sum_c Wq[l][d][c] * kbuf[l][j][c]
__global__ __launch_bounds__(256) void wqk_build(
    const float* __restrict__ Wq, const float* __restrict__ kbufs,
    float* __restrict__ wqk)
{
    int j = blockIdx.x, l = blockIdx.y;
    int d = threadIdx.x;
    __shared__ float kk[CDIM];
    kk[d] = kbufs[((size_t)l * MSLOT + j) * CDIM + d];
    __syncthreads();
    const float* wrow = Wq + ((size_t)l * CDIM + d) * CDIM;
    float acc = 0.f;
#pragma unroll 4
    for (int c = 0; c < CDIM; c++) acc += wrow[c] * kk[c];
    wqk[((size_t)l * MSLOT + j) * CDIM + d] = acc * 0.0625f;
}

// ---------------------------------------------------------------------------
// CSR construction
// ---------------------------------------------------------------------------
__global__ void count_deg(const int* __restrict__ dst, int* __restrict__ deg, int ne)
{
    int e = blockIdx.x * blockDim.x + threadIdx.x;
    if (e < ne) atomicAdd(&deg[dst[e]], 1);
}

__global__ __launch_bounds__(1024) void scan_kernel(const int* __restrict__ deg,
                                                    int* __restrict__ offs, int n)
{
    __shared__ int swt[16];
    __shared__ int srun;
    int tid = threadIdx.x, lane = tid & 63, wid = tid >> 6;
    if (tid == 0) srun = 0;
    __syncthreads();
    for (int base = 0; base < n; base += 1024) {
        int v = (base + tid < n) ? deg[base + tid] : 0;
        int x = v;
#pragma unroll
        for (int d = 1; d < 64; d <<= 1) {
            int t = __shfl_up(x, d);
            if (lane >= d) x += t;
        }
        if (lane == 63) swt[wid] = x;
        __syncthreads();
        if (wid == 0) {
            int w = (lane < 16) ? swt[lane] : 0;
#pragma unroll
            for (int d = 1; d < 16; d <<= 1) {
                int t = __shfl_up(w, d);
                if (lane >= d) w += t;
            }
            if (lane < 16) swt[lane] = w;
        }
        __syncthreads();
        int wbase = (wid == 0) ? 0 : swt[wid - 1];
        int total = swt[15];
        int run = srun;
        if (base + tid < n) offs[base + tid] = run + wbase + x - v;
        __syncthreads();
        if (tid == 0) srun = run + total;
        __syncthreads();
    }
}

__global__ void fill_csr(const int* __restrict__ src, const int* __restrict__ dst,
                         const int* __restrict__ offs, int* __restrict__ cursor,
                         int* __restrict__ csr_src, int ne)
{
    int e = blockIdx.x * blockDim.x + threadIdx.x;
    if (e < ne) {
        int d = dst[e];
        int p = atomicAdd(&cursor[d], 1);
        csr_src[offs[d] + p] = src[e];
    }
}

// ---------------------------------------------------------------------------
// Fully fused GAT + cross-attn. Phase 1 uses (edge,head)-per-lane layout:
// 8 edges x 8 heads per iteration, per-head reductions are shfl_xor 8/16/32
// (7 shfls total vs 96 in the per-head-butterfly variant). Alpha stored
// unnormalized in LDS [e*9+h] (conflict-free), normalized by 1/den at the end.
// wqk/v read directly from global (L2-resident, 10 KB) - no LDS staging.
// out = relu(gat + softmax(gat.Wqk).v + cur)
// ---------------------------------------------------------------------------
__global__ __launch_bounds__(256) void gat_agg_fused(
    const ushort_t* __restrict__ h, const float* __restrict__ esrc, const float* __restrict__ edst,
    const int* __restrict__ offs, const int* __restrict__ deg, const int* __restrict__ csr_src,
    const float* __restrict__ wqk, const float* __restrict__ vbuf,
    const float* __restrict__ cur,
    float* __restrict__ outf, ushort_t* __restrict__ outbf, int n)
{
    __shared__ float alphaL[4][576];   // [e*9 + head]
    __shared__ int   sIdx[4][64];
    int tid = threadIdx.x;
    int lane = tid & 63;
    int wslot = tid >> 6;
    int node = blockIdx.x * 4 + wslot;
    int start = offs[node], cnt = deg[node];
    int chead = lane >> 3;

    float4 gat4;
    if (cnt <= 64) {
        int eh = lane >> 3, hh = lane & 7;
        float edl = edst[(size_t)node * NHEAD + hh];
        int sl = 0;
        if (lane < cnt) sl = csr_src[start + lane];
        sIdx[wslot][lane] = sl;
        __builtin_amdgcn_s_waitcnt(0);   // wave-local LDS visibility
        int nit = (cnt + 7) >> 3;
        float lg[8];
        float m = -3.0e38f;
        for (int it = 0; it < nit; it++) {
            int e = it * 8 + eh;
            float v = -3.0e38f;
            if (e < cnt) {
                int se = sIdx[wslot][e];
                float t = esrc[(size_t)se * NHEAD + hh] + edl;
                v = t > 0.f ? t : 0.2f * t;
            }
            lg[it] = v;
            m = fmaxf(m, v);
        }
        m = fmaxf(m, __shfl_xor(m, 8));
        m = fmaxf(m, __shfl_xor(m, 16));
        m = fmaxf(m, __shfl_xor(m, 32));
        float den = 0.f;
        for (int it = 0; it < nit; it++) {
            int e = it * 8 + eh;
            float w = 0.f;
            if (e < cnt) w = __expf(lg[it] - m);
            den += w;
            alphaL[wslot][e * 9 + hh] = w;
        }
        den += __shfl_xor(den, 8);
        den += __shfl_xor(den, 16);
        den += __shfl_xor(den, 32);
        float inv = 1.f / (den + 1e-16f);
        float invc = __shfl(inv, chead);   // inv for this lane's channel head
        __builtin_amdgcn_s_waitcnt(0);

        float4 acc = make_float4(0.f, 0.f, 0.f, 0.f);
        const float* aBase = &alphaL[wslot][chead];
        const int* sBase = sIdx[wslot];
        int rounds = (cnt + 3) >> 2;     // tail alphas are 0, sIdx 0 => no-op
        for (int rr = 0; rr < rounds; rr++) {
            int i0 = rr * 4;
            int s0 = sBase[i0 + 0], s1 = sBase[i0 + 1], s2 = sBase[i0 + 2], s3 = sBase[i0 + 3];
            float a0 = aBase[(i0 + 0) * 9], a1 = aBase[(i0 + 1) * 9];
            float a2 = aBase[(i0 + 2) * 9], a3 = aBase[(i0 + 3) * 9];
            ushort4 h0 = *(const ushort4*)(h + (size_t)s0 * CDIM + lane * 4);
            ushort4 h1 = *(const ushort4*)(h + (size_t)s1 * CDIM + lane * 4);
            ushort4 h2 = *(const ushort4*)(h + (size_t)s2 * CDIM + lane * 4);
            ushort4 h3 = *(const ushort4*)(h + (size_t)s3 * CDIM + lane * 4);
            acc.x += a0 * bf2f(h0.x) + a1 * bf2f(h1.x) + a2 * bf2f(h2.x) + a3 * bf2f(h3.x);
            acc.y += a0 * bf2f(h0.y) + a1 * bf2f(h1.y) + a2 * bf2f(h2.y) + a3 * bf2f(h3.y);
            acc.z += a0 * bf2f(h0.z) + a1 * bf2f(h1.z) + a2 * bf2f(h2.z) + a3 * bf2f(h3.z);
            acc.w += a0 * bf2f(h0.w) + a1 * bf2f(h1.w) + a2 * bf2f(h2.w) + a3 * bf2f(h3.w);
        }
        gat4.x = fmaxf(acc.x * invc, 0.f);
        gat4.y = fmaxf(acc.y * invc, 0.f);
        gat4.z = fmaxf(acc.z * invc, 0.f);
        gat4.w = fmaxf(acc.w * invc, 0.f);
    } else {
        // slow path (deg > 64): two-pass serial (rare)
        int hh = lane & 7;
        float edl = edst[node * NHEAD + hh];
        float m = -3.0e38f;
        int i8 = lane >> 3;
        for (int i = 0; i < cnt; i += 8) {
            int ii = i + i8;
            if (ii < cnt) {
                int s = csr_src[start + ii];
                float lgv = esrc[s * NHEAD + hh] + edl;
                lgv = lgv > 0.f ? lgv : 0.2f * lgv;
                m = fmaxf(m, lgv);
            }
        }
        m = fmaxf(m, __shfl_xor(m, 8));
        m = fmaxf(m, __shfl_xor(m, 16));
        m = fmaxf(m, __shfl_xor(m, 32));
        float4 acc = make_float4(0.f, 0.f, 0.f, 0.f);
        float den = 0.f;
        for (int i = 0; i < cnt; i++) {
            int s = csr_src[start + i];
            float lgv = esrc[s * NHEAD + hh] + edl;
            lgv = lgv > 0.f ? lgv : 0.2f * lgv;
            float w = __expf(lgv - m);
            den += w;
            float wc = __shfl(w, chead);
            ushort4 hu = *(const ushort4*)(h + (size_t)s * CDIM + lane * 4);
            acc.x += wc * bf2f(hu.x); acc.y += wc * bf2f(hu.y);
            acc.z += wc * bf2f(hu.z); acc.w += wc * bf2f(hu.w);
        }
        float dc = __shfl(den, chead) + 1e-16f;
        float inv = 1.f / dc;
        gat4.x = fmaxf(acc.x * inv, 0.f);
        gat4.y = fmaxf(acc.y * inv, 0.f);
        gat4.z = fmaxf(acc.z * inv, 0.f);
        gat4.w = fmaxf(acc.w * inv, 0.f);
    }

    // --- cross-attention epilogue: wqk/v direct from global (L2) ---
    float s[MSLOT];
#pragma unroll
    for (int j = 0; j < MSLOT; j++) {
        float4 w4 = *(const float4*)(wqk + j * CDIM + lane * 4);
        s[j] = gat4.x * w4.x + gat4.y * w4.y + gat4.z * w4.z + gat4.w * w4.w;
    }
#pragma unroll
    for (int d = 1; d < 64; d <<= 1) {
#pragma unroll
        for (int j = 0; j < MSLOT; j++) s[j] += __shfl_xor(s[j], d);
    }
    float m = s[0];
#pragma unroll
    for (int j = 1; j < MSLOT; j++) m = fmaxf(m, s[j]);
    float sum = 0.f;
#pragma unroll
    for (int j = 0; j < MSLOT; j++) { s[j] = __expf(s[j] - m); sum += s[j]; }
    float inv = 1.f / sum;

    float4 c4 = *(const float4*)(cur + (size_t)node * CDIM + lane * 4);
    float4 o;
    o.x = gat4.x + c4.x; o.y = gat4.y + c4.y; o.z = gat4.z + c4.z; o.w = gat4.w + c4.w;
#pragma unroll
    for (int j = 0; j < MSLOT; j++) {
        float p = s[j] * inv;
        float4 v4 = *(const float4*)(vbuf + j * CDIM + lane * 4);
        o.x += p * v4.x; o.y += p * v4.y; o.z += p * v4.z; o.w += p * v4.w;
    }
    o.x = fmaxf(o.x, 0.f); o.y = fmaxf(o.y, 0.f); o.z = fmaxf(o.z, 0.f); o.w = fmaxf(o.w, 0.f);
    *(float4*)(outf + (size_t)node * CDIM + lane * 4) = o;
    ushort4 ob;
    ob.x = f2bf(o.x); ob.y = f2bf(o.y); ob.z = f2bf(o.z); ob.w = f2bf(o.w);
    *(ushort4*)(outbf + (size_t)node * CDIM + lane * 4) = ob;
}

// ---------------------------------------------------------------------------
__global__ void col_sum(const float* __restrict__ node, float* __restrict__ pooled, int n)
{
    float acc = 0.f;
    int c = threadIdx.x;
    for (int r = blockIdx.x; r < n; r += gridDim.x) acc += node[(size_t)r * CDIM + c];
    atomicAdd(&pooled[c], acc);
}

__global__ void finalize(const float* __restrict__ pooled, const float* __restrict__ mem,
                         const float* __restrict__ Wc, const float* __restrict__ bc,
                         float* __restrict__ out)
{
    int lane = threadIdx.x;
    float a0 = 0.f, a1 = 0.f;
    for (int i = lane; i < CDIM + MDIM; i += 64) {
        float f;
        if (i < CDIM) {
            f = pooled[i] * (1.0f / (float)N_NODES);
        } else {
            float s = 0.f;
            for (int r = 0; r < MSLOT; r++) s += mem[r * MDIM + (i - CDIM)];
            f = s * (1.0f / (float)MSLOT);
        }
        a0 += f * Wc[i * NCLS + 0];
        a1 += f * Wc[i * NCLS + 1];
    }
#pragma unroll
    for (int d = 1; d < 64; d <<= 1) { a0 += __shfl_xor(a0, d); a1 += __shfl_xor(a1, d); }
    if (lane == 0) { out[0] = a0 + bc[0]; out[1] = a1 + bc[1]; }
}

// ---------------------------------------------------------------------------
extern "C" void kernel_launch(void* const* d_in, const int* in_sizes, int n_in,
                              void* d_out, int out_size, void* d_ws, size_t ws_size,
                              hipStream_t stream)
{
    const float* x    = (const float*)d_in[0];
    const int*   ei   = (const int*)d_in[1];
    const float* temb = (const float*)d_in[2];
    const float* Wi   = (const float*)d_in[3];
    const float* bi   = (const float*)d_in[4];
    const float* Wg   = (const float*)d_in[5];
    const float* a_s  = (const float*)d_in[6];
    const float* a_d  = (const float*)d_in[7];
    const float* Wt   = (const float*)d_in[8];
    const float* Wq   = (const float*)d_in[9];
    const float* Wk   = (const float*)d_in[10];
    const float* Wv   = (const float*)d_in[11];
    const float* mem  = (const float*)d_in[12];
    const float* Wc   = (const float*)d_in[13];
    const float* bc   = (const float*)d_in[14];
    float* out = (float*)d_out;
    char* ws = (char*)d_ws;

    const size_t NC_BYTES  = (size_t)N_NODES * CDIM * 4;
    const size_t NCB_BYTES = (size_t)N_NODES * CDIM * 2;
    size_t off = 0;
    float* bufA   = (float*)(ws + off); off += NC_BYTES;      // node fp32
    float* bufB   = (float*)(ws + off); off += NC_BYTES;      // next node fp32
    ushort_t* hbf    = (ushort_t*)(ws + off); off += NCB_BYTES;
    ushort_t* nodebf = (ushort_t*)(ws + off); off += NCB_BYTES;
    ushort_t* xbf    = (ushort_t*)(ws + off); off += (size_t)N_NODES * FEAT * 2;
    ushort_t* tembbf = (ushort_t*)(ws + off); off += (size_t)N_NODES * TDIM * 2;
    float* esrc   = (float*)(ws + off); off += (size_t)N_NODES * NHEAD * 4;
    float* edst   = (float*)(ws + off); off += (size_t)N_NODES * NHEAD * 4;
    float* kbufs  = (float*)(ws + off); off += (size_t)NLAYER * MSLOT * CDIM * 4;
    float* vbufs  = (float*)(ws + off); off += (size_t)NLAYER * MSLOT * CDIM * 4;
    float* wqkL   = (float*)(ws + off); off += (size_t)NLAYER * MSLOT * CDIM * 4;
    float* Wtp    = (float*)(ws + off); off += (size_t)NLAYER * TDIM * CDIM * 4;
    ushort_t* Bt_i = (ushort_t*)(ws + off); off += (size_t)CDIM * FEAT * 2;
    ushort_t* Bt_h = (ushort_t*)(ws + off); off += (size_t)NLAYER * CDIM * (CDIM + TDIM) * 2;
    size_t zero_base = off;
    float* pooled = (float*)(ws + off); off += CDIM * 4;
    int* deg      = (int*)(ws + off);   off += N_NODES * 4;
    int* cursor   = (int*)(ws + off);   off += N_NODES * 4;
    size_t zero_len = off - zero_base;
    int* offs     = (int*)(ws + off);   off += (N_NODES + 4) * 4;
    int* csr_src  = (int*)(ws + off);   off += (size_t)E_EDGES * 4;

    const int* srcIdx = ei;
    const int* dstIdx = ei + E_EDGES;

    hipMemsetAsync(ws + zero_base, 0, zero_len, stream);

    // ---- prep ----
    cvt_bf16<<<(N_NODES * FEAT + 255) / 256, 256, 0, stream>>>(x, xbf, N_NODES * FEAT);
    cvt_bf16<<<(N_NODES * TDIM + 255) / 256, 256, 0, stream>>>(temb, tembbf, N_NODES * TDIM);
    gemm64<<<dim3(4, 1, NLAYER), 256, 0, stream>>>(Wt, nullptr, Wg, nullptr, Wtp,
        TDIM, CDIM, CDIM, 0, TDIM * CDIM, CDIM * CDIM, TDIM * CDIM);
    transpose_cast<<<dim3(CDIM / 32, FEAT / 32, 1), 256, 0, stream>>>(
        Wi, FEAT, CDIM, Bt_i, FEAT, 0, 0, 0);
    transpose_cast<<<dim3(CDIM / 32, CDIM / 32, NLAYER), 256, 0, stream>>>(
        Wg, CDIM, CDIM, Bt_h, CDIM + TDIM, 0, CDIM * CDIM, CDIM * (CDIM + TDIM));
    transpose_cast<<<dim3(CDIM / 32, TDIM / 32, NLAYER), 256, 0, stream>>>(
        Wtp, TDIM, CDIM, Bt_h, CDIM + TDIM, CDIM, TDIM * CDIM, CDIM * (CDIM + TDIM));
    gemm64<<<dim3(4, 1, NLAYER), 256, 0, stream>>>(mem, nullptr, Wk, nullptr, kbufs,
        MSLOT, MDIM, CDIM, 0, 0, MDIM * CDIM, MSLOT * CDIM);
    gemm64<<<dim3(4, 1, NLAYER), 256, 0, stream>>>(mem, nullptr, Wv, nullptr, vbufs,
        MSLOT, MDIM, CDIM, 0, 0, MDIM * CDIM, MSLOT * CDIM);
    wqk_build<<<dim3(MSLOT, NLAYER), 256, 0, stream>>>(Wq, kbufs, wqkL);

    // ---- CSR ----
    count_deg<<<(E_EDGES + 255) / 256, 256, 0, stream>>>(dstIdx, deg, E_EDGES);
    scan_kernel<<<1, 1024, 0, stream>>>(deg, offs, N_NODES);
    fill_csr<<<(E_EDGES + 255) / 256, 256, 0, stream>>>(srcIdx, dstIdx, offs, cursor, csr_src, E_EDGES);

    int mfmaBlocks = (N_NODES + 63) / 64;   // 313
    int nodeBlocks = N_NODES / 4;

    // node = relu(x @ Wi + bi)
    gemm_mfma<<<mfmaBlocks, 256, 0, stream>>>(xbf, FEAT, FEAT, nullptr, 0, FEAT,
                                              Bt_i, bi, bufA, nodebf, 1, N_NODES);

    float* cur = bufA;
    float* alt = bufB;
    for (int l = 0; l < NLAYER; l++) {
        gemm_h<<<mfmaBlocks, 256, 0, stream>>>(nodebf, CDIM, CDIM, tembbf, TDIM, CDIM + TDIM,
                                               Bt_h + (size_t)l * CDIM * (CDIM + TDIM),
                                               a_s + (size_t)l * CDIM, a_d + (size_t)l * CDIM,
                                               hbf, esrc, edst, N_NODES);
        gat_agg_fused<<<nodeBlocks, 256, 0, stream>>>(hbf, esrc, edst, offs, deg, csr_src,
                                                      wqkL + (size_t)l * MSLOT * CDIM,
                                                      vbufs + (size_t)l * MSLOT * CDIM,
                                                      cur, alt, nodebf, N_NODES);
        float* t = cur; cur = alt; alt = t;
    }

    col_sum<<<128, 256, 0, stream>>>(cur, pooled, N_NODES);
    finalize<<<1, 64, 0, stream>>>(pooled, mem, Wc, bc, out);
}

// Round 6
// 518.016 us; speedup vs baseline: 2.6440x; 1.0932x over previous
//
#include <hip/hip_runtime.h>
#include <hip/hip_bf16.h>

#define N_NODES 20000
#define E_EDGES 320000
#define FEAT 128
#define CDIM 256
#define NHEAD 8
#define HDIM 32
#define NLAYER 5
#define TDIM 64
#define MSLOT 10
#define MDIM 128
#define NCLS 2

typedef unsigned short ushort_t;
typedef short short8 __attribute__((ext_vector_type(8)));
typedef float floatx4 __attribute__((ext_vector_type(4)));

__device__ __forceinline__ ushort_t f2bf(float f) {
    union { float f; unsigned int u; } t; t.f = f;
    unsigned int r = (t.u + 0x7FFF + ((t.u >> 16) & 1)) >> 16;
    return (ushort_t)r;
}
__device__ __forceinline__ float bf2f(ushort_t u) {
    union { float f; unsigned int u; } t; t.u = ((unsigned int)u) << 16;
    return t.f;
}

// ---------------------------------------------------------------------------
// bf16 MFMA GEMM, BM=64, BN=128, BK=32. grid (2, M/64). 4 waves; wave w owns
// cols [col0 + w*32, +32). C/D map: row = row0+mt*16+lq*4+r,
// col = col0 + wid*32 + nt*16 + li. 626 blocks -> good CU balance.
// ---------------------------------------------------------------------------
__global__ __launch_bounds__(256) void gemm_mfma(
    const ushort_t* __restrict__ A1, int lda1, int K1,
    const ushort_t* __restrict__ A2, int lda2, int Ktot,
    const ushort_t* __restrict__ Bt,
    const float* __restrict__ bias,
    float* Cf, ushort_t* Cbf, int doRelu, int M)
{
    __shared__ __align__(16) ushort_t smemA[64 * 32];
    __shared__ __align__(16) ushort_t smemB[128 * 32];
    int tid = threadIdx.x;
    int lane = tid & 63, wid = tid >> 6;
    int li = lane & 15, lq = lane >> 4;
    int row0 = blockIdx.y * 64;
    int col0 = blockIdx.x * 128;

    floatx4 acc[4][2];
#pragma unroll
    for (int a = 0; a < 4; a++)
#pragma unroll
        for (int b = 0; b < 2; b++) acc[a][b] = {0.f, 0.f, 0.f, 0.f};

    int ar = tid >> 2, ac = tid & 3;
    int agc = (ac - (ar >> 1)) & 3;
    int arow = row0 + ar; if (arow >= M) arow = M - 1;

    for (int k0 = 0; k0 < Ktot; k0 += 32) {
        __syncthreads();
        const ushort_t* Ab; int lda;
        if (k0 < K1) { Ab = A1 + k0; lda = lda1; }
        else         { Ab = A2 + (k0 - K1); lda = lda2; }
        {
            const void* g = (const void*)(Ab + (size_t)arow * lda + agc * 8);
            __builtin_amdgcn_global_load_lds(
                (const __attribute__((address_space(1))) void*)g,
                (__attribute__((address_space(3))) void*)&smemA[wid * 512], 16, 0, 0);
        }
#pragma unroll
        for (int j = 0; j < 2; j++) {
            int slot = j * 256 + tid;
            int n = slot >> 2, c = slot & 3;
            int gc = (c - (n >> 1)) & 3;
            const void* g = (const void*)(Bt + (size_t)(col0 + n) * Ktot + k0 + gc * 8);
            __builtin_amdgcn_global_load_lds(
                (const __attribute__((address_space(1))) void*)g,
                (__attribute__((address_space(3))) void*)&smemB[(j * 256 + wid * 64) * 8], 16, 0, 0);
        }
        __syncthreads();

        short8 af[4], bfr[2];
#pragma unroll
        for (int mt = 0; mt < 4; mt++) {
            int m = mt * 16 + li;
            int sw = (lq + (m >> 1)) & 3;
            af[mt] = *(const short8*)&smemA[m * 32 + sw * 8];
        }
#pragma unroll
        for (int nt = 0; nt < 2; nt++) {
            int nl = wid * 32 + nt * 16 + li;
            int sw = (lq + (nl >> 1)) & 3;
            bfr[nt] = *(const short8*)&smemB[nl * 32 + sw * 8];
        }
#pragma unroll
        for (int mt = 0; mt < 4; mt++)
#pragma unroll
            for (int nt = 0; nt < 2; nt++)
                acc[mt][nt] = __builtin_amdgcn_mfma_f32_16x16x32_bf16(af[mt], bfr[nt], acc[mt][nt], 0, 0, 0);
    }

#pragma unroll
    for (int mt = 0; mt < 4; mt++) {
        int row = row0 + mt * 16 + lq * 4;
#pragma unroll
        for (int nt = 0; nt < 2; nt++) {
            int col = col0 + wid * 32 + nt * 16 + li;
            float bv = bias ? bias[col] : 0.f;
#pragma unroll
            for (int r = 0; r < 4; r++) {
                if (row + r < M) {
                    float v = acc[mt][nt][r] + bv;
                    if (doRelu) v = fmaxf(v, 0.f);
                    if (Cf)  Cf[(size_t)(row + r) * CDIM + col] = v;
                    if (Cbf) Cbf[(size_t)(row + r) * CDIM + col] = f2bf(v);
                }
            }
        }
    }
}

// h-GEMM (BM=64,BN=128) with fused head-logits epilogue. Wave wid's 32 cols
// are exactly head hd = blockIdx.x*4+wid: per-row head dot reduces with
// 4 shfl_xor, stored straight to esrc/edst. No LDS epilogue, no extra barrier.
__global__ __launch_bounds__(256) void gemm_h(
    const ushort_t* __restrict__ A1, int lda1, int K1,
    const ushort_t* __restrict__ A2, int lda2, int Ktot,
    const ushort_t* __restrict__ Bt,
    const float* __restrict__ a_s, const float* __restrict__ a_d,
    ushort_t* __restrict__ Cbf,
    float* __restrict__ esrc, float* __restrict__ edst, int M)
{
    __shared__ __align__(16) ushort_t smemA[64 * 32];
    __shared__ __align__(16) ushort_t smemB[128 * 32];
    int tid = threadIdx.x;
    int lane = tid & 63, wid = tid >> 6;
    int li = lane & 15, lq = lane >> 4;
    int row0 = blockIdx.y * 64;
    int col0 = blockIdx.x * 128;

    floatx4 acc[4][2];
#pragma unroll
    for (int a = 0; a < 4; a++)
#pragma unroll
        for (int b = 0; b < 2; b++) acc[a][b] = {0.f, 0.f, 0.f, 0.f};

    int ar = tid >> 2, ac = tid & 3;
    int agc = (ac - (ar >> 1)) & 3;
    int arow = row0 + ar; if (arow >= M) arow = M - 1;

    for (int k0 = 0; k0 < Ktot; k0 += 32) {
        __syncthreads();
        const ushort_t* Ab; int lda;
        if (k0 < K1) { Ab = A1 + k0; lda = lda1; }
        else         { Ab = A2 + (k0 - K1); lda = lda2; }
        {
            const void* g = (const void*)(Ab + (size_t)arow * lda + agc * 8);
            __builtin_amdgcn_global_load_lds(
                (const __attribute__((address_space(1))) void*)g,
                (__attribute__((address_space(3))) void*)&smemA[wid * 512], 16, 0, 0);
        }
#pragma unroll
        for (int j = 0; j < 2; j++) {
            int slot = j * 256 + tid;
            int n = slot >> 2, c = slot & 3;
            int gc = (c - (n >> 1)) & 3;
            const void* g = (const void*)(Bt + (size_t)(col0 + n) * Ktot + k0 + gc * 8);
            __builtin_amdgcn_global_load_lds(
                (const __attribute__((address_space(1))) void*)g,
                (__attribute__((address_space(3))) void*)&smemB[(j * 256 + wid * 64) * 8], 16, 0, 0);
        }
        __syncthreads();

        short8 af[4], bfr[2];
#pragma unroll
        for (int mt = 0; mt < 4; mt++) {
            int m = mt * 16 + li;
            int sw = (lq + (m >> 1)) & 3;
            af[mt] = *(const short8*)&smemA[m * 32 + sw * 8];
        }
#pragma unroll
        for (int nt = 0; nt < 2; nt++) {
            int nl = wid * 32 + nt * 16 + li;
            int sw = (lq + (nl >> 1)) & 3;
            bfr[nt] = *(const short8*)&smemB[nl * 32 + sw * 8];
        }
#pragma unroll
        for (int mt = 0; mt < 4; mt++)
#pragma unroll
            for (int nt = 0; nt < 2; nt++)
                acc[mt][nt] = __builtin_amdgcn_mfma_f32_16x16x32_bf16(af[mt], bfr[nt], acc[mt][nt], 0, 0, 0);
    }

    int hd = blockIdx.x * 4 + wid;
    float as0 = a_s[col0 + wid * 32 + li];
    float as1 = a_s[col0 + wid * 32 + 16 + li];
    float ad0 = a_d[col0 + wid * 32 + li];
    float ad1 = a_d[col0 + wid * 32 + 16 + li];

#pragma unroll
    for (int mt = 0; mt < 4; mt++) {
        int row = row0 + mt * 16 + lq * 4;
#pragma unroll
        for (int nt = 0; nt < 2; nt++) {
            int col = col0 + wid * 32 + nt * 16 + li;
#pragma unroll
            for (int r = 0; r < 4; r++)
                if (row + r < M)
                    Cbf[(size_t)(row + r) * CDIM + col] = f2bf(acc[mt][nt][r]);
        }
#pragma unroll
        for (int r = 0; r < 4; r++) {
            float ps = acc[mt][0][r] * as0 + acc[mt][1][r] * as1;
            float pd = acc[mt][0][r] * ad0 + acc[mt][1][r] * ad1;
#pragma unroll
            for (int d = 1; d < 16; d <<= 1) {
                ps += __shfl_xor(ps, d);
                pd += __shfl_xor(pd, d);
            }
            if (li == 0 && row + r < M) {
                esrc[(size_t)(row + r) * NHEAD + hd] = ps;
                edst[(size_t)(row + r) * NHEAD + hd] = pd;
            }
        }
    }
}

// ---------------------------------------------------------------------------
// fp32 tiled GEMM (tiny matmuls), batched.
// ---------------------------------------------------------------------------
__global__ __launch_bounds__(256) void gemm64(
    const float* __restrict__ A, const float* __restrict__ A2,
    const float* __restrict__ B, const float* __restrict__ bias,
    float* __restrict__ C, int M, int K, int Nf, int doRelu,
    int sA, int sB, int sC)
{
    __shared__ float As[16][64];
    __shared__ float Bs[16][64];
    A += (size_t)blockIdx.z * sA;
    B += (size_t)blockIdx.z * sB;
    C += (size_t)blockIdx.z * sC;
    int tid = threadIdx.x;
    int tx = tid & 15, ty = tid >> 4;
    int row0 = blockIdx.y * 64, col0 = blockIdx.x * 64;
    int ar = tid >> 2;
    int ac = (tid & 3) * 4;

    float acc[4][4] = {};

    for (int k0 = 0; k0 < K; k0 += 16) {
        int arow = row0 + ar;
        float4 av = make_float4(0.f, 0.f, 0.f, 0.f);
        if (arow < M) {
            av = *(const float4*)(A + (size_t)arow * K + k0 + ac);
            if (A2) {
                float4 a2 = *(const float4*)(A2 + (size_t)arow * K + k0 + ac);
                av.x += a2.x; av.y += a2.y; av.z += a2.z; av.w += a2.w;
            }
        }
        As[ac + 0][ar] = av.x;
        As[ac + 1][ar] = av.y;
        As[ac + 2][ar] = av.z;
        As[ac + 3][ar] = av.w;
        float4 bv = *(const float4*)(B + (size_t)(k0 + (tid >> 4)) * Nf + col0 + (tid & 15) * 4);
        *(float4*)&Bs[tid >> 4][(tid & 15) * 4] = bv;
        __syncthreads();
#pragma unroll
        for (int kk = 0; kk < 16; kk++) {
            float4 a = *(const float4*)&As[kk][ty * 4];
            float4 b = *(const float4*)&Bs[kk][tx * 4];
            acc[0][0] += a.x * b.x; acc[0][1] += a.x * b.y; acc[0][2] += a.x * b.z; acc[0][3] += a.x * b.w;
            acc[1][0] += a.y * b.x; acc[1][1] += a.y * b.y; acc[1][2] += a.y * b.z; acc[1][3] += a.y * b.w;
            acc[2][0] += a.z * b.x; acc[2][1] += a.z * b.y; acc[2][2] += a.z * b.z; acc[2][3] += a.z * b.w;
            acc[3][0] += a.w * b.x; acc[3][1] += a.w * b.y; acc[3][2] += a.w * b.z; acc[3][3] += a.w * b.w;
        }
        __syncthreads();
    }

    float4 bv = make_float4(0.f, 0.f, 0.f, 0.f);
    if (bias) bv = *(const float4*)(bias + col0 + tx * 4);
#pragma unroll
    for (int i = 0; i < 4; i++) {
        int r = row0 + ty * 4 + i;
        if (r < M) {
            float4 o;
            o.x = acc[i][0] + bv.x;
            o.y = acc[i][1] + bv.y;
            o.z = acc[i][2] + bv.z;
            o.w = acc[i][3] + bv.w;
            if (doRelu) {
                o.x = fmaxf(o.x, 0.f); o.y = fmaxf(o.y, 0.f);
                o.z = fmaxf(o.z, 0.f); o.w = fmaxf(o.w, 0.f);
            }
            *(float4*)(C + (size_t)r * Nf + col0 + tx * 4) = o;
        }
    }
}

// ---------------------------------------------------------------------------
// Prep kernels
// ---------------------------------------------------------------------------
__global__ void cvt_bf16(const float* __restrict__ in, ushort_t* __restrict__ out, int n)
{
    int i = blockIdx.x * blockDim.x + threadIdx.x;
    if (i < n) out[i] = f2bf(in[i]);
}

__global__ __launch_bounds__(256) void transpose_cast(
    const float* __restrict__ in, int K, int Nn,
    ushort_t* __restrict__ out, int ostride, int koff,
    int inBatchStride, int outBatchStride)
{
    __shared__ float tile[32][33];
    in  += (size_t)blockIdx.z * inBatchStride;
    out += (size_t)blockIdx.z * outBatchStride;
    int k0 = blockIdx.y * 32, n0 = blockIdx.x * 32;
    int tx = threadIdx.x & 31, ty = threadIdx.x >> 5;
#pragma unroll
    for (int j = 0; j < 4; j++)
        tile[ty + j * 8][tx] = in[(size_t)(k0 + ty + j * 8) * Nn + n0 + tx];
    __syncthreads();
#pragma unroll
    for (int j = 0; j < 4; j++) {
        int n = n0 + ty + j * 8;
        out[(size_t)n * ostride + koff + k0 + tx] = f2bf(tile[tx][ty + j * 8]);
    }
}

// Wqk[l][j][d] = (1/16) * sum_c Wq[l][d][c] * kbuf[l][j][c]
__global__ __launch_bounds__(256) void wqk_build(
    const float* __restrict__ Wq, const float* __restrict__ kbufs,
    float* __restrict__ wqk)
{
    int j = blockIdx.x, l = blockIdx.y;
    int d = threadIdx.x;
    __shared__ float kk[CDIM];
    kk[d] = kbufs[((size_t)l * MSLOT + j) * CDIM + d];
    __syncthreads();
    const float* wrow = Wq + ((size_t)l * CDIM + d) * CDIM;
    float acc = 0.f;
#pragma unroll 4
    for (int c = 0; c < CDIM; c++) acc += wrow[c] * kk[c];
    wqk[((size_t)l * MSLOT + j) * CDIM + d] = acc * 0.0625f;
}

// ---------------------------------------------------------------------------
// CSR construction
// ---------------------------------------------------------------------------
__global__ void count_deg(const int* __restrict__ dst, int* __restrict__ deg, int ne)
{
    int e = blockIdx.x * blockDim.x + threadIdx.x;
    if (e < ne) atomicAdd(&deg[dst[e]], 1);
}

// single-pass exclusive scan: thread t owns 20 contiguous elements
__global__ __launch_bounds__(1024) void scan_kernel(const int* __restrict__ deg,
                                                    int* __restrict__ offs, int n)
{
    __shared__ int swt[16];
    int tid = threadIdx.x, lane = tid & 63, wid = tid >> 6;
    int base = tid * 20;
    int v[20];
    int s = 0;
#pragma unroll
    for (int i = 0; i < 20; i++) {
        int d = (base + i < n) ? deg[base + i] : 0;
        v[i] = d; s += d;
    }
    int x = s;
#pragma unroll
    for (int d = 1; d < 64; d <<= 1) {
        int t = __shfl_up(x, d);
        if (lane >= d) x += t;
    }
    if (lane == 63) swt[wid] = x;
    __syncthreads();
    if (wid == 0) {
        int w = (lane < 16) ? swt[lane] : 0;
#pragma unroll
        for (int d = 1; d < 16; d <<= 1) {
            int t = __shfl_up(w, d);
            if (lane >= d) w += t;
        }
        if (lane < 16) swt[lane] = w;
    }
    __syncthreads();
    int wbase = (wid == 0) ? 0 : swt[wid - 1];
    int run = wbase + x - s;
#pragma unroll
    for (int i = 0; i < 20; i++) {
        if (base + i < n) offs[base + i] = run;
        run += v[i];
    }
}

__global__ void fill_csr(const int* __restrict__ src, const int* __restrict__ dst,
                         const int* __restrict__ offs, int* __restrict__ cursor,
                         int* __restrict__ csr_src, int ne)
{
    int e = blockIdx.x * blockDim.x + threadIdx.x;
    if (e < ne) {
        int d = dst[e];
        int p = atomicAdd(&cursor[d], 1);
        csr_src[offs[d] + p] = src[e];
    }
}

// ---------------------------------------------------------------------------
// Fully fused GAT + cross-attn, LDS-free fast path. Phase 1: (edge,head) per
// lane, fully unrolled (deg<=64 -> nit<=8), indices/alphas routed via shfl.
// Phase 2: 8 h-rows in flight per round.
// out = relu(gat + softmax(gat.Wqk).v + cur)
// ---------------------------------------------------------------------------
__global__ __launch_bounds__(256) void gat_agg_fused(
    const ushort_t* __restrict__ h, const float* __restrict__ esrc, const float* __restrict__ edst,
    const int* __restrict__ offs, const int* __restrict__ deg, const int* __restrict__ csr_src,
    const float* __restrict__ wqk, const float* __restrict__ vbuf,
    const float* __restrict__ cur,
    float* __restrict__ outf, ushort_t* __restrict__ outbf, int n)
{
    int tid = threadIdx.x;
    int lane = tid & 63;
    int wslot = tid >> 6;
    int node = blockIdx.x * 4 + wslot;
    int start = offs[node], cnt = deg[node];
    int chead = lane >> 3;

    float4 gat4;
    if (cnt <= 64) {
        int eh = lane >> 3, hh = lane & 7;
        float edl = edst[(size_t)node * NHEAD + hh];
        int sl = (lane < cnt) ? csr_src[start + lane] : 0;
        int nit = (cnt + 7) >> 3;
        float lg[8], w8[8];
        float m = -3.0e38f;
#pragma unroll
        for (int it = 0; it < 8; it++) {
            float v = -3.0e38f;
            if (it < nit) {
                int e = it * 8 + eh;
                int se = __shfl(sl, e);
                if (e < cnt) {
                    float t = esrc[(size_t)se * NHEAD + hh] + edl;
                    v = t > 0.f ? t : 0.2f * t;
                }
            }
            lg[it] = v;
            m = fmaxf(m, v);
        }
        m = fmaxf(m, __shfl_xor(m, 8));
        m = fmaxf(m, __shfl_xor(m, 16));
        m = fmaxf(m, __shfl_xor(m, 32));
        float den = 0.f;
#pragma unroll
        for (int it = 0; it < 8; it++) {
            float w = 0.f;
            if (it < nit) {
                int e = it * 8 + eh;
                if (e < cnt) w = __expf(lg[it] - m);
            }
            w8[it] = w;
            den += w;
        }
        den += __shfl_xor(den, 8);
        den += __shfl_xor(den, 16);
        den += __shfl_xor(den, 32);
        float inv = 1.f / (den + 1e-16f);
        float invc = __shfl(inv, chead);

        float4 acc = make_float4(0.f, 0.f, 0.f, 0.f);
#pragma unroll
        for (int rr = 0; rr < 8; rr++) {
            if (rr < nit) {
                int sv[8]; float av[8];
#pragma unroll
                for (int k = 0; k < 8; k++) {
                    sv[k] = __shfl(sl, rr * 8 + k);
                    av[k] = __shfl(w8[rr], (k << 3) | chead);
                }
                ushort4 hv[8];
#pragma unroll
                for (int k = 0; k < 8; k++)
                    hv[k] = *(const ushort4*)(h + (size_t)sv[k] * CDIM + lane * 4);
#pragma unroll
                for (int k = 0; k < 8; k++) {
                    acc.x += av[k] * bf2f(hv[k].x);
                    acc.y += av[k] * bf2f(hv[k].y);
                    acc.z += av[k] * bf2f(hv[k].z);
                    acc.w += av[k] * bf2f(hv[k].w);
                }
            }
        }
        gat4.x = fmaxf(acc.x * invc, 0.f);
        gat4.y = fmaxf(acc.y * invc, 0.f);
        gat4.z = fmaxf(acc.z * invc, 0.f);
        gat4.w = fmaxf(acc.w * invc, 0.f);
    } else {
        // slow path (deg > 64): two-pass serial (rare)
        int hh = lane & 7;
        float edl = edst[(size_t)node * NHEAD + hh];
        float m = -3.0e38f;
        int i8 = lane >> 3;
        for (int i = 0; i < cnt; i += 8) {
            int ii = i + i8;
            if (ii < cnt) {
                int s = csr_src[start + ii];
                float lgv = esrc[(size_t)s * NHEAD + hh] + edl;
                lgv = lgv > 0.f ? lgv : 0.2f * lgv;
                m = fmaxf(m, lgv);
            }
        }
        m = fmaxf(m, __shfl_xor(m, 8));
        m = fmaxf(m, __shfl_xor(m, 16));
        m = fmaxf(m, __shfl_xor(m, 32));
        float4 acc = make_float4(0.f, 0.f, 0.f, 0.f);
        float den = 0.f;
        for (int i = 0; i < cnt; i++) {
            int s = csr_src[start + i];
            float lgv = esrc[(size_t)s * NHEAD + hh] + edl;
            lgv = lgv > 0.f ? lgv : 0.2f * lgv;
            float w = __expf(lgv - m);
            den += w;
            float wc = __shfl(w, chead);
            ushort4 hu = *(const ushort4*)(h + (size_t)s * CDIM + lane * 4);
            acc.x += wc * bf2f(hu.x); acc.y += wc * bf2f(hu.y);
            acc.z += wc * bf2f(hu.z); acc.w += wc * bf2f(hu.w);
        }
        float dc = __shfl(den, chead) + 1e-16f;
        float inv = 1.f / dc;
        gat4.x = fmaxf(acc.x * inv, 0.f);
        gat4.y = fmaxf(acc.y * inv, 0.f);
        gat4.z = fmaxf(acc.z * inv, 0.f);
        gat4.w = fmaxf(acc.w * inv, 0.f);
    }

    // --- cross-attention epilogue: wqk/v direct from global (L2) ---
    float s[MSLOT];
#pragma unroll
    for (int j = 0; j < MSLOT; j++) {
        float4 w4 = *(const float4*)(wqk + j * CDIM + lane * 4);
        s[j] = gat4.x * w4.x + gat4.y * w4.y + gat4.z * w4.z + gat4.w * w4.w;
    }
#pragma unroll
    for (int d = 1; d < 64; d <<= 1) {
#pragma unroll
        for (int j = 0; j < MSLOT; j++) s[j] += __shfl_xor(s[j], d);
    }
    float m = s[0];
#pragma unroll
    for (int j = 1; j < MSLOT; j++) m = fmaxf(m, s[j]);
    float sum = 0.f;
#pragma unroll
    for (int j = 0; j < MSLOT; j++) { s[j] = __expf(s[j] - m); sum += s[j]; }
    float inv = 1.f / sum;

    float4 c4 = *(const float4*)(cur + (size_t)node * CDIM + lane * 4);
    float4 o;
    o.x = gat4.x + c4.x; o.y = gat4.y + c4.y; o.z = gat4.z + c4.z; o.w = gat4.w + c4.w;
#pragma unroll
    for (int j = 0; j < MSLOT; j++) {
        float p = s[j] * inv;
        float4 v4 = *(const float4*)(vbuf + j * CDIM + lane * 4);
        o.x += p * v4.x; o.y += p * v4.y; o.z += p * v4.z; o.w += p * v4.w;
    }
    o.x = fmaxf(o.x, 0.f); o.y = fmaxf(o.y, 0.f); o.z = fmaxf(o.z, 0.f); o.w = fmaxf(o.w, 0.f);
    *(float4*)(outf + (size_t)node * CDIM + lane * 4) = o;
    ushort4 ob;
    ob.x = f2bf(o.x); ob.y = f2bf(o.y); ob.z = f2bf(o.z); ob.w = f2bf(o.w);
    *(ushort4*)(outbf + (size_t)node * CDIM + lane * 4) = ob;
}

// ---------------------------------------------------------------------------
__global__ void col_sum(const float* __restrict__ node, float* __restrict__ pooled, int n)
{
    float acc = 0.f;
    int c = threadIdx.x;
    for (int r = blockIdx.x; r < n; r += gridDim.x) acc += node[(size_t)r * CDIM + c];
    atomicAdd(&pooled[c], acc);
}

__global__ void finalize(const float* __restrict__ pooled, const float* __restrict__ mem,
                         const float* __restrict__ Wc, const float* __restrict__ bc,
                         float* __restrict__ out)
{
    int lane = threadIdx.x;
    float a0 = 0.f, a1 = 0.f;
    for (int i = lane; i < CDIM + MDIM; i += 64) {
        float f;
        if (i < CDIM) {
            f = pooled[i] * (1.0f / (float)N_NODES);
        } else {
            float s = 0.f;
            for (int r = 0; r < MSLOT; r++) s += mem[r * MDIM + (i - CDIM)];
            f = s * (1.0f / (float)MSLOT);
        }
        a0 += f * Wc[i * NCLS + 0];
        a1 += f * Wc[i * NCLS + 1];
    }
#pragma unroll
    for (int d = 1; d < 64; d <<= 1) { a0 += __shfl_xor(a0, d); a1 += __shfl_xor(a1, d); }
    if (lane == 0) { out[0] = a0 + bc[0]; out[1] = a1 + bc[1]; }
}

// ---------------------------------------------------------------------------
extern "C" void kernel_launch(void* const* d_in, const int* in_sizes, int n_in,
                              void* d_out, int out_size, void* d_ws, size_t ws_size,
                              hipStream_t stream)
{
    const float* x    = (const float*)d_in[0];
    const int*   ei   = (const int*)d_in[1];
    const float* temb = (const float*)d_in[2];
    const float* Wi   = (const float*)d_in[3];
    const float* bi   = (const float*)d_in[4];
    const float* Wg   = (const float*)d_in[5];
    const float* a_s  = (const float*)d_in[6];
    const float* a_d  = (const float*)d_in[7];
    const float* Wt   = (const float*)d_in[8];
    const float* Wq   = (const float*)d_in[9];
    const float* Wk   = (const float*)d_in[10];
    const float* Wv   = (const float*)d_in[11];
    const float* mem  = (const float*)d_in[12];
    const float* Wc   = (const float*)d_in[13];
    const float* bc   = (const float*)d_in[14];
    float* out = (float*)d_out;
    char* ws = (char*)d_ws;

    const size_t NC_BYTES  = (size_t)N_NODES * CDIM * 4;
    const size_t NCB_BYTES = (size_t)N_NODES * CDIM * 2;
    size_t off = 0;
    float* bufA   = (float*)(ws + off); off += NC_BYTES;
    float* bufB   = (float*)(ws + off); off += NC_BYTES;
    ushort_t* hbf    = (ushort_t*)(ws + off); off += NCB_BYTES;
    ushort_t* nodebf = (ushort_t*)(ws + off); off += NCB_BYTES;
    ushort_t* xbf    = (ushort_t*)(ws + off); off += (size_t)N_NODES * FEAT * 2;
    ushort_t* tembbf = (ushort_t*)(ws + off); off += (size_t)N_NODES * TDIM * 2;
    float* esrc   = (float*)(ws + off); off += (size_t)N_NODES * NHEAD * 4;
    float* edst   = (float*)(ws + off); off += (size_t)N_NODES * NHEAD * 4;
    float* kbufs  = (float*)(ws + off); off += (size_t)NLAYER * MSLOT * CDIM * 4;
    float* vbufs  = (float*)(ws + off); off += (size_t)NLAYER * MSLOT * CDIM * 4;
    float* wqkL   = (float*)(ws + off); off += (size_t)NLAYER * MSLOT * CDIM * 4;
    float* Wtp    = (float*)(ws + off); off += (size_t)NLAYER * TDIM * CDIM * 4;
    ushort_t* Bt_i = (ushort_t*)(ws + off); off += (size_t)CDIM * FEAT * 2;
    ushort_t* Bt_h = (ushort_t*)(ws + off); off += (size_t)NLAYER * CDIM * (CDIM + TDIM) * 2;
    size_t zero_base = off;
    float* pooled = (float*)(ws + off); off += CDIM * 4;
    int* deg      = (int*)(ws + off);   off += N_NODES * 4;
    int* cursor   = (int*)(ws + off);   off += N_NODES * 4;
    size_t zero_len = off - zero_base;
    int* offs     = (int*)(ws + off);   off += (N_NODES + 4) * 4;
    int* csr_src  = (int*)(ws + off);   off += (size_t)E_EDGES * 4;

    const int* srcIdx = ei;
    const int* dstIdx = ei + E_EDGES;

    hipMemsetAsync(ws + zero_base, 0, zero_len, stream);

    // ---- prep ----
    cvt_bf16<<<(N_NODES * FEAT + 255) / 256, 256, 0, stream>>>(x, xbf, N_NODES * FEAT);
    cvt_bf16<<<(N_NODES * TDIM + 255) / 256, 256, 0, stream>>>(temb, tembbf, N_NODES * TDIM);
    gemm64<<<dim3(4, 1, NLAYER), 256, 0, stream>>>(Wt, nullptr, Wg, nullptr, Wtp,
        TDIM, CDIM, CDIM, 0, TDIM * CDIM, CDIM * CDIM, TDIM * CDIM);
    transpose_cast<<<dim3(CDIM / 32, FEAT / 32, 1), 256, 0, stream>>>(
        Wi, FEAT, CDIM, Bt_i, FEAT, 0, 0, 0);
    transpose_cast<<<dim3(CDIM / 32, CDIM / 32, NLAYER), 256, 0, stream>>>(
        Wg, CDIM, CDIM, Bt_h, CDIM + TDIM, 0, CDIM * CDIM, CDIM * (CDIM + TDIM));
    transpose_cast<<<dim3(CDIM / 32, TDIM / 32, NLAYER), 256, 0, stream>>>(
        Wtp, TDIM, CDIM, Bt_h, CDIM + TDIM, CDIM, TDIM * CDIM, CDIM * (CDIM + TDIM));
    gemm64<<<dim3(4, 1, NLAYER), 256, 0, stream>>>(mem, nullptr, Wk, nullptr, kbufs,
        MSLOT, MDIM, CDIM, 0, 0, MDIM * CDIM, MSLOT * CDIM);
    gemm64<<<dim3(4, 1, NLAYER), 256, 0, stream>>>(mem, nullptr, Wv, nullptr, vbufs,
        MSLOT, MDIM, CDIM, 0, 0, MDIM * CDIM, MSLOT * CDIM);
    wqk_build<<<dim3(MSLOT, NLAYER), 256, 0, stream>>>(Wq, kbufs, wqkL);

    // ---- CSR ----
    count_deg<<<(E_EDGES + 255) / 256, 256, 0, stream>>>(dstIdx, deg, E_EDGES);
    scan_kernel<<<1, 1024, 0, stream>>>(deg, offs, N_NODES);
    fill_csr<<<(E_EDGES + 255) / 256, 256, 0, stream>>>(srcIdx, dstIdx, offs, cursor, csr_src, E_EDGES);

    dim3 mfmaGrid(2, (N_NODES + 63) / 64);   // 626 blocks
    int nodeBlocks = N_NODES / 4;

    gemm_mfma<<<mfmaGrid, 256, 0, stream>>>(xbf, FEAT, FEAT, nullptr, 0, FEAT,
                                            Bt_i, bi, bufA, nodebf, 1, N_NODES);

    float* cur = bufA;
    float* alt = bufB;
    for (int l = 0; l < NLAYER; l++) {
        gemm_h<<<mfmaGrid, 256, 0, stream>>>(nodebf, CDIM, CDIM, tembbf, TDIM, CDIM + TDIM,
                                             Bt_h + (size_t)l * CDIM * (CDIM + TDIM),
                                             a_s + (size_t)l * CDIM, a_d + (size_t)l * CDIM,
                                             hbf, esrc, edst, N_NODES);
        gat_agg_fused<<<nodeBlocks, 256, 0, stream>>>(hbf, esrc, edst, offs, deg, csr_src,
                                                      wqkL + (size_t)l * MSLOT * CDIM,
                                                      vbufs + (size_t)l * MSLOT * CDIM,
                                                      cur, alt, nodebf, N_NODES);
        float* t = cur; cur = alt; alt = t;
    }

    col_sum<<<128, 256, 0, stream>>>(cur, pooled, N_NODES);
    finalize<<<1, 64, 0, stream>>>(pooled, mem, Wc, bc, out);
}

// Round 7
// 508.316 us; speedup vs baseline: 2.6944x; 1.0191x over previous
//
#include <hip/hip_runtime.h>
#include <hip/hip_bf16.h>

#define N_NODES 20000
#define E_EDGES 320000
#define FEAT 128
#define CDIM 256
#define NHEAD 8
#define HDIM 32
#define NLAYER 5
#define TDIM 64
#define MSLOT 10
#define MDIM 128
#define NCLS 2

typedef unsigned short ushort_t;
typedef short short8 __attribute__((ext_vector_type(8)));
typedef float floatx4 __attribute__((ext_vector_type(4)));

__device__ __forceinline__ ushort_t f2bf(float f) {
    union { float f; unsigned int u; } t; t.f = f;
    unsigned int r = (t.u + 0x7FFF + ((t.u >> 16) & 1)) >> 16;
    return (ushort_t)r;
}
__device__ __forceinline__ float bf2f(ushort_t u) {
    union { float f; unsigned int u; } t; t.u = ((unsigned int)u) << 16;
    return t.f;
}

// ---------------------------------------------------------------------------
// bf16 MFMA GEMM, BM=64, BN=128, BK=32. grid (2, M/64). bf16-only output.
// ---------------------------------------------------------------------------
__global__ __launch_bounds__(256) void gemm_mfma(
    const ushort_t* __restrict__ A1, int lda1, int K1,
    const ushort_t* __restrict__ A2, int lda2, int Ktot,
    const ushort_t* __restrict__ Bt,
    const float* __restrict__ bias,
    ushort_t* Cbf, int doRelu, int M)
{
    __shared__ __align__(16) ushort_t smemA[64 * 32];
    __shared__ __align__(16) ushort_t smemB[128 * 32];
    int tid = threadIdx.x;
    int lane = tid & 63, wid = tid >> 6;
    int li = lane & 15, lq = lane >> 4;
    int row0 = blockIdx.y * 64;
    int col0 = blockIdx.x * 128;

    floatx4 acc[4][2];
#pragma unroll
    for (int a = 0; a < 4; a++)
#pragma unroll
        for (int b = 0; b < 2; b++) acc[a][b] = {0.f, 0.f, 0.f, 0.f};

    int ar = tid >> 2, ac = tid & 3;
    int agc = (ac - (ar >> 1)) & 3;
    int arow = row0 + ar; if (arow >= M) arow = M - 1;

    for (int k0 = 0; k0 < Ktot; k0 += 32) {
        __syncthreads();
        const ushort_t* Ab; int lda;
        if (k0 < K1) { Ab = A1 + k0; lda = lda1; }
        else         { Ab = A2 + (k0 - K1); lda = lda2; }
        {
            const void* g = (const void*)(Ab + (size_t)arow * lda + agc * 8);
            __builtin_amdgcn_global_load_lds(
                (const __attribute__((address_space(1))) void*)g,
                (__attribute__((address_space(3))) void*)&smemA[wid * 512], 16, 0, 0);
        }
#pragma unroll
        for (int j = 0; j < 2; j++) {
            int slot = j * 256 + tid;
            int n = slot >> 2, c = slot & 3;
            int gc = (c - (n >> 1)) & 3;
            const void* g = (const void*)(Bt + (size_t)(col0 + n) * Ktot + k0 + gc * 8);
            __builtin_amdgcn_global_load_lds(
                (const __attribute__((address_space(1))) void*)g,
                (__attribute__((address_space(3))) void*)&smemB[(j * 256 + wid * 64) * 8], 16, 0, 0);
        }
        __syncthreads();

        short8 af[4], bfr[2];
#pragma unroll
        for (int mt = 0; mt < 4; mt++) {
            int m = mt * 16 + li;
            int sw = (lq + (m >> 1)) & 3;
            af[mt] = *(const short8*)&smemA[m * 32 + sw * 8];
        }
#pragma unroll
        for (int nt = 0; nt < 2; nt++) {
            int nl = wid * 32 + nt * 16 + li;
            int sw = (lq + (nl >> 1)) & 3;
            bfr[nt] = *(const short8*)&smemB[nl * 32 + sw * 8];
        }
#pragma unroll
        for (int mt = 0; mt < 4; mt++)
#pragma unroll
            for (int nt = 0; nt < 2; nt++)
                acc[mt][nt] = __builtin_amdgcn_mfma_f32_16x16x32_bf16(af[mt], bfr[nt], acc[mt][nt], 0, 0, 0);
    }

#pragma unroll
    for (int mt = 0; mt < 4; mt++) {
        int row = row0 + mt * 16 + lq * 4;
#pragma unroll
        for (int nt = 0; nt < 2; nt++) {
            int col = col0 + wid * 32 + nt * 16 + li;
            float bv = bias ? bias[col] : 0.f;
#pragma unroll
            for (int r = 0; r < 4; r++) {
                if (row + r < M) {
                    float v = acc[mt][nt][r] + bv;
                    if (doRelu) v = fmaxf(v, 0.f);
                    Cbf[(size_t)(row + r) * CDIM + col] = f2bf(v);
                }
            }
        }
    }
}

// h-GEMM (BM=64,BN=128) with fused head-logits epilogue. Wave wid's 32 cols
// are exactly head hd = blockIdx.x*4+wid: per-row head dot reduces with
// 4 shfl_xor, stored straight to esrc/edst. No LDS epilogue, no extra barrier.
__global__ __launch_bounds__(256) void gemm_h(
    const ushort_t* __restrict__ A1, int lda1, int K1,
    const ushort_t* __restrict__ A2, int lda2, int Ktot,
    const ushort_t* __restrict__ Bt,
    const float* __restrict__ a_s, const float* __restrict__ a_d,
    ushort_t* __restrict__ Cbf,
    float* __restrict__ esrc, float* __restrict__ edst, int M)
{
    __shared__ __align__(16) ushort_t smemA[64 * 32];
    __shared__ __align__(16) ushort_t smemB[128 * 32];
    int tid = threadIdx.x;
    int lane = tid & 63, wid = tid >> 6;
    int li = lane & 15, lq = lane >> 4;
    int row0 = blockIdx.y * 64;
    int col0 = blockIdx.x * 128;

    floatx4 acc[4][2];
#pragma unroll
    for (int a = 0; a < 4; a++)
#pragma unroll
        for (int b = 0; b < 2; b++) acc[a][b] = {0.f, 0.f, 0.f, 0.f};

    int ar = tid >> 2, ac = tid & 3;
    int agc = (ac - (ar >> 1)) & 3;
    int arow = row0 + ar; if (arow >= M) arow = M - 1;

    for (int k0 = 0; k0 < Ktot; k0 += 32) {
        __syncthreads();
        const ushort_t* Ab; int lda;
        if (k0 < K1) { Ab = A1 + k0; lda = lda1; }
        else         { Ab = A2 + (k0 - K1); lda = lda2; }
        {
            const void* g = (const void*)(Ab + (size_t)arow * lda + agc * 8);
            __builtin_amdgcn_global_load_lds(
                (const __attribute__((address_space(1))) void*)g,
                (__attribute__((address_space(3))) void*)&smemA[wid * 512], 16, 0, 0);
        }
#pragma unroll
        for (int j = 0; j < 2; j++) {
            int slot = j * 256 + tid;
            int n = slot >> 2, c = slot & 3;
            int gc = (c - (n >> 1)) & 3;
            const void* g = (const void*)(Bt + (size_t)(col0 + n) * Ktot + k0 + gc * 8);
            __builtin_amdgcn_global_load_lds(
                (const __attribute__((address_space(1))) void*)g,
                (__attribute__((address_space(3))) void*)&smemB[(j * 256 + wid * 64) * 8], 16, 0, 0);
        }
        __syncthreads();

        short8 af[4], bfr[2];
#pragma unroll
        for (int mt = 0; mt < 4; mt++) {
            int m = mt * 16 + li;
            int sw = (lq + (m >> 1)) & 3;
            af[mt] = *(const short8*)&smemA[m * 32 + sw * 8];
        }
#pragma unroll
        for (int nt = 0; nt < 2; nt++) {
            int nl = wid * 32 + nt * 16 + li;
            int sw = (lq + (nl >> 1)) & 3;
            bfr[nt] = *(const short8*)&smemB[nl * 32 + sw * 8];
        }
#pragma unroll
        for (int mt = 0; mt < 4; mt++)
#pragma unroll
            for (int nt = 0; nt < 2; nt++)
                acc[mt][nt] = __builtin_amdgcn_mfma_f32_16x16x32_bf16(af[mt], bfr[nt], acc[mt][nt], 0, 0, 0);
    }

    int hd = blockIdx.x * 4 + wid;
    float as0 = a_s[col0 + wid * 32 + li];
    float as1 = a_s[col0 + wid * 32 + 16 + li];
    float ad0 = a_d[col0 + wid * 32 + li];
    float ad1 = a_d[col0 + wid * 32 + 16 + li];

#pragma unroll
    for (int mt = 0; mt < 4; mt++) {
        int row = row0 + mt * 16 + lq * 4;
#pragma unroll
        for (int nt = 0; nt < 2; nt++) {
            int col = col0 + wid * 32 + nt * 16 + li;
#pragma unroll
            for (int r = 0; r < 4; r++)
                if (row + r < M)
                    Cbf[(size_t)(row + r) * CDIM + col] = f2bf(acc[mt][nt][r]);
        }
#pragma unroll
        for (int r = 0; r < 4; r++) {
            float ps = acc[mt][0][r] * as0 + acc[mt][1][r] * as1;
            float pd = acc[mt][0][r] * ad0 + acc[mt][1][r] * ad1;
#pragma unroll
            for (int d = 1; d < 16; d <<= 1) {
                ps += __shfl_xor(ps, d);
                pd += __shfl_xor(pd, d);
            }
            if (li == 0 && row + r < M) {
                esrc[(size_t)(row + r) * NHEAD + hd] = ps;
                edst[(size_t)(row + r) * NHEAD + hd] = pd;
            }
        }
    }
}

// ---------------------------------------------------------------------------
// fp32 tiled GEMM (tiny matmuls), batched.
// ---------------------------------------------------------------------------
__global__ __launch_bounds__(256) void gemm64(
    const float* __restrict__ A, const float* __restrict__ A2,
    const float* __restrict__ B, const float* __restrict__ bias,
    float* __restrict__ C, int M, int K, int Nf, int doRelu,
    int sA, int sB, int sC)
{
    __shared__ float As[16][64];
    __shared__ float Bs[16][64];
    A += (size_t)blockIdx.z * sA;
    B += (size_t)blockIdx.z * sB;
    C += (size_t)blockIdx.z * sC;
    int tid = threadIdx.x;
    int tx = tid & 15, ty = tid >> 4;
    int row0 = blockIdx.y * 64, col0 = blockIdx.x * 64;
    int ar = tid >> 2;
    int ac = (tid & 3) * 4;

    float acc[4][4] = {};

    for (int k0 = 0; k0 < K; k0 += 16) {
        int arow = row0 + ar;
        float4 av = make_float4(0.f, 0.f, 0.f, 0.f);
        if (arow < M) {
            av = *(const float4*)(A + (size_t)arow * K + k0 + ac);
            if (A2) {
                float4 a2 = *(const float4*)(A2 + (size_t)arow * K + k0 + ac);
                av.x += a2.x; av.y += a2.y; av.z += a2.z; av.w += a2.w;
            }
        }
        As[ac + 0][ar] = av.x;
        As[ac + 1][ar] = av.y;
        As[ac + 2][ar] = av.z;
        As[ac + 3][ar] = av.w;
        float4 bv = *(const float4*)(B + (size_t)(k0 + (tid >> 4)) * Nf + col0 + (tid & 15) * 4);
        *(float4*)&Bs[tid >> 4][(tid & 15) * 4] = bv;
        __syncthreads();
#pragma unroll
        for (int kk = 0; kk < 16; kk++) {
            float4 a = *(const float4*)&As[kk][ty * 4];
            float4 b = *(const float4*)&Bs[kk][tx * 4];
            acc[0][0] += a.x * b.x; acc[0][1] += a.x * b.y; acc[0][2] += a.x * b.z; acc[0][3] += a.x * b.w;
            acc[1][0] += a.y * b.x; acc[1][1] += a.y * b.y; acc[1][2] += a.y * b.z; acc[1][3] += a.y * b.w;
            acc[2][0] += a.z * b.x; acc[2][1] += a.z * b.y; acc[2][2] += a.z * b.z; acc[2][3] += a.z * b.w;
            acc[3][0] += a.w * b.x; acc[3][1] += a.w * b.y; acc[3][2] += a.w * b.z; acc[3][3] += a.w * b.w;
        }
        __syncthreads();
    }

    float4 bv = make_float4(0.f, 0.f, 0.f, 0.f);
    if (bias) bv = *(const float4*)(bias + col0 + tx * 4);
#pragma unroll
    for (int i = 0; i < 4; i++) {
        int r = row0 + ty * 4 + i;
        if (r < M) {
            float4 o;
            o.x = acc[i][0] + bv.x;
            o.y = acc[i][1] + bv.y;
            o.z = acc[i][2] + bv.z;
            o.w = acc[i][3] + bv.w;
            if (doRelu) {
                o.x = fmaxf(o.x, 0.f); o.y = fmaxf(o.y, 0.f);
                o.z = fmaxf(o.z, 0.f); o.w = fmaxf(o.w, 0.f);
            }
            *(float4*)(C + (size_t)r * Nf + col0 + tx * 4) = o;
        }
    }
}

// ---------------------------------------------------------------------------
// Prep kernels
// ---------------------------------------------------------------------------
__global__ void cvt_bf16(const float* __restrict__ in, ushort_t* __restrict__ out, int n)
{
    int i = blockIdx.x * blockDim.x + threadIdx.x;
    if (i < n) out[i] = f2bf(in[i]);
}

__global__ __launch_bounds__(256) void transpose_cast(
    const float* __restrict__ in, int K, int Nn,
    ushort_t* __restrict__ out, int ostride, int koff,
    int inBatchStride, int outBatchStride)
{
    __shared__ float tile[32][33];
    in  += (size_t)blockIdx.z * inBatchStride;
    out += (size_t)blockIdx.z * outBatchStride;
    int k0 = blockIdx.y * 32, n0 = blockIdx.x * 32;
    int tx = threadIdx.x & 31, ty = threadIdx.x >> 5;
#pragma unroll
    for (int j = 0; j < 4; j++)
        tile[ty + j * 8][tx] = in[(size_t)(k0 + ty + j * 8) * Nn + n0 + tx];
    __syncthreads();
#pragma unroll
    for (int j = 0; j < 4; j++) {
        int n = n0 + ty + j * 8;
        out[(size_t)n * ostride + koff + k0 + tx] = f2bf(tile[tx][ty + j * 8]);
    }
}

// Wqk[l][j][d] = (1/16) * sum_c Wq[l][d][c] * kbuf[l][j][c]
__global__ __launch_bounds__(256) void wqk_build(
    const float* __restrict__ Wq, const float* __restrict__ kbufs,
    float* __restrict__ wqk)
{
    int j = blockIdx.x, l = blockIdx.y;
    int d = threadIdx.x;
    __shared__ float kk[CDIM];
    kk[d] = kbufs[((size_t)l * MSLOT + j) * CDIM + d];
    __syncthreads();
    const float* wrow = Wq + ((size_t)l * CDIM + d) * CDIM;
    float acc = 0.f;
#pragma unroll 4
    for (int c = 0; c < CDIM; c++) acc += wrow[c] * kk[c];
    wqk[((size_t)l * MSLOT + j) * CDIM + d] = acc * 0.0625f;
}

// ---------------------------------------------------------------------------
// CSR construction
// ---------------------------------------------------------------------------
__global__ void count_deg(const int* __restrict__ dst, int* __restrict__ deg, int ne)
{
    int e = blockIdx.x * blockDim.x + threadIdx.x;
    if (e < ne) atomicAdd(&deg[dst[e]], 1);
}

// single-pass exclusive scan: thread t owns 20 contiguous elements
__global__ __launch_bounds__(1024) void scan_kernel(const int* __restrict__ deg,
                                                    int* __restrict__ offs, int n)
{
    __shared__ int swt[16];
    int tid = threadIdx.x, lane = tid & 63, wid = tid >> 6;
    int base = tid * 20;
    int v[20];
    int s = 0;
#pragma unroll
    for (int i = 0; i < 20; i++) {
        int d = (base + i < n) ? deg[base + i] : 0;
        v[i] = d; s += d;
    }
    int x = s;
#pragma unroll
    for (int d = 1; d < 64; d <<= 1) {
        int t = __shfl_up(x, d);
        if (lane >= d) x += t;
    }
    if (lane == 63) swt[wid] = x;
    __syncthreads();
    if (wid == 0) {
        int w = (lane < 16) ? swt[lane] : 0;
#pragma unroll
        for (int d = 1; d < 16; d <<= 1) {
            int t = __shfl_up(w, d);
            if (lane >= d) w += t;
        }
        if (lane < 16) swt[lane] = w;
    }
    __syncthreads();
    int wbase = (wid == 0) ? 0 : swt[wid - 1];
    int run = wbase + x - s;
#pragma unroll
    for (int i = 0; i < 20; i++) {
        if (base + i < n) offs[base + i] = run;
        run += v[i];
    }
}

__global__ void fill_csr(const int* __restrict__ src, const int* __restrict__ dst,
                         const int* __restrict__ offs, int* __restrict__ cursor,
                         int* __restrict__ csr_src, int ne)
{
    int e = blockIdx.x * blockDim.x + threadIdx.x;
    if (e < ne) {
        int d = dst[e];
        int p = atomicAdd(&cursor[d], 1);
        csr_src[offs[d] + p] = src[e];
    }
}

// ---------------------------------------------------------------------------
// Fully fused GAT + cross-attn, LDS-free, bf16-only node state.
// out = relu(gat + softmax(gat.Wqk).v + node_in)   (bf16 in, bf16 out)
// ---------------------------------------------------------------------------
__global__ __launch_bounds__(256) void gat_agg_fused(
    const ushort_t* __restrict__ h, const float* __restrict__ esrc, const float* __restrict__ edst,
    const int* __restrict__ offs, const int* __restrict__ deg, const int* __restrict__ csr_src,
    const float* __restrict__ wqk, const float* __restrict__ vbuf,
    const ushort_t* __restrict__ node_in,
    ushort_t* __restrict__ node_out, int n)
{
    int tid = threadIdx.x;
    int lane = tid & 63;
    int wslot = tid >> 6;
    int node = blockIdx.x * 4 + wslot;
    int start = offs[node], cnt = deg[node];
    int chead = lane >> 3;

    float4 gat4;
    if (cnt <= 64) {
        int eh = lane >> 3, hh = lane & 7;
        float edl = edst[(size_t)node * NHEAD + hh];
        int sl = (lane < cnt) ? csr_src[start + lane] : 0;
        int nit = (cnt + 7) >> 3;
        float lg[8], w8[8];
        float m = -3.0e38f;
#pragma unroll
        for (int it = 0; it < 8; it++) {
            float v = -3.0e38f;
            if (it < nit) {
                int e = it * 8 + eh;
                int se = __shfl(sl, e);
                if (e < cnt) {
                    float t = esrc[(size_t)se * NHEAD + hh] + edl;
                    v = t > 0.f ? t : 0.2f * t;
                }
            }
            lg[it] = v;
            m = fmaxf(m, v);
        }
        m = fmaxf(m, __shfl_xor(m, 8));
        m = fmaxf(m, __shfl_xor(m, 16));
        m = fmaxf(m, __shfl_xor(m, 32));
        float den = 0.f;
#pragma unroll
        for (int it = 0; it < 8; it++) {
            float w = 0.f;
            if (it < nit) {
                int e = it * 8 + eh;
                if (e < cnt) w = __expf(lg[it] - m);
            }
            w8[it] = w;
            den += w;
        }
        den += __shfl_xor(den, 8);
        den += __shfl_xor(den, 16);
        den += __shfl_xor(den, 32);
        float inv = 1.f / (den + 1e-16f);
        float invc = __shfl(inv, chead);

        float4 acc = make_float4(0.f, 0.f, 0.f, 0.f);
#pragma unroll
        for (int rr = 0; rr < 8; rr++) {
            if (rr < nit) {
                int sv[8]; float av[8];
#pragma unroll
                for (int k = 0; k < 8; k++) {
                    sv[k] = __shfl(sl, rr * 8 + k);
                    av[k] = __shfl(w8[rr], (k << 3) | chead);
                }
                ushort4 hv[8];
#pragma unroll
                for (int k = 0; k < 8; k++)
                    hv[k] = *(const ushort4*)(h + (size_t)sv[k] * CDIM + lane * 4);
#pragma unroll
                for (int k = 0; k < 8; k++) {
                    acc.x += av[k] * bf2f(hv[k].x);
                    acc.y += av[k] * bf2f(hv[k].y);
                    acc.z += av[k] * bf2f(hv[k].z);
                    acc.w += av[k] * bf2f(hv[k].w);
                }
            }
        }
        gat4.x = fmaxf(acc.x * invc, 0.f);
        gat4.y = fmaxf(acc.y * invc, 0.f);
        gat4.z = fmaxf(acc.z * invc, 0.f);
        gat4.w = fmaxf(acc.w * invc, 0.f);
    } else {
        // slow path (deg > 64): two-pass serial (rare)
        int hh = lane & 7;
        float edl = edst[(size_t)node * NHEAD + hh];
        float m = -3.0e38f;
        int i8 = lane >> 3;
        for (int i = 0; i < cnt; i += 8) {
            int ii = i + i8;
            if (ii < cnt) {
                int s = csr_src[start + ii];
                float lgv = esrc[(size_t)s * NHEAD + hh] + edl;
                lgv = lgv > 0.f ? lgv : 0.2f * lgv;
                m = fmaxf(m, lgv);
            }
        }
        m = fmaxf(m, __shfl_xor(m, 8));
        m = fmaxf(m, __shfl_xor(m, 16));
        m = fmaxf(m, __shfl_xor(m, 32));
        float4 acc = make_float4(0.f, 0.f, 0.f, 0.f);
        float den = 0.f;
        for (int i = 0; i < cnt; i++) {
            int s = csr_src[start + i];
            float lgv = esrc[(size_t)s * NHEAD + hh] + edl;
            lgv = lgv > 0.f ? lgv : 0.2f * lgv;
            float w = __expf(lgv - m);
            den += w;
            float wc = __shfl(w, chead);
            ushort4 hu = *(const ushort4*)(h + (size_t)s * CDIM + lane * 4);
            acc.x += wc * bf2f(hu.x); acc.y += wc * bf2f(hu.y);
            acc.z += wc * bf2f(hu.z); acc.w += wc * bf2f(hu.w);
        }
        float dc = __shfl(den, chead) + 1e-16f;
        float inv = 1.f / dc;
        gat4.x = fmaxf(acc.x * inv, 0.f);
        gat4.y = fmaxf(acc.y * inv, 0.f);
        gat4.z = fmaxf(acc.z * inv, 0.f);
        gat4.w = fmaxf(acc.w * inv, 0.f);
    }

    // --- cross-attention epilogue: wqk/v direct from global (L2) ---
    float s[MSLOT];
#pragma unroll
    for (int j = 0; j < MSLOT; j++) {
        float4 w4 = *(const float4*)(wqk + j * CDIM + lane * 4);
        s[j] = gat4.x * w4.x + gat4.y * w4.y + gat4.z * w4.z + gat4.w * w4.w;
    }
#pragma unroll
    for (int d = 1; d < 64; d <<= 1) {
#pragma unroll
        for (int j = 0; j < MSLOT; j++) s[j] += __shfl_xor(s[j], d);
    }
    float m = s[0];
#pragma unroll
    for (int j = 1; j < MSLOT; j++) m = fmaxf(m, s[j]);
    float sum = 0.f;
#pragma unroll
    for (int j = 0; j < MSLOT; j++) { s[j] = __expf(s[j] - m); sum += s[j]; }
    float inv = 1.f / sum;

    ushort4 c4 = *(const ushort4*)(node_in + (size_t)node * CDIM + lane * 4);
    float4 o;
    o.x = gat4.x + bf2f(c4.x); o.y = gat4.y + bf2f(c4.y);
    o.z = gat4.z + bf2f(c4.z); o.w = gat4.w + bf2f(c4.w);
#pragma unroll
    for (int j = 0; j < MSLOT; j++) {
        float p = s[j] * inv;
        float4 v4 = *(const float4*)(vbuf + j * CDIM + lane * 4);
        o.x += p * v4.x; o.y += p * v4.y; o.z += p * v4.z; o.w += p * v4.w;
    }
    o.x = fmaxf(o.x, 0.f); o.y = fmaxf(o.y, 0.f); o.z = fmaxf(o.z, 0.f); o.w = fmaxf(o.w, 0.f);
    ushort4 ob;
    ob.x = f2bf(o.x); ob.y = f2bf(o.y); ob.z = f2bf(o.z); ob.w = f2bf(o.w);
    *(ushort4*)(node_out + (size_t)node * CDIM + lane * 4) = ob;
}

// ---------------------------------------------------------------------------
__global__ void col_sum(const ushort_t* __restrict__ node, float* __restrict__ pooled, int n)
{
    float acc = 0.f;
    int c = threadIdx.x;
    for (int r = blockIdx.x; r < n; r += gridDim.x) acc += bf2f(node[(size_t)r * CDIM + c]);
    atomicAdd(&pooled[c], acc);
}

__global__ void finalize(const float* __restrict__ pooled, const float* __restrict__ mem,
                         const float* __restrict__ Wc, const float* __restrict__ bc,
                         float* __restrict__ out)
{
    int lane = threadIdx.x;
    float a0 = 0.f, a1 = 0.f;
    for (int i = lane; i < CDIM + MDIM; i += 64) {
        float f;
        if (i < CDIM) {
            f = pooled[i] * (1.0f / (float)N_NODES);
        } else {
            float s = 0.f;
            for (int r = 0; r < MSLOT; r++) s += mem[r * MDIM + (i - CDIM)];
            f = s * (1.0f / (float)MSLOT);
        }
        a0 += f * Wc[i * NCLS + 0];
        a1 += f * Wc[i * NCLS + 1];
    }
#pragma unroll
    for (int d = 1; d < 64; d <<= 1) { a0 += __shfl_xor(a0, d); a1 += __shfl_xor(a1, d); }
    if (lane == 0) { out[0] = a0 + bc[0]; out[1] = a1 + bc[1]; }
}

// ---------------------------------------------------------------------------
extern "C" void kernel_launch(void* const* d_in, const int* in_sizes, int n_in,
                              void* d_out, int out_size, void* d_ws, size_t ws_size,
                              hipStream_t stream)
{
    const float* x    = (const float*)d_in[0];
    const int*   ei   = (const int*)d_in[1];
    const float* temb = (const float*)d_in[2];
    const float* Wi   = (const float*)d_in[3];
    const float* bi   = (const float*)d_in[4];
    const float* Wg   = (const float*)d_in[5];
    const float* a_s  = (const float*)d_in[6];
    const float* a_d  = (const float*)d_in[7];
    const float* Wt   = (const float*)d_in[8];
    const float* Wq   = (const float*)d_in[9];
    const float* Wk   = (const float*)d_in[10];
    const float* Wv   = (const float*)d_in[11];
    const float* mem  = (const float*)d_in[12];
    const float* Wc   = (const float*)d_in[13];
    const float* bc   = (const float*)d_in[14];
    float* out = (float*)d_out;
    char* ws = (char*)d_ws;

    const size_t NCB_BYTES = (size_t)N_NODES * CDIM * 2;
    size_t off = 0;
    ushort_t* nodeA  = (ushort_t*)(ws + off); off += NCB_BYTES;
    ushort_t* nodeB  = (ushort_t*)(ws + off); off += NCB_BYTES;
    ushort_t* hbf    = (ushort_t*)(ws + off); off += NCB_BYTES;
    ushort_t* xbf    = (ushort_t*)(ws + off); off += (size_t)N_NODES * FEAT * 2;
    ushort_t* tembbf = (ushort_t*)(ws + off); off += (size_t)N_NODES * TDIM * 2;
    float* esrc   = (float*)(ws + off); off += (size_t)N_NODES * NHEAD * 4;
    float* edst   = (float*)(ws + off); off += (size_t)N_NODES * NHEAD * 4;
    float* kbufs  = (float*)(ws + off); off += (size_t)NLAYER * MSLOT * CDIM * 4;
    float* vbufs  = (float*)(ws + off); off += (size_t)NLAYER * MSLOT * CDIM * 4;
    float* wqkL   = (float*)(ws + off); off += (size_t)NLAYER * MSLOT * CDIM * 4;
    float* Wtp    = (float*)(ws + off); off += (size_t)NLAYER * TDIM * CDIM * 4;
    ushort_t* Bt_i = (ushort_t*)(ws + off); off += (size_t)CDIM * FEAT * 2;
    ushort_t* Bt_h = (ushort_t*)(ws + off); off += (size_t)NLAYER * CDIM * (CDIM + TDIM) * 2;
    size_t zero_base = off;
    float* pooled = (float*)(ws + off); off += CDIM * 4;
    int* deg      = (int*)(ws + off);   off += N_NODES * 4;
    int* cursor   = (int*)(ws + off);   off += N_NODES * 4;
    size_t zero_len = off - zero_base;
    int* offs     = (int*)(ws + off);   off += (N_NODES + 4) * 4;
    int* csr_src  = (int*)(ws + off);   off += (size_t)E_EDGES * 4;

    const int* srcIdx = ei;
    const int* dstIdx = ei + E_EDGES;

    hipMemsetAsync(ws + zero_base, 0, zero_len, stream);

    // ---- prep ----
    cvt_bf16<<<(N_NODES * FEAT + 255) / 256, 256, 0, stream>>>(x, xbf, N_NODES * FEAT);
    cvt_bf16<<<(N_NODES * TDIM + 255) / 256, 256, 0, stream>>>(temb, tembbf, N_NODES * TDIM);
    gemm64<<<dim3(4, 1, NLAYER), 256, 0, stream>>>(Wt, nullptr, Wg, nullptr, Wtp,
        TDIM, CDIM, CDIM, 0, TDIM * CDIM, CDIM * CDIM, TDIM * CDIM);
    transpose_cast<<<dim3(CDIM / 32, FEAT / 32, 1), 256, 0, stream>>>(
        Wi, FEAT, CDIM, Bt_i, FEAT, 0, 0, 0);
    transpose_cast<<<dim3(CDIM / 32, CDIM / 32, NLAYER), 256, 0, stream>>>(
        Wg, CDIM, CDIM, Bt_h, CDIM + TDIM, 0, CDIM * CDIM, CDIM * (CDIM + TDIM));
    transpose_cast<<<dim3(CDIM / 32, TDIM / 32, NLAYER), 256, 0, stream>>>(
        Wtp, TDIM, CDIM, Bt_h, CDIM + TDIM, CDIM, TDIM * CDIM, CDIM * (CDIM + TDIM));
    gemm64<<<dim3(4, 1, NLAYER), 256, 0, stream>>>(mem, nullptr, Wk, nullptr, kbufs,
        MSLOT, MDIM, CDIM, 0, 0, MDIM * CDIM, MSLOT * CDIM);
    gemm64<<<dim3(4, 1, NLAYER), 256, 0, stream>>>(mem, nullptr, Wv, nullptr, vbufs,
        MSLOT, MDIM, CDIM, 0, 0, MDIM * CDIM, MSLOT * CDIM);
    wqk_build<<<dim3(MSLOT, NLAYER), 256, 0, stream>>>(Wq, kbufs, wqkL);

    // ---- CSR ----
    count_deg<<<(E_EDGES + 255) / 256, 256, 0, stream>>>(dstIdx, deg, E_EDGES);
    scan_kernel<<<1, 1024, 0, stream>>>(deg, offs, N_NODES);
    fill_csr<<<(E_EDGES + 255) / 256, 256, 0, stream>>>(srcIdx, dstIdx, offs, cursor, csr_src, E_EDGES);

    dim3 mfmaGrid(2, (N_NODES + 63) / 64);   // 626 blocks
    int nodeBlocks = N_NODES / 4;

    // node = relu(x @ Wi + bi) -> nodeA (bf16)
    gemm_mfma<<<mfmaGrid, 256, 0, stream>>>(xbf, FEAT, FEAT, nullptr, 0, FEAT,
                                            Bt_i, bi, nodeA, 1, N_NODES);

    ushort_t* cur = nodeA;
    ushort_t* alt = nodeB;
    for (int l = 0; l < NLAYER; l++) {
        gemm_h<<<mfmaGrid, 256, 0, stream>>>(cur, CDIM, CDIM, tembbf, TDIM, CDIM + TDIM,
                                             Bt_h + (size_t)l * CDIM * (CDIM + TDIM),
                                             a_s + (size_t)l * CDIM, a_d + (size_t)l * CDIM,
                                             hbf, esrc, edst, N_NODES);
        gat_agg_fused<<<nodeBlocks, 256, 0, stream>>>(hbf, esrc, edst, offs, deg, csr_src,
                                                      wqkL + (size_t)l * MSLOT * CDIM,
                                                      vbufs + (size_t)l * MSLOT * CDIM,
                                                      cur, alt, N_NODES);
        ushort_t* t = cur; cur = alt; alt = t;
    }

    col_sum<<<128, 256, 0, stream>>>(cur, pooled, N_NODES);
    finalize<<<1, 64, 0, stream>>>(pooled, mem, Wc, bc, out);
}

// Round 8
// 479.214 us; speedup vs baseline: 2.8581x; 1.0607x over previous
//
#include <hip/hip_runtime.h>
#include <hip/hip_bf16.h>

#define N_NODES 20000
#define E_EDGES 320000
#define FEAT 128
#define CDIM 256
#define NHEAD 8
#define HDIM 32
#define NLAYER 5
#define TDIM 64
#define MSLOT 10
#define MDIM 128
#define NCLS 2

typedef unsigned short ushort_t;
typedef unsigned char uchar_t;
typedef short short8 __attribute__((ext_vector_type(8)));
typedef float floatx4 __attribute__((ext_vector_type(4)));
typedef float floatx2 __attribute__((ext_vector_type(2)));

__device__ __forceinline__ ushort_t f2bf(float f) {
    union { float f; unsigned int u; } t; t.f = f;
    unsigned int r = (t.u + 0x7FFF + ((t.u >> 16) & 1)) >> 16;
    return (ushort_t)r;
}
__device__ __forceinline__ float bf2f(ushort_t u) {
    union { float f; unsigned int u; } t; t.u = ((unsigned int)u) << 16;
    return t.f;
}

// ---------------------------------------------------------------------------
// bf16 MFMA GEMM, BM=32, BN=128, BK=32. grid (2, M/32) = 1250 blocks
// (4.9 blocks/CU). 4 waves; wave w owns cols [col0+w*32, +32).
// C/D map: row = row0+mt*16+lq*4+r, col = col0+wid*32+nt*16+li.
// M % 32 == 0 -> no row guards.
// ---------------------------------------------------------------------------
__global__ __launch_bounds__(256) void gemm_mfma(
    const ushort_t* __restrict__ A1, int lda1, int K1,
    const ushort_t* __restrict__ A2, int lda2, int Ktot,
    const ushort_t* __restrict__ Bt,
    const float* __restrict__ bias,
    ushort_t* Cbf, int doRelu)
{
    __shared__ __align__(16) ushort_t smemA[32 * 32];
    __shared__ __align__(16) ushort_t smemB[128 * 32];
    int tid = threadIdx.x;
    int lane = tid & 63, wid = tid >> 6;
    int li = lane & 15, lq = lane >> 4;
    int row0 = blockIdx.y * 32;
    int col0 = blockIdx.x * 128;

    floatx4 acc[2][2];
#pragma unroll
    for (int a = 0; a < 2; a++)
#pragma unroll
        for (int b = 0; b < 2; b++) acc[a][b] = {0.f, 0.f, 0.f, 0.f};

    int ar = tid >> 2, ac = tid & 3;
    int agc = (ac - (ar >> 1)) & 3;

    for (int k0 = 0; k0 < Ktot; k0 += 32) {
        __syncthreads();
        const ushort_t* Ab; int lda;
        if (k0 < K1) { Ab = A1 + k0; lda = lda1; }
        else         { Ab = A2 + (k0 - K1); lda = lda2; }
        if (wid < 2) {
            const void* g = (const void*)(Ab + (size_t)(row0 + ar) * lda + agc * 8);
            __builtin_amdgcn_global_load_lds(
                (const __attribute__((address_space(1))) void*)g,
                (__attribute__((address_space(3))) void*)&smemA[wid * 512], 16, 0, 0);
        }
#pragma unroll
        for (int j = 0; j < 2; j++) {
            int slot = j * 256 + tid;
            int n = slot >> 2, c = slot & 3;
            int gc = (c - (n >> 1)) & 3;
            const void* g = (const void*)(Bt + (size_t)(col0 + n) * Ktot + k0 + gc * 8);
            __builtin_amdgcn_global_load_lds(
                (const __attribute__((address_space(1))) void*)g,
                (__attribute__((address_space(3))) void*)&smemB[(j * 256 + wid * 64) * 8], 16, 0, 0);
        }
        __syncthreads();

        short8 af[2], bfr[2];
#pragma unroll
        for (int mt = 0; mt < 2; mt++) {
            int m = mt * 16 + li;
            int sw = (lq + (m >> 1)) & 3;
            af[mt] = *(const short8*)&smemA[m * 32 + sw * 8];
        }
#pragma unroll
        for (int nt = 0; nt < 2; nt++) {
            int nl = wid * 32 + nt * 16 + li;
            int sw = (lq + (nl >> 1)) & 3;
            bfr[nt] = *(const short8*)&smemB[nl * 32 + sw * 8];
        }
#pragma unroll
        for (int mt = 0; mt < 2; mt++)
#pragma unroll
            for (int nt = 0; nt < 2; nt++)
                acc[mt][nt] = __builtin_amdgcn_mfma_f32_16x16x32_bf16(af[mt], bfr[nt], acc[mt][nt], 0, 0, 0);
    }

#pragma unroll
    for (int mt = 0; mt < 2; mt++) {
        int row = row0 + mt * 16 + lq * 4;
#pragma unroll
        for (int nt = 0; nt < 2; nt++) {
            int col = col0 + wid * 32 + nt * 16 + li;
            float bv = bias ? bias[col] : 0.f;
#pragma unroll
            for (int r = 0; r < 4; r++) {
                float v = acc[mt][nt][r] + bv;
                if (doRelu) v = fmaxf(v, 0.f);
                Cbf[(size_t)(row + r) * CDIM + col] = f2bf(v);
            }
        }
    }
}

// h-GEMM (BM=32,BN=128): writes h in fp8 e4m3 (HW cvt) + fused head logits.
// Wave wid's 32 cols = exactly head hd = blockIdx.x*4+wid.
__global__ __launch_bounds__(256) void gemm_h(
    const ushort_t* __restrict__ A1, int lda1, int K1,
    const ushort_t* __restrict__ A2, int lda2, int Ktot,
    const ushort_t* __restrict__ Bt,
    const float* __restrict__ a_s, const float* __restrict__ a_d,
    uchar_t* __restrict__ Cf8,
    float* __restrict__ esrc, float* __restrict__ edst)
{
    __shared__ __align__(16) ushort_t smemA[32 * 32];
    __shared__ __align__(16) ushort_t smemB[128 * 32];
    int tid = threadIdx.x;
    int lane = tid & 63, wid = tid >> 6;
    int li = lane & 15, lq = lane >> 4;
    int row0 = blockIdx.y * 32;
    int col0 = blockIdx.x * 128;

    floatx4 acc[2][2];
#pragma unroll
    for (int a = 0; a < 2; a++)
#pragma unroll
        for (int b = 0; b < 2; b++) acc[a][b] = {0.f, 0.f, 0.f, 0.f};

    int ar = tid >> 2, ac = tid & 3;
    int agc = (ac - (ar >> 1)) & 3;

    for (int k0 = 0; k0 < Ktot; k0 += 32) {
        __syncthreads();
        const ushort_t* Ab; int lda;
        if (k0 < K1) { Ab = A1 + k0; lda = lda1; }
        else         { Ab = A2 + (k0 - K1); lda = lda2; }
        if (wid < 2) {
            const void* g = (const void*)(Ab + (size_t)(row0 + ar) * lda + agc * 8);
            __builtin_amdgcn_global_load_lds(
                (const __attribute__((address_space(1))) void*)g,
                (__attribute__((address_space(3))) void*)&smemA[wid * 512], 16, 0, 0);
        }
#pragma unroll
        for (int j = 0; j < 2; j++) {
            int slot = j * 256 + tid;
            int n = slot >> 2, c = slot & 3;
            int gc = (c - (n >> 1)) & 3;
            const void* g = (const void*)(Bt + (size_t)(col0 + n) * Ktot + k0 + gc * 8);
            __builtin_amdgcn_global_load_lds(
                (const __attribute__((address_space(1))) void*)g,
                (__attribute__((address_space(3))) void*)&smemB[(j * 256 + wid * 64) * 8], 16, 0, 0);
        }
        __syncthreads();

        short8 af[2], bfr[2];
#pragma unroll
        for (int mt = 0; mt < 2; mt++) {
            int m = mt * 16 + li;
            int sw = (lq + (m >> 1)) & 3;
            af[mt] = *(const short8*)&smemA[m * 32 + sw * 8];
        }
#pragma unroll
        for (int nt = 0; nt < 2; nt++) {
            int nl = wid * 32 + nt * 16 + li;
            int sw = (lq + (nl >> 1)) & 3;
            bfr[nt] = *(const short8*)&smemB[nl * 32 + sw * 8];
        }
#pragma unroll
        for (int mt = 0; mt < 2; mt++)
#pragma unroll
            for (int nt = 0; nt < 2; nt++)
                acc[mt][nt] = __builtin_amdgcn_mfma_f32_16x16x32_bf16(af[mt], bfr[nt], acc[mt][nt], 0, 0, 0);
    }

    int hd = blockIdx.x * 4 + wid;
    int cbase = col0 + wid * 32 + li;
    float as0 = a_s[cbase];
    float as1 = a_s[cbase + 16];
    float ad0 = a_d[cbase];
    float ad1 = a_d[cbase + 16];

#pragma unroll
    for (int mt = 0; mt < 2; mt++) {
        int row = row0 + mt * 16 + lq * 4;
#pragma unroll
        for (int r = 0; r < 4; r++) {
            float v0 = acc[mt][0][r];
            float v1 = acc[mt][1][r];
            // fp8 store: pack (v0,v1) -> bytes 0,1
            unsigned int pk = __builtin_amdgcn_cvt_pk_fp8_f32(v0, v1, 0, false);
            Cf8[(size_t)(row + r) * CDIM + cbase]      = (uchar_t)(pk & 0xff);
            Cf8[(size_t)(row + r) * CDIM + cbase + 16] = (uchar_t)((pk >> 8) & 0xff);
            // head logits (fp32, pre-quantization)
            float ps = v0 * as0 + v1 * as1;
            float pd = v0 * ad0 + v1 * ad1;
#pragma unroll
            for (int d = 1; d < 16; d <<= 1) {
                ps += __shfl_xor(ps, d);
                pd += __shfl_xor(pd, d);
            }
            if (li == 0) {
                esrc[(size_t)(row + r) * NHEAD + hd] = ps;
                edst[(size_t)(row + r) * NHEAD + hd] = pd;
            }
        }
    }
}

// ---------------------------------------------------------------------------
// fp32 tiled GEMM (tiny matmuls), batched.
// ---------------------------------------------------------------------------
__global__ __launch_bounds__(256) void gemm64(
    const float* __restrict__ A, const float* __restrict__ A2,
    const float* __restrict__ B, const float* __restrict__ bias,
    float* __restrict__ C, int M, int K, int Nf, int doRelu,
    int sA, int sB, int sC)
{
    __shared__ float As[16][64];
    __shared__ float Bs[16][64];
    A += (size_t)blockIdx.z * sA;
    B += (size_t)blockIdx.z * sB;
    C += (size_t)blockIdx.z * sC;
    int tid = threadIdx.x;
    int tx = tid & 15, ty = tid >> 4;
    int row0 = blockIdx.y * 64, col0 = blockIdx.x * 64;
    int ar = tid >> 2;
    int ac = (tid & 3) * 4;

    float acc[4][4] = {};

    for (int k0 = 0; k0 < K; k0 += 16) {
        int arow = row0 + ar;
        float4 av = make_float4(0.f, 0.f, 0.f, 0.f);
        if (arow < M) {
            av = *(const float4*)(A + (size_t)arow * K + k0 + ac);
            if (A2) {
                float4 a2 = *(const float4*)(A2 + (size_t)arow * K + k0 + ac);
                av.x += a2.x; av.y += a2.y; av.z += a2.z; av.w += a2.w;
            }
        }
        As[ac + 0][ar] = av.x;
        As[ac + 1][ar] = av.y;
        As[ac + 2][ar] = av.z;
        As[ac + 3][ar] = av.w;
        float4 bv = *(const float4*)(B + (size_t)(k0 + (tid >> 4)) * Nf + col0 + (tid & 15) * 4);
        *(float4*)&Bs[tid >> 4][(tid & 15) * 4] = bv;
        __syncthreads();
#pragma unroll
        for (int kk = 0; kk < 16; kk++) {
            float4 a = *(const float4*)&As[kk][ty * 4];
            float4 b = *(const float4*)&Bs[kk][tx * 4];
            acc[0][0] += a.x * b.x; acc[0][1] += a.x * b.y; acc[0][2] += a.x * b.z; acc[0][3] += a.x * b.w;
            acc[1][0] += a.y * b.x; acc[1][1] += a.y * b.y; acc[1][2] += a.y * b.z; acc[1][3] += a.y * b.w;
            acc[2][0] += a.z * b.x; acc[2][1] += a.z * b.y; acc[2][2] += a.z * b.z; acc[2][3] += a.z * b.w;
            acc[3][0] += a.w * b.x; acc[3][1] += a.w * b.y; acc[3][2] += a.w * b.z; acc[3][3] += a.w * b.w;
        }
        __syncthreads();
    }

    float4 bv = make_float4(0.f, 0.f, 0.f, 0.f);
    if (bias) bv = *(const float4*)(bias + col0 + tx * 4);
#pragma unroll
    for (int i = 0; i < 4; i++) {
        int r = row0 + ty * 4 + i;
        if (r < M) {
            float4 o;
            o.x = acc[i][0] + bv.x;
            o.y = acc[i][1] + bv.y;
            o.z = acc[i][2] + bv.z;
            o.w = acc[i][3] + bv.w;
            if (doRelu) {
                o.x = fmaxf(o.x, 0.f); o.y = fmaxf(o.y, 0.f);
                o.z = fmaxf(o.z, 0.f); o.w = fmaxf(o.w, 0.f);
            }
            *(float4*)(C + (size_t)r * Nf + col0 + tx * 4) = o;
        }
    }
}

// ---------------------------------------------------------------------------
// Prep kernels
// ---------------------------------------------------------------------------
__global__ void cvt_bf16(const float* __restrict__ in, ushort_t* __restrict__ out, int n)
{
    int i = blockIdx.x * blockDim.x + threadIdx.x;
    if (i < n) out[i] = f2bf(in[i]);
}

__global__ __launch_bounds__(256) void transpose_cast(
    const float* __restrict__ in, int K, int Nn,
    ushort_t* __restrict__ out, int ostride, int koff,
    int inBatchStride, int outBatchStride)
{
    __shared__ float tile[32][33];
    in  += (size_t)blockIdx.z * inBatchStride;
    out += (size_t)blockIdx.z * outBatchStride;
    int k0 = blockIdx.y * 32, n0 = blockIdx.x * 32;
    int tx = threadIdx.x & 31, ty = threadIdx.x >> 5;
#pragma unroll
    for (int j = 0; j < 4; j++)
        tile[ty + j * 8][tx] = in[(size_t)(k0 + ty + j * 8) * Nn + n0 + tx];
    __syncthreads();
#pragma unroll
    for (int j = 0; j < 4; j++) {
        int n = n0 + ty + j * 8;
        out[(size_t)n * ostride + koff + k0 + tx] = f2bf(tile[tx][ty + j * 8]);
    }
}

// Wqk[l][j][d] = (1/16) * sum_c Wq[l][d][c] * kbuf[l][j][c]
__global__ __launch_bounds__(256) void wqk_build(
    const float* __restrict__ Wq, const float* __restrict__ kbufs,
    float* __restrict__ wqk)
{
    int j = blockIdx.x, l = blockIdx.y;
    int d = threadIdx.x;
    __shared__ float kk[CDIM];
    kk[d] = kbufs[((size_t)l * MSLOT + j) * CDIM + d];
    __syncthreads();
    const float* wrow = Wq + ((size_t)l * CDIM + d) * CDIM;
    float acc = 0.f;
#pragma unroll 4
    for (int c = 0; c < CDIM; c++) acc += wrow[c] * kk[c];
    wqk[((size_t)l * MSLOT + j) * CDIM + d] = acc * 0.0625f;
}

// ---------------------------------------------------------------------------
// CSR construction
// ---------------------------------------------------------------------------
__global__ void count_deg(const int* __restrict__ dst, int* __restrict__ deg, int ne)
{
    int e = blockIdx.x * blockDim.x + threadIdx.x;
    if (e < ne) atomicAdd(&deg[dst[e]], 1);
}

// single-pass exclusive scan: thread t owns 20 contiguous elements
__global__ __launch_bounds__(1024) void scan_kernel(const int* __restrict__ deg,
                                                    int* __restrict__ offs, int n)
{
    __shared__ int swt[16];
    int tid = threadIdx.x, lane = tid & 63, wid = tid >> 6;
    int base = tid * 20;
    int v[20];
    int s = 0;
#pragma unroll
    for (int i = 0; i < 20; i++) {
        int d = (base + i < n) ? deg[base + i] : 0;
        v[i] = d; s += d;
    }
    int x = s;
#pragma unroll
    for (int d = 1; d < 64; d <<= 1) {
        int t = __shfl_up(x, d);
        if (lane >= d) x += t;
    }
    if (lane == 63) swt[wid] = x;
    __syncthreads();
    if (wid == 0) {
        int w = (lane < 16) ? swt[lane] : 0;
#pragma unroll
        for (int d = 1; d < 16; d <<= 1) {
            int t = __shfl_up(w, d);
            if (lane >= d) w += t;
        }
        if (lane < 16) swt[lane] = w;
    }
    __syncthreads();
    int wbase = (wid == 0) ? 0 : swt[wid - 1];
    int run = wbase + x - s;
#pragma unroll
    for (int i = 0; i < 20; i++) {
        if (base + i < n) offs[base + i] = run;
        run += v[i];
    }
}

__global__ void fill_csr(const int* __restrict__ src, const int* __restrict__ dst,
                         const int* __restrict__ offs, int* __restrict__ cursor,
                         int* __restrict__ csr_src, int ne)
{
    int e = blockIdx.x * blockDim.x + threadIdx.x;
    if (e < ne) {
        int d = dst[e];
        int p = atomicAdd(&cursor[d], 1);
        csr_src[offs[d] + p] = src[e];
    }
}

// ---------------------------------------------------------------------------
// Fully fused GAT + cross-attn. h in fp8 e4m3 (HW decode); node state bf16.
// out = relu(gat + softmax(gat.Wqk).v + node_in)
// ---------------------------------------------------------------------------
__global__ __launch_bounds__(256) void gat_agg_fused(
    const uchar_t* __restrict__ h, const float* __restrict__ esrc, const float* __restrict__ edst,
    const int* __restrict__ offs, const int* __restrict__ deg, const int* __restrict__ csr_src,
    const float* __restrict__ wqk, const float* __restrict__ vbuf,
    const ushort_t* __restrict__ node_in,
    ushort_t* __restrict__ node_out, int n)
{
    int tid = threadIdx.x;
    int lane = tid & 63;
    int wslot = tid >> 6;
    int node = blockIdx.x * 4 + wslot;
    int start = offs[node], cnt = deg[node];
    int chead = lane >> 3;

    float4 gat4;
    if (cnt <= 64) {
        int eh = lane >> 3, hh = lane & 7;
        float edl = edst[(size_t)node * NHEAD + hh];
        int sl = (lane < cnt) ? csr_src[start + lane] : 0;
        int nit = (cnt + 7) >> 3;
        float lg[8], w8[8];
        float m = -3.0e38f;
#pragma unroll
        for (int it = 0; it < 8; it++) {
            float v = -3.0e38f;
            if (it < nit) {
                int e = it * 8 + eh;
                int se = __shfl(sl, e);
                if (e < cnt) {
                    float t = esrc[(size_t)se * NHEAD + hh] + edl;
                    v = t > 0.f ? t : 0.2f * t;
                }
            }
            lg[it] = v;
            m = fmaxf(m, v);
        }
        m = fmaxf(m, __shfl_xor(m, 8));
        m = fmaxf(m, __shfl_xor(m, 16));
        m = fmaxf(m, __shfl_xor(m, 32));
        float den = 0.f;
#pragma unroll
        for (int it = 0; it < 8; it++) {
            float w = 0.f;
            if (it < nit) {
                int e = it * 8 + eh;
                if (e < cnt) w = __expf(lg[it] - m);
            }
            w8[it] = w;
            den += w;
        }
        den += __shfl_xor(den, 8);
        den += __shfl_xor(den, 16);
        den += __shfl_xor(den, 32);
        float inv = 1.f / (den + 1e-16f);
        float invc = __shfl(inv, chead);

        float4 acc = make_float4(0.f, 0.f, 0.f, 0.f);
#pragma unroll
        for (int rr = 0; rr < 8; rr++) {
            if (rr < nit) {
                int sv[8]; float av[8];
#pragma unroll
                for (int k = 0; k < 8; k++) {
                    sv[k] = __shfl(sl, rr * 8 + k);
                    av[k] = __shfl(w8[rr], (k << 3) | chead);
                }
                unsigned int hw[8];
#pragma unroll
                for (int k = 0; k < 8; k++)
                    hw[k] = *(const unsigned int*)(h + (size_t)sv[k] * CDIM + lane * 4);
#pragma unroll
                for (int k = 0; k < 8; k++) {
                    floatx2 lo = __builtin_amdgcn_cvt_pk_f32_fp8((int)hw[k], false);
                    floatx2 hi = __builtin_amdgcn_cvt_pk_f32_fp8((int)hw[k], true);
                    acc.x += av[k] * lo.x;
                    acc.y += av[k] * lo.y;
                    acc.z += av[k] * hi.x;
                    acc.w += av[k] * hi.y;
                }
            }
        }
        gat4.x = fmaxf(acc.x * invc, 0.f);
        gat4.y = fmaxf(acc.y * invc, 0.f);
        gat4.z = fmaxf(acc.z * invc, 0.f);
        gat4.w = fmaxf(acc.w * invc, 0.f);
    } else {
        // slow path (deg > 64): two-pass serial (rare)
        int hh = lane & 7;
        float edl = edst[(size_t)node * NHEAD + hh];
        float m = -3.0e38f;
        int i8 = lane >> 3;
        for (int i = 0; i < cnt; i += 8) {
            int ii = i + i8;
            if (ii < cnt) {
                int s = csr_src[start + ii];
                float lgv = esrc[(size_t)s * NHEAD + hh] + edl;
                lgv = lgv > 0.f ? lgv : 0.2f * lgv;
                m = fmaxf(m, lgv);
            }
        }
        m = fmaxf(m, __shfl_xor(m, 8));
        m = fmaxf(m, __shfl_xor(m, 16));
        m = fmaxf(m, __shfl_xor(m, 32));
        float4 acc = make_float4(0.f, 0.f, 0.f, 0.f);
        float den = 0.f;
        for (int i = 0; i < cnt; i++) {
            int s = csr_src[start + i];
            float lgv = esrc[(size_t)s * NHEAD + hh] + edl;
            lgv = lgv > 0.f ? lgv : 0.2f * lgv;
            float w = __expf(lgv - m);
            den += w;
            float wc = __shfl(w, chead);
            unsigned int hwv = *(const unsigned int*)(h + (size_t)s * CDIM + lane * 4);
            floatx2 lo = __builtin_amdgcn_cvt_pk_f32_fp8((int)hwv, false);
            floatx2 hi = __builtin_amdgcn_cvt_pk_f32_fp8((int)hwv, true);
            acc.x += wc * lo.x; acc.y += wc * lo.y;
            acc.z += wc * hi.x; acc.w += wc * hi.y;
        }
        float dc = __shfl(den, chead) + 1e-16f;
        float inv = 1.f / dc;
        gat4.x = fmaxf(acc.x * inv, 0.f);
        gat4.y = fmaxf(acc.y * inv, 0.f);
        gat4.z = fmaxf(acc.z * inv, 0.f);
        gat4.w = fmaxf(acc.w * inv, 0.f);
    }

    // --- cross-attention epilogue: wqk/v direct from global (L2) ---
    float s[MSLOT];
#pragma unroll
    for (int j = 0; j < MSLOT; j++) {
        float4 w4 = *(const float4*)(wqk + j * CDIM + lane * 4);
        s[j] = gat4.x * w4.x + gat4.y * w4.y + gat4.z * w4.z + gat4.w * w4.w;
    }
#pragma unroll
    for (int d = 1; d < 64; d <<= 1) {
#pragma unroll
        for (int j = 0; j < MSLOT; j++) s[j] += __shfl_xor(s[j], d);
    }
    float m = s[0];
#pragma unroll
    for (int j = 1; j < MSLOT; j++) m = fmaxf(m, s[j]);
    float sum = 0.f;
#pragma unroll
    for (int j = 0; j < MSLOT; j++) { s[j] = __expf(s[j] - m); sum += s[j]; }
    float inv = 1.f / sum;

    ushort4 c4 = *(const ushort4*)(node_in + (size_t)node * CDIM + lane * 4);
    float4 o;
    o.x = gat4.x + bf2f(c4.x); o.y = gat4.y + bf2f(c4.y);
    o.z = gat4.z + bf2f(c4.z); o.w = gat4.w + bf2f(c4.w);
#pragma unroll
    for (int j = 0; j < MSLOT; j++) {
        float p = s[j] * inv;
        float4 v4 = *(const float4*)(vbuf + j * CDIM + lane * 4);
        o.x += p * v4.x; o.y += p * v4.y; o.z += p * v4.z; o.w += p * v4.w;
    }
    o.x = fmaxf(o.x, 0.f); o.y = fmaxf(o.y, 0.f); o.z = fmaxf(o.z, 0.f); o.w = fmaxf(o.w, 0.f);
    ushort4 ob;
    ob.x = f2bf(o.x); ob.y = f2bf(o.y); ob.z = f2bf(o.z); ob.w = f2bf(o.w);
    *(ushort4*)(node_out + (size_t)node * CDIM + lane * 4) = ob;
}

// ---------------------------------------------------------------------------
__global__ void col_sum(const ushort_t* __restrict__ node, float* __restrict__ pooled, int n)
{
    float acc = 0.f;
    int c = threadIdx.x;
    for (int r = blockIdx.x; r < n; r += gridDim.x) acc += bf2f(node[(size_t)r * CDIM + c]);
    atomicAdd(&pooled[c], acc);
}

__global__ void finalize(const float* __restrict__ pooled, const float* __restrict__ mem,
                         const float* __restrict__ Wc, const float* __restrict__ bc,
                         float* __restrict__ out)
{
    int lane = threadIdx.x;
    float a0 = 0.f, a1 = 0.f;
    for (int i = lane; i < CDIM + MDIM; i += 64) {
        float f;
        if (i < CDIM) {
            f = pooled[i] * (1.0f / (float)N_NODES);
        } else {
            float s = 0.f;
            for (int r = 0; r < MSLOT; r++) s += mem[r * MDIM + (i - CDIM)];
            f = s * (1.0f / (float)MSLOT);
        }
        a0 += f * Wc[i * NCLS + 0];
        a1 += f * Wc[i * NCLS + 1];
    }
#pragma unroll
    for (int d = 1; d < 64; d <<= 1) { a0 += __shfl_xor(a0, d); a1 += __shfl_xor(a1, d); }
    if (lane == 0) { out[0] = a0 + bc[0]; out[1] = a1 + bc[1]; }
}

// ---------------------------------------------------------------------------
extern "C" void kernel_launch(void* const* d_in, const int* in_sizes, int n_in,
                              void* d_out, int out_size, void* d_ws, size_t ws_size,
                              hipStream_t stream)
{
    const float* x    = (const float*)d_in[0];
    const int*   ei   = (const int*)d_in[1];
    const float* temb = (const float*)d_in[2];
    const float* Wi   = (const float*)d_in[3];
    const float* bi   = (const float*)d_in[4];
    const float* Wg   = (const float*)d_in[5];
    const float* a_s  = (const float*)d_in[6];
    const float* a_d  = (const float*)d_in[7];
    const float* Wt   = (const float*)d_in[8];
    const float* Wq   = (const float*)d_in[9];
    const float* Wk   = (const float*)d_in[10];
    const float* Wv   = (const float*)d_in[11];
    const float* mem  = (const float*)d_in[12];
    const float* Wc   = (const float*)d_in[13];
    const float* bc   = (const float*)d_in[14];
    float* out = (float*)d_out;
    char* ws = (char*)d_ws;

    const size_t NCB_BYTES = (size_t)N_NODES * CDIM * 2;
    size_t off = 0;
    ushort_t* nodeA  = (ushort_t*)(ws + off); off += NCB_BYTES;
    ushort_t* nodeB  = (ushort_t*)(ws + off); off += NCB_BYTES;
    uchar_t*  hf8    = (uchar_t*)(ws + off);  off += (size_t)N_NODES * CDIM;   // 5.12 MB
    ushort_t* xbf    = (ushort_t*)(ws + off); off += (size_t)N_NODES * FEAT * 2;
    ushort_t* tembbf = (ushort_t*)(ws + off); off += (size_t)N_NODES * TDIM * 2;
    float* esrc   = (float*)(ws + off); off += (size_t)N_NODES * NHEAD * 4;
    float* edst   = (float*)(ws + off); off += (size_t)N_NODES * NHEAD * 4;
    float* kbufs  = (float*)(ws + off); off += (size_t)NLAYER * MSLOT * CDIM * 4;
    float* vbufs  = (float*)(ws + off); off += (size_t)NLAYER * MSLOT * CDIM * 4;
    float* wqkL   = (float*)(ws + off); off += (size_t)NLAYER * MSLOT * CDIM * 4;
    float* Wtp    = (float*)(ws + off); off += (size_t)NLAYER * TDIM * CDIM * 4;
    ushort_t* Bt_i = (ushort_t*)(ws + off); off += (size_t)CDIM * FEAT * 2;
    ushort_t* Bt_h = (ushort_t*)(ws + off); off += (size_t)NLAYER * CDIM * (CDIM + TDIM) * 2;
    size_t zero_base = off;
    float* pooled = (float*)(ws + off); off += CDIM * 4;
    int* deg      = (int*)(ws + off);   off += N_NODES * 4;
    int* cursor   = (int*)(ws + off);   off += N_NODES * 4;
    size_t zero_len = off - zero_base;
    int* offs     = (int*)(ws + off);   off += (N_NODES + 4) * 4;
    int* csr_src  = (int*)(ws + off);   off += (size_t)E_EDGES * 4;

    const int* srcIdx = ei;
    const int* dstIdx = ei + E_EDGES;

    hipMemsetAsync(ws + zero_base, 0, zero_len, stream);

    // ---- prep ----
    cvt_bf16<<<(N_NODES * FEAT + 255) / 256, 256, 0, stream>>>(x, xbf, N_NODES * FEAT);
    cvt_bf16<<<(N_NODES * TDIM + 255) / 256, 256, 0, stream>>>(temb, tembbf, N_NODES * TDIM);
    gemm64<<<dim3(4, 1, NLAYER), 256, 0, stream>>>(Wt, nullptr, Wg, nullptr, Wtp,
        TDIM, CDIM, CDIM, 0, TDIM * CDIM, CDIM * CDIM, TDIM * CDIM);
    transpose_cast<<<dim3(CDIM / 32, FEAT / 32, 1), 256, 0, stream>>>(
        Wi, FEAT, CDIM, Bt_i, FEAT, 0, 0, 0);
    transpose_cast<<<dim3(CDIM / 32, CDIM / 32, NLAYER), 256, 0, stream>>>(
        Wg, CDIM, CDIM, Bt_h, CDIM + TDIM, 0, CDIM * CDIM, CDIM * (CDIM + TDIM));
    transpose_cast<<<dim3(CDIM / 32, TDIM / 32, NLAYER), 256, 0, stream>>>(
        Wtp, TDIM, CDIM, Bt_h, CDIM + TDIM, CDIM, TDIM * CDIM, CDIM * (CDIM + TDIM));
    gemm64<<<dim3(4, 1, NLAYER), 256, 0, stream>>>(mem, nullptr, Wk, nullptr, kbufs,
        MSLOT, MDIM, CDIM, 0, 0, MDIM * CDIM, MSLOT * CDIM);
    gemm64<<<dim3(4, 1, NLAYER), 256, 0, stream>>>(mem, nullptr, Wv, nullptr, vbufs,
        MSLOT, MDIM, CDIM, 0, 0, MDIM * CDIM, MSLOT * CDIM);
    wqk_build<<<dim3(MSLOT, NLAYER), 256, 0, stream>>>(Wq, kbufs, wqkL);

    // ---- CSR ----
    count_deg<<<(E_EDGES + 255) / 256, 256, 0, stream>>>(dstIdx, deg, E_EDGES);
    scan_kernel<<<1, 1024, 0, stream>>>(deg, offs, N_NODES);
    fill_csr<<<(E_EDGES + 255) / 256, 256, 0, stream>>>(srcIdx, dstIdx, offs, cursor, csr_src, E_EDGES);

    dim3 mfmaGrid(2, N_NODES / 32);   // 2 x 625 = 1250 blocks
    int nodeBlocks = N_NODES / 4;

    // node = relu(x @ Wi + bi) -> nodeA (bf16)
    gemm_mfma<<<mfmaGrid, 256, 0, stream>>>(xbf, FEAT, FEAT, nullptr, 0, FEAT,
                                            Bt_i, bi, nodeA, 1);

    ushort_t* cur = nodeA;
    ushort_t* alt = nodeB;
    for (int l = 0; l < NLAYER; l++) {
        gemm_h<<<mfmaGrid, 256, 0, stream>>>(cur, CDIM, CDIM, tembbf, TDIM, CDIM + TDIM,
                                             Bt_h + (size_t)l * CDIM * (CDIM + TDIM),
                                             a_s + (size_t)l * CDIM, a_d + (size_t)l * CDIM,
                                             hf8, esrc, edst);
        gat_agg_fused<<<nodeBlocks, 256, 0, stream>>>(hf8, esrc, edst, offs, deg, csr_src,
                                                      wqkL + (size_t)l * MSLOT * CDIM,
                                                      vbufs + (size_t)l * MSLOT * CDIM,
                                                      cur, alt, N_NODES);
        ushort_t* t = cur; cur = alt; alt = t;
    }

    col_sum<<<128, 256, 0, stream>>>(cur, pooled, N_NODES);
    finalize<<<1, 64, 0, stream>>>(pooled, mem, Wc, bc, out);
}